// Round 12
// baseline (451.315 us; speedup 1.0000x reference)
//
#include <hip/hip_runtime.h>
#include <math.h>

namespace {

constexpr int B_ = 8;
constexpr int S_ = 2048;
constexpr int D_ = 768;
constexpr int N_ = 196;     // image spatial
constexpr int NF_ = 99;     // image freq bins
constexpr int NFREQ_ = 257;
constexpr int NSEG_ = 9;
constexpr int NBINS_ = NFREQ_ * NSEG_;  // 2313
constexpr int NW_ = D_ * D_;            // 589824
constexpr float TWOPI_ = 6.28318530717958647692f;

using bf16x8 = __attribute__((ext_vector_type(8))) short;
using f32x4  = __attribute__((ext_vector_type(4))) float;

__device__ __forceinline__ int rev9(int x) { return (int)(__brev((unsigned)x) >> 23); }
__device__ __forceinline__ int padz(int i) { return i + (i >> 4); }

__device__ __forceinline__ unsigned short f2bf(float x) {
  unsigned u = __float_as_uint(x);
  u = (u + 0x7FFFu + ((u >> 16) & 1u)) >> 16;
  return (unsigned short)u;
}
__device__ __forceinline__ float bf2f(unsigned short h) {
  return __uint_as_float(((unsigned)h) << 16);
}

// exact GELU via Abramowitz-Stegun 7.1.26 erf (|eps| <= 1.5e-7)
__device__ __forceinline__ float gelu_f(float v) {
  const float x = fabsf(v) * 0.70710678118654752440f;
  const float t = 1.0f / fmaf(0.3275911f, x, 1.0f);
  float p = fmaf(fmaf(fmaf(fmaf(1.061405429f, t, -1.453152027f), t, 1.421413741f),
                      t, -0.284496736f), t, 0.254829592f);
  const float e = __expf(-x * x);
  const float er = 1.0f - p * t * e;
  return 0.5f * v * (1.0f + ((v < 0.f) ? -er : er));
}

__device__ __forceinline__ void gload16(const void* g, void* l) {
  __builtin_amdgcn_global_load_lds((const __attribute__((address_space(1))) void*)g,
                                   (__attribute__((address_space(3))) void*)l, 16, 0, 0);
}

__device__ __forceinline__ float2 cmulf(float2 a, float2 b) {
  return make_float2(a.x * b.x - a.y * b.y, a.x * b.y + a.y * b.x);
}
__device__ __forceinline__ float2 cadd(float2 a, float2 b) {
  return make_float2(a.x + b.x, a.y + b.y);
}
__device__ __forceinline__ float2 csub(float2 a, float2 b) {
  return make_float2(a.x - b.x, a.y - b.y);
}

// ---------------- batched transpose (B,R,C) -> (B,C,R) ----------------
__global__ __launch_bounds__(256) void k_transpose_g(const float* __restrict__ src,
                                                     float* __restrict__ dst,
                                                     int R, int C) {
  __shared__ float tile[32][33];
  const int b = blockIdx.z;
  const int c0 = blockIdx.x * 32;
  const int r0 = blockIdx.y * 32;
  const int tx = threadIdx.x & 31, ty = threadIdx.x >> 5;
  for (int i = ty; i < 32; i += 8)
    tile[i][tx] = src[((size_t)b * R + r0 + i) * C + c0 + tx];
  __syncthreads();
  for (int i = ty; i < 32; i += 8)
    dst[((size_t)b * C + c0 + i) * R + r0 + tx] = tile[tx][i];
}

// ---- fused prep: weight bf16 conv (4 mats) + filter bank + twiddles ----
constexpr int PREP_W = (NW_ + 255) / 256;
constexpr int PREP_WALL = 4 * PREP_W;
constexpr int PREP_FC = (NBINS_ * D_ + 255) / 256;
__global__ __launch_bounds__(256) void k_prep(
    const float* __restrict__ w0, const float* __restrict__ w1,
    const float* __restrict__ w2, const float* __restrict__ w3,
    unsigned short* __restrict__ wbf, const float2* __restrict__ e2,
    float2* __restrict__ FcT, float2* __restrict__ twg) {
  const int bid = blockIdx.x;
  if (bid < PREP_WALL) {
    const int m = bid / PREP_W;
    const int i = (bid - m * PREP_W) * 256 + threadIdx.x;
    if (i >= NW_) return;
    const float* src = (m == 0) ? w0 : (m == 1) ? w1 : (m == 2) ? w2 : w3;
    wbf[(size_t)m * NW_ + i] = f2bf(src[i]);
  } else if (bid < PREP_WALL + PREP_FC) {
    const int o = (bid - PREP_WALL) * 256 + threadIdx.x;
    if (o >= NBINS_ * D_) return;
    const int d = o / NBINS_;
    const int r = o - d * NBINS_;
    const int f = r / NFREQ_;
    const int k = r - f * NFREQ_;
    const int s = k * 9 + f;
    const float2 a = e2[(size_t)s * D_ + d];
    const float2 b = e2[(size_t)(NBINS_ + s) * D_ + d];
    FcT[o] = make_float2(-(a.x + b.x), -(a.y + b.y));
  } else {
    const int i = (bid - PREP_WALL - PREP_FC) * 256 + threadIdx.x;
    if (i >= 511) return;
    const int v = i + 1;
    const int h = 1 << (31 - __clz(v));
    const int j = v - h;
    float sn, cs;
    sincosf((float)j * ((TWOPI_ * 0.5f) / (float)h), &sn, &cs);
    twg[i] = make_float2(cs, sn);
  }
}

// ---- image forward DFT + filter + gate partials ----
__global__ __launch_bounds__(256) void k_img_dft_f(
    const float* __restrict__ image, const float2* __restrict__ bank2,
    const float2* __restrict__ gsel2, float2* __restrict__ imgF,
    float* __restrict__ part) {
  const int fg = blockIdx.x;
  const int f0 = fg * 9;
  const int d = blockIdx.y * 256 + threadIdx.x;
  const int b = blockIdx.z;
  __shared__ float2 tws[9 * N_];
  for (int idx = threadIdx.x; idx < 9 * N_; idx += 256) {
    const int fi = idx / N_;
    const int t = idx - fi * N_;
    const int r = ((f0 + fi) * t) % N_;
    float sn, cs;
    sincosf(TWOPI_ * (float)r / (float)N_, &sn, &cs);
    tws[idx] = make_float2(cs, sn);
  }
  __syncthreads();
  float re[9] = {}, im[9] = {};
  const float* ip = image + (size_t)b * N_ * D_ + d;
  for (int t = 0; t < N_; ++t) {
    const float v = ip[(size_t)t * D_];
#pragma unroll
    for (int fi = 0; fi < 9; ++fi) {
      const float2 w = tws[fi * N_ + t];
      re[fi] = fmaf(v, w.x, re[fi]);
      im[fi] = fmaf(-v, w.y, im[fi]);
    }
  }
  const float sc = 1.0f / (196.0f * 99.0f);
  float gp = 0.f;
#pragma unroll
  for (int fi = 0; fi < 9; ++fi) {
    const int f = f0 + fi;
    const float pr = (re[fi] * re[fi] - im[fi] * im[fi]) * sc;
    const float pi2 = (2.f * re[fi] * im[fi]) * sc;
    const size_t fd = (size_t)f * D_ + d;
    const float2 c0 = bank2[fd];
    const float2 c1 = bank2[(size_t)NF_ * D_ + fd];
    const float fcr = -(c0.x + c1.x), fci = -(c0.y + c1.y);
    const float zr = pr * fcr - pi2 * fci;
    const float zi = pr * fci + pi2 * fcr;
    imgF[(size_t)(b * NF_ + f) * D_ + d] = make_float2(zr, zi);
    const float2 gw = gsel2[fd];
    gp += zr * gw.x - zi * gw.y;
  }
  part[((size_t)b * 11 + fg) * D_ + d] = gp;
}

// ---- gate matvec, folds 11 partials: gate[b][d0..d0+16) ----
__global__ __launch_bounds__(256) void k_gate_mm2(const float* __restrict__ part,
                                                  const float* __restrict__ W,
                                                  const float* __restrict__ bias,
                                                  float* __restrict__ gate) {
  __shared__ float row[8][D_];
  __shared__ float red[16][16][8];
  const int tid = threadIdx.x;
  const int d0 = blockIdx.x * 16;
  for (int i = tid; i < 8 * D_; i += 256) {
    const int b = i / D_, e = i - b * D_;
    float s = 0.f;
    for (int p = 0; p < 11; ++p) s += part[((size_t)b * 11 + p) * D_ + e];
    row[b][e] = s * (1.0f / 99.0f);
  }
  __syncthreads();
  const int dl = tid >> 4;
  const int ec = tid & 15;
  const float* w = W + (size_t)(d0 + dl) * D_ + ec * 48;
  float acc[8] = {};
  for (int e = 0; e < 48; e += 4) {
    const float4 wv = *reinterpret_cast<const float4*>(w + e);
    const int eg = ec * 48 + e;
#pragma unroll
    for (int b = 0; b < 8; ++b) {
      acc[b] = fmaf(row[b][eg], wv.x, acc[b]);
      acc[b] = fmaf(row[b][eg + 1], wv.y, acc[b]);
      acc[b] = fmaf(row[b][eg + 2], wv.z, acc[b]);
      acc[b] = fmaf(row[b][eg + 3], wv.w, acc[b]);
    }
  }
#pragma unroll
  for (int b = 0; b < 8; ++b) red[dl][ec][b] = acc[b];
  __syncthreads();
  if (tid < 128) {
    const int dl2 = tid >> 3, b = tid & 7;
    float s = bias[d0 + dl2];
    for (int c = 0; c < 16; ++c) s += red[dl2][c][b];
    gate[b * D_ + d0 + dl2] = s;
  }
}

// ---- image inverse DFT (ortho) + residual ----
__global__ __launch_bounds__(256) void k_img_idft(
    const float2* __restrict__ imgF, const float* __restrict__ image,
    float* __restrict__ xi) {
  const int t0 = blockIdx.x * 14;
  const int d = blockIdx.y * 256 + threadIdx.x;
  const int b = blockIdx.z;
  __shared__ float2 tws[14 * NF_];
  for (int idx = threadIdx.x; idx < 14 * NF_; idx += 256) {
    const int ti = idx / NF_;
    const int f = idx - ti * NF_;
    const int r = ((t0 + ti) * f) % N_;
    float sn, cs;
    sincosf(TWOPI_ * (float)r / (float)N_, &sn, &cs);
    tws[idx] = make_float2(cs, sn);
  }
  __syncthreads();
  const float2* zp = imgF + (size_t)b * NF_ * D_ + d;
  const float2 z0 = zp[0];
  const float2 zny = zp[(size_t)(NF_ - 1) * D_];
  float acc[14];
#pragma unroll
  for (int ti = 0; ti < 14; ++ti)
    acc[ti] = z0.x + (((t0 + ti) & 1) ? -zny.x : zny.x);
  for (int f = 1; f < NF_ - 1; ++f) {
    const float2 z = zp[(size_t)f * D_];
#pragma unroll
    for (int ti = 0; ti < 14; ++ti) {
      const float2 w = tws[ti * NF_ + f];
      acc[ti] += 2.f * (z.x * w.x - z.y * w.y);
    }
  }
#pragma unroll
  for (int ti = 0; ti < 14; ++ti) {
    const size_t idx = (size_t)(b * N_ + t0 + ti) * D_ + d;
    xi[idx] = acc[ti] * (1.0f / 14.0f) + image[idx];
  }
}

// ---------------- LayerNorm f32 in -> bf16 out ----------------
__global__ __launch_bounds__(256) void k_layernorm_f2b(const float* __restrict__ x,
                                                       const float* __restrict__ g,
                                                       const float* __restrict__ b,
                                                       unsigned short* __restrict__ out) {
  const int row = blockIdx.x;
  const int tid = threadIdx.x;
  const float* xr = x + (size_t)row * D_;
  const float v0 = xr[tid], v1 = xr[tid + 256], v2 = xr[tid + 512];
  float s = v0 + v1 + v2;
  float q = v0 * v0 + v1 * v1 + v2 * v2;
  __shared__ float red[8];
  for (int off = 32; off > 0; off >>= 1) {
    s += __shfl_down(s, off);
    q += __shfl_down(q, off);
  }
  if ((tid & 63) == 0) { red[tid >> 6] = s; red[4 + (tid >> 6)] = q; }
  __syncthreads();
  s = red[0] + red[1] + red[2] + red[3];
  q = red[4] + red[5] + red[6] + red[7];
  const float mean = s * (1.0f / 768.0f);
  const float var = q * (1.0f / 768.0f) - mean * mean;
  const float inv = rsqrtf(var + 1e-5f);
  unsigned short* orow = out + (size_t)row * D_;
  orow[tid]       = f2bf((v0 - mean) * inv * g[tid]       + b[tid]);
  orow[tid + 256] = f2bf((v1 - mean) * inv * g[tid + 256] + b[tid + 256]);
  orow[tid + 512] = f2bf((v2 - mean) * inv * g[tid + 512] + b[tid + 512]);
}

// ================= ecg fused FFT (radix-8, 512 thr, 2 signals/block) ===========
template <int H, int DIR, bool TRIV>
__device__ __forceinline__ void pass8(float2* z, int l,
                                      float2 wa, float2 wb, float2 wc) {
  asm volatile("s_waitcnt lgkmcnt(0)" ::: "memory");
  const float sg = (DIR < 0) ? -1.f : 1.f;
  const int base = (H == 1) ? (l << 3)
                 : (H == 8) ? (((l >> 3) << 6) | (l & 7))
                            : l;
  const float2 x0 = z[padz(base)],         x1 = z[padz(base + H)];
  const float2 x2 = z[padz(base + 2 * H)], x3 = z[padz(base + 3 * H)];
  const float2 x4 = z[padz(base + 4 * H)], x5 = z[padz(base + 5 * H)];
  const float2 x6 = z[padz(base + 6 * H)], x7 = z[padz(base + 7 * H)];
  const float2 WA = make_float2(wa.x, sg * wa.y);
  const float2 WB = make_float2(wb.x, sg * wb.y);
  const float2 WC = make_float2(wc.x, sg * wc.y);
  const float2 WBp = make_float2(-sg * WB.y, sg * WB.x);  // WB * W4
  float2 t, u;
  t = TRIV ? x1 : cmulf(x1, WA); const float2 A0 = cadd(x0, t), A1 = csub(x0, t);
  t = TRIV ? x3 : cmulf(x3, WA); const float2 A2 = cadd(x2, t), A3 = csub(x2, t);
  t = TRIV ? x5 : cmulf(x5, WA); const float2 A4 = cadd(x4, t), A5 = csub(x4, t);
  t = TRIV ? x7 : cmulf(x7, WA); const float2 A6 = cadd(x6, t), A7 = csub(x6, t);
  t = TRIV ? A2 : cmulf(A2, WB);
  u = TRIV ? make_float2(-sg * A3.y, sg * A3.x) : cmulf(A3, WBp);
  const float2 B0 = cadd(A0, t), B2 = csub(A0, t);
  const float2 B1 = cadd(A1, u), B3 = csub(A1, u);
  t = TRIV ? A6 : cmulf(A6, WB);
  u = TRIV ? make_float2(-sg * A7.y, sg * A7.x) : cmulf(A7, WBp);
  const float2 B4 = cadd(A4, t), B6 = csub(A4, t);
  const float2 B5 = cadd(A5, u), B7 = csub(A5, u);
  const float r_ = 0.70710678118654752440f;
  const float2 F1 = TRIV ? make_float2(r_, sg * r_)
                         : cmulf(WC, make_float2(r_, sg * r_));
  const float2 F2 = TRIV ? make_float2(0.f, sg)
                         : make_float2(-sg * WC.y, sg * WC.x);
  const float2 F3 = TRIV ? make_float2(-r_, sg * r_)
                         : cmulf(WC, make_float2(-r_, sg * r_));
  t = TRIV ? B4 : cmulf(B4, WC);
  z[padz(base)]         = cadd(B0, t);
  z[padz(base + 4 * H)] = csub(B0, t);
  t = cmulf(B5, F1);
  z[padz(base + H)]     = cadd(B1, t);
  z[padz(base + 5 * H)] = csub(B1, t);
  t = cmulf(B6, F2);
  z[padz(base + 2 * H)] = cadd(B2, t);
  z[padz(base + 6 * H)] = csub(B2, t);
  t = cmulf(B7, F3);
  z[padz(base + 3 * H)] = cadd(B3, t);
  z[padz(base + 7 * H)] = csub(B3, t);
}

template <int FA, int FB>
__device__ __forceinline__ void scatter_buf(float2* z, const float (&s)[8],
                                            float wlo, float whi, int rlo, int rhi) {
  constexpr int iAlo = (FA > 0) ? FA - 1 : 0;
  constexpr int iAhi = (FA < 8) ? FA : 0;
  constexpr int iBlo = (FB > 0) ? FB - 1 : 0;
  constexpr int iBhi = (FB >= 0 && FB < 8) ? FB : 0;
  const float aLo = (FA == 0) ? 0.f : s[iAlo] * wlo;
  const float aHi = (FA == 8) ? 0.f : s[iAhi] * whi;
  const float bLo = (FB <= 0) ? 0.f : s[iBlo] * wlo;
  const float bHi = (FB < 0 || FB == 8) ? 0.f : s[iBhi] * whi;
  z[rlo] = make_float2(aLo, bLo);
  z[rhi] = make_float2(aHi, bHi);
}

// A-part scaled by gA, B-part by gB
template <int FA, int FB>
__device__ __forceinline__ void filt_pack(const float2* z, int k, float gA, float gB,
                                          float2 cA, float2 cB,
                                          float2& Ck, float2& Cm) {
  const int q = (512 - k) & 511;
  const float2 Zk = z[padz(k)], Zq = z[padz(q)];
  const float sc = 0.5f / 256.f;
  const float ar = (Zk.x + Zq.x) * sc, ai = (Zk.y - Zq.y) * sc;
  float yar, yai, ybr = 0.f, ybi = 0.f;
  {
    const float pr = (ar * ar - ai * ai) * (1.f / 2313.f);
    const float pi = (2.f * ar * ai) * (1.f / 2313.f);
    yar = (pr * cA.x - pi * cA.y) * gA;
    yai = (pr * cA.y + pi * cA.x) * gA;
  }
  if (FB >= 0) {
    const float br = (Zk.y + Zq.y) * sc, bi = (Zq.x - Zk.x) * sc;
    const float pr = (br * br - bi * bi) * (1.f / 2313.f);
    const float pi = (2.f * br * bi) * (1.f / 2313.f);
    ybr = (pr * cB.x - pi * cB.y) * gB;
    ybi = (pr * cB.y + pi * cB.x) * gB;
  }
  if (k == 0 || k == 256) {
    Ck = make_float2(yar, ybr);
    Cm = Ck;
  } else {
    Ck = make_float2(yar - ybi, yai + ybr);
    Cm = make_float2(yar + ybi, ybr - yai);
  }
}

__global__ __launch_bounds__(512) void k_ecg_fft(
    const float* __restrict__ ecgT, const float2* __restrict__ FcT,
    const float* __restrict__ gate, const float2* __restrict__ twg,
    unsigned short* __restrict__ xtT) {
  const int bd = blockIdx.x;              // 0..3071
  const int b = bd / 384, d0 = bd - (bd / 384) * 384;
  const int tid = threadIdx.x;
  const int grp = tid >> 8;               // signal group 0/1
  const int lt = tid & 255;
  const int wid = tid >> 6;               // wave 0..7 <-> buffer
  const int l = tid & 63;
  const int d = d0 + grp * 384;
  const int myBD = b * 768 + d;

  __shared__ float2 z[8][544];            // 34.8 KB

  float s[8];
  const float* src = ecgT + (size_t)myBD * S_;
#pragma unroll
  for (int k = 0; k < 8; ++k) s[k] = src[k * 256 + lt];

  float2 ptw[6];
  ptw[0] = twg[7 + (l & 7)];
  ptw[1] = twg[15 + (l & 7)];
  ptw[2] = twg[31 + (l & 7)];
  ptw[3] = twg[63 + l];
  ptw[4] = twg[127 + l];
  ptw[5] = twg[255 + l];
  const float2 t8 = twg[255 + lt];
  const float c0 = t8.x;
  const float wlo = 0.5f - 0.5f * c0;
  const float whi = 0.5f + 0.5f * c0;
  const int rlo = padz(rev9(lt)), rhi = padz(rev9(lt + 256));

  const float gX = gate[b * 768 + d0];
  const float gY = gate[b * 768 + d0 + 384];
  const float gOwn = grp ? gY : gX;
  const float2* fc = FcT + (size_t)d * NBINS_;

  float accr[10];
#pragma unroll
  for (int i = 0; i < 10; ++i) accr[i] = 0.f;

  // ======== super A: frames (0,8),(1,2),(3,4),(5,6) of own signal ========
  const float2 cA0 = fc[0 * 257 + lt], cB0 = fc[8 * 257 + lt];
  const float2 cA1 = fc[1 * 257 + lt], cB1 = fc[2 * 257 + lt];
  const float2 cA2 = fc[3 * 257 + lt], cB2 = fc[4 * 257 + lt];
  const float2 cA3 = fc[5 * 257 + lt], cB3 = fc[6 * 257 + lt];
  float2* zg = z[grp * 4];
  scatter_buf<0, 8>(z[grp * 4 + 0], s, wlo, whi, rlo, rhi);
  scatter_buf<1, 2>(z[grp * 4 + 1], s, wlo, whi, rlo, rhi);
  scatter_buf<3, 4>(z[grp * 4 + 2], s, wlo, whi, rlo, rhi);
  scatter_buf<5, 6>(z[grp * 4 + 3], s, wlo, whi, rlo, rhi);
  __syncthreads();
  {  // forward FFT: wave w -> buffer w (all 8 busy)
    float2* zz = z[wid];
    pass8<1, -1, true>(zz, l, ptw[0], ptw[1], ptw[2]);
    pass8<8, -1, false>(zz, l, ptw[0], ptw[1], ptw[2]);
    pass8<64, -1, false>(zz, l, ptw[3], ptw[4], ptw[5]);
  }
  __syncthreads();
  float2 Ck0, Cm0, Ck1, Cm1, Ck2, Cm2, Ck3, Cm3;
  float2 Cn0, Cn1, Cn2, Cn3, dum;
  filt_pack<0, 8>(z[grp * 4 + 0], lt, gOwn, gOwn, cA0, cB0, Ck0, Cm0);
  filt_pack<1, 2>(z[grp * 4 + 1], lt, gOwn, gOwn, cA1, cB1, Ck1, Cm1);
  filt_pack<3, 4>(z[grp * 4 + 2], lt, gOwn, gOwn, cA2, cB2, Ck2, Cm2);
  filt_pack<5, 6>(z[grp * 4 + 3], lt, gOwn, gOwn, cA3, cB3, Ck3, Cm3);
  if (lt == 0) {
    float2 nA, nB;
    nA = fc[0 * 257 + 256]; nB = fc[8 * 257 + 256];
    filt_pack<0, 8>(z[grp * 4 + 0], 256, gOwn, gOwn, nA, nB, Cn0, dum);
    nA = fc[1 * 257 + 256]; nB = fc[2 * 257 + 256];
    filt_pack<1, 2>(z[grp * 4 + 1], 256, gOwn, gOwn, nA, nB, Cn1, dum);
    nA = fc[3 * 257 + 256]; nB = fc[4 * 257 + 256];
    filt_pack<3, 4>(z[grp * 4 + 2], 256, gOwn, gOwn, nA, nB, Cn2, dum);
    nA = fc[5 * 257 + 256]; nB = fc[6 * 257 + 256];
    filt_pack<5, 6>(z[grp * 4 + 3], 256, gOwn, gOwn, nA, nB, Cn3, dum);
  }
  __syncthreads();
  {
    zg[0 * 544 + rlo] = Ck0; zg[1 * 544 + rlo] = Ck1;
    zg[2 * 544 + rlo] = Ck2; zg[3 * 544 + rlo] = Ck3;
    if (lt == 0) {
      zg[0 * 544 + padz(1)] = Cn0; zg[1 * 544 + padz(1)] = Cn1;
      zg[2 * 544 + padz(1)] = Cn2; zg[3 * 544 + padz(1)] = Cn3;
    } else {
      const int rm = padz(rev9(512 - lt));
      zg[0 * 544 + rm] = Cm0; zg[1 * 544 + rm] = Cm1;
      zg[2 * 544 + rm] = Cm2; zg[3 * 544 + rm] = Cm3;
    }
  }
  __syncthreads();
  {  // inverse FFT
    float2* zz = z[wid];
    pass8<1, 1, true>(zz, l, ptw[0], ptw[1], ptw[2]);
    pass8<8, 1, false>(zz, l, ptw[0], ptw[1], ptw[2]);
    pass8<64, 1, false>(zz, l, ptw[3], ptw[4], ptw[5]);
  }
  __syncthreads();
  {  // overlap-add (own group's 4 buffers)
    float2 vLo, vHi;
    vLo = zg[0 * 544 + padz(lt)]; vHi = zg[0 * 544 + padz(lt + 256)];
    accr[0] += 0.5f * wlo * vLo.x; accr[1] += 0.5f * whi * vHi.x;
    accr[8] += 0.5f * wlo * vLo.y; accr[9] += 0.5f * whi * vHi.y;
    vLo = zg[1 * 544 + padz(lt)]; vHi = zg[1 * 544 + padz(lt + 256)];
    accr[1] += 0.5f * wlo * vLo.x; accr[2] += 0.5f * whi * vHi.x;
    accr[2] += 0.5f * wlo * vLo.y; accr[3] += 0.5f * whi * vHi.y;
    vLo = zg[2 * 544 + padz(lt)]; vHi = zg[2 * 544 + padz(lt + 256)];
    accr[3] += 0.5f * wlo * vLo.x; accr[4] += 0.5f * whi * vHi.x;
    accr[4] += 0.5f * wlo * vLo.y; accr[5] += 0.5f * whi * vHi.y;
    vLo = zg[3 * 544 + padz(lt)]; vHi = zg[3 * 544 + padz(lt + 256)];
    accr[5] += 0.5f * wlo * vLo.x; accr[6] += 0.5f * whi * vHi.x;
    accr[6] += 0.5f * wlo * vLo.y; accr[7] += 0.5f * whi * vHi.y;
  }
  __syncthreads();  // z[0] reads done before super C overwrites

  // ======== super C: (X7 re, Y7 im) in buffer 0 ========
  {
    float* z0f = (float*)z[0];
    z0f[2 * rlo + grp] = s[6] * wlo;   // frame 7 lo half
    z0f[2 * rhi + grp] = s[7] * whi;   // frame 7 hi half
  }
  __syncthreads();
  if (wid == 0) {
    pass8<1, -1, true>(z[0], l, ptw[0], ptw[1], ptw[2]);
    pass8<8, -1, false>(z[0], l, ptw[0], ptw[1], ptw[2]);
    pass8<64, -1, false>(z[0], l, ptw[3], ptw[4], ptw[5]);
  }
  __syncthreads();
  float2 CkC, CmC, CnC;
  if (grp == 0) {
    const float2* fcY = FcT + (size_t)(d0 + 384) * NBINS_;
    const float2 cA = fc[7 * 257 + lt];
    const float2 cB = fcY[7 * 257 + lt];
    filt_pack<7, 7>(z[0], lt, gX, gY, cA, cB, CkC, CmC);
    if (lt == 0) {
      const float2 nA = fc[7 * 257 + 256];
      const float2 nB = fcY[7 * 257 + 256];
      filt_pack<7, 7>(z[0], 256, gX, gY, nA, nB, CnC, dum);
    }
  }
  __syncthreads();
  if (grp == 0) {
    z[0][rlo] = CkC;
    if (lt == 0) z[0][padz(1)] = CnC;
    else z[0][padz(rev9(512 - lt))] = CmC;
  }
  __syncthreads();
  if (wid == 0) {
    pass8<1, 1, true>(z[0], l, ptw[0], ptw[1], ptw[2]);
    pass8<8, 1, false>(z[0], l, ptw[0], ptw[1], ptw[2]);
    pass8<64, 1, false>(z[0], l, ptw[3], ptw[4], ptw[5]);
  }
  __syncthreads();
  {
    const float2 vLo = z[0][padz(lt)], vHi = z[0][padz(lt + 256)];
    const float xlo = grp ? vLo.y : vLo.x;
    const float xhi = grp ? vHi.y : vHi.x;
    accr[7] += 0.5f * wlo * xlo;
    accr[8] += 0.5f * whi * xhi;
  }

  // ---- output: own signal ----
  const float rinv = 1.0f / (0.5f + 0.5f * c0 * c0);
  unsigned short* dst = xtT + (size_t)myBD * S_;
#pragma unroll
  for (int i2 = 0; i2 < 8; ++i2)
    dst[i2 * 256 + lt] = f2bf(accr[i2 + 1] * rinv + s[i2]);
}

// ---- per-(b,t) LN stats over d, reading bf16 xtT[b][d][t] as uint pairs ----
__global__ __launch_bounds__(256) void k_colstats_bf(const unsigned short* __restrict__ xtT,
                                                     float2* __restrict__ stats) {
  const int b = blockIdx.y;
  const int t0 = blockIdx.x * 128;
  const int tx = threadIdx.x & 63;
  const int ty = threadIdx.x >> 6;
  float s0 = 0.f, q0 = 0.f, s1 = 0.f, q1 = 0.f;
  const unsigned int* base = (const unsigned int*)(xtT + (size_t)b * D_ * S_);
  for (int dd = ty; dd < D_; dd += 4) {
    const unsigned int u = base[(size_t)dd * (S_ / 2) + (t0 >> 1) + tx];
    const float v0 = bf2f((unsigned short)(u & 0xffffu));
    const float v1 = bf2f((unsigned short)(u >> 16));
    s0 += v0; q0 = fmaf(v0, v0, q0);
    s1 += v1; q1 = fmaf(v1, v1, q1);
  }
  __shared__ float sh[4][64][4];
  sh[ty][tx][0] = s0; sh[ty][tx][1] = q0; sh[ty][tx][2] = s1; sh[ty][tx][3] = q1;
  __syncthreads();
  if (ty == 0) {
    s0 = sh[0][tx][0] + sh[1][tx][0] + sh[2][tx][0] + sh[3][tx][0];
    q0 = sh[0][tx][1] + sh[1][tx][1] + sh[2][tx][1] + sh[3][tx][1];
    s1 = sh[0][tx][2] + sh[1][tx][2] + sh[2][tx][2] + sh[3][tx][2];
    q1 = sh[0][tx][3] + sh[1][tx][3] + sh[2][tx][3] + sh[3][tx][3];
    stats[(size_t)b * S_ + t0 + 2 * tx]     = make_float2(s0, q0);
    stats[(size_t)b * S_ + t0 + 2 * tx + 1] = make_float2(s1, q1);
  }
}

// ---- transpose + LN apply, bf16 in -> bf16 out ----
__global__ __launch_bounds__(256) void k_transpose_ln(
    const unsigned short* __restrict__ xtT, const float2* __restrict__ stats,
    const float* __restrict__ g, const float* __restrict__ bia,
    unsigned short* __restrict__ xhat) {
  __shared__ float tile[32][33];
  const int b = blockIdx.z;
  const int t0 = blockIdx.x * 32;
  const int d0 = blockIdx.y * 32;
  const int tx = threadIdx.x & 31, ty = threadIdx.x >> 5;
  for (int i = ty; i < 32; i += 8)
    tile[i][tx] = bf2f(xtT[((size_t)b * D_ + d0 + i) * S_ + t0 + tx]);
  __syncthreads();
  const float gv = g[d0 + tx], bv = bia[d0 + tx];
  for (int i = ty; i < 32; i += 8) {
    const float2 st = stats[(size_t)b * S_ + t0 + i];
    const float mean = st.x * (1.0f / 768.0f);
    const float var = st.y * (1.0f / 768.0f) - mean * mean;
    const float inv = rsqrtf(var + 1e-5f);
    xhat[((size_t)b * S_ + t0 + i) * D_ + d0 + tx] =
        f2bf((tile[tx][i] - mean) * inv * gv + bv);
  }
}

// ---- dual-segment LayerNorm, bf16 in -> f32 out ----
__global__ __launch_bounds__(256) void k_layernorm_dual(
    const unsigned short* __restrict__ x1, const float* __restrict__ g1,
    const float* __restrict__ b1, float* __restrict__ o1, int n1,
    const unsigned short* __restrict__ x2, const float* __restrict__ g2,
    const float* __restrict__ b2, float* __restrict__ o2) {
  int row = blockIdx.x;
  const unsigned short* x; const float *g, *b; float* o;
  if (row < n1) { x = x1; g = g1; b = b1; o = o1; }
  else { row -= n1; x = x2; g = g2; b = b2; o = o2; }
  const int tid = threadIdx.x;
  const unsigned short* xr = x + (size_t)row * D_;
  const float v0 = bf2f(xr[tid]), v1 = bf2f(xr[tid + 256]), v2 = bf2f(xr[tid + 512]);
  float s = v0 + v1 + v2;
  float q = v0 * v0 + v1 * v1 + v2 * v2;
  __shared__ float red[8];
  for (int off = 32; off > 0; off >>= 1) {
    s += __shfl_down(s, off);
    q += __shfl_down(q, off);
  }
  if ((tid & 63) == 0) { red[tid >> 6] = s; red[4 + (tid >> 6)] = q; }
  __syncthreads();
  s = red[0] + red[1] + red[2] + red[3];
  q = red[4] + red[5] + red[6] + red[7];
  const float mean = s * (1.0f / 768.0f);
  const float var = q * (1.0f / 768.0f) - mean * mean;
  const float inv = rsqrtf(var + 1e-5f);
  float* orow = o + (size_t)row * D_;
  orow[tid]       = (v0 - mean) * inv * g[tid]       + b[tid];
  orow[tid + 256] = (v1 - mean) * inv * g[tid + 256] + b[tid + 256];
  orow[tid + 512] = (v2 - mean) * inv * g[tid + 512] + b[tid + 512];
}

// ---------- dual-segment MFMA GEMM, double-buffered pipeline ----------
// MODE 0: exact GELU -> bf16 ; MODE 1: +resid(bf16) -> bf16
template <int MODE>
__global__ __launch_bounds__(256) void k_gemm_dual(
    const unsigned short* __restrict__ A1, const unsigned short* __restrict__ W1,
    const float* __restrict__ b1, const unsigned short* __restrict__ r1,
    unsigned short* __restrict__ o1, int M1, int nby1,
    const unsigned short* __restrict__ A2, const unsigned short* __restrict__ W2,
    const float* __restrict__ b2, const unsigned short* __restrict__ r2,
    unsigned short* __restrict__ o2, int M2) {
  __shared__ unsigned short Asm[2][128 * 64];
  __shared__ unsigned short Bsm[2][128 * 64];
  const int tid = threadIdx.x;
  const int lane = tid & 63, wid = tid >> 6;
  const int wr = wid >> 1, wc = wid & 1;
  int bx, by;
  {
    const int nwg = gridDim.x * gridDim.y;
    const int bid = blockIdx.y * gridDim.x + blockIdx.x;
    const int xcd = bid & 7, lin = bid >> 3;
    const int qq = nwg >> 3, rr = nwg & 7;
    const int nbid = (xcd < rr) ? xcd * (qq + 1) + lin
                                : rr * (qq + 1) + (xcd - rr) * qq + lin;
    bx = nbid % gridDim.x;
    by = nbid / gridDim.x;
  }
  const unsigned short* Abf; const unsigned short* Wbf; const float* bias;
  const unsigned short* resid; unsigned short* outb; int M;
  if (by < nby1) { Abf = A1; Wbf = W1; bias = b1; resid = r1; outb = o1; M = M1; }
  else { by -= nby1; Abf = A2; Wbf = W2; bias = b2; resid = r2; outb = o2; M = M2; }
  const int n0 = bx * 128, m0 = by * 128;

  auto STAGE = [&](int buf, int kt) {
    const int k0 = kt * 64;
#pragma unroll
    for (int i = 0; i < 4; ++i) {
      const int c = tid + 256 * i;
      const int row = c >> 3, sl = c & 7;
      const int gsl = sl ^ (row & 7);
      gload16(Abf + (size_t)(m0 + row) * 768 + k0 + gsl * 8, &Asm[buf][c * 8]);
      gload16(Wbf + (size_t)(n0 + row) * 768 + k0 + gsl * 8, &Bsm[buf][c * 8]);
    }
  };

  f32x4 acc[4][4] = {};
  STAGE(0, 0);
  for (int kt = 0; kt < 12; ++kt) {
    const int cur = kt & 1;
    if (kt < 11) {
      STAGE(cur ^ 1, kt + 1);
      asm volatile("s_waitcnt vmcnt(8)" ::: "memory");
    } else {
      asm volatile("s_waitcnt vmcnt(0)" ::: "memory");
    }
    __builtin_amdgcn_sched_barrier(0);
    __builtin_amdgcn_s_barrier();
#pragma unroll
    for (int ks = 0; ks < 2; ++ks) {
      bf16x8 af[4], bfv[4];
#pragma unroll
      for (int mi = 0; mi < 4; ++mi) {
        const int row = wr * 64 + mi * 16 + (lane & 15);
        const int sl = (ks * 4 + (lane >> 4)) ^ (row & 7);
        af[mi] = *(const bf16x8*)((const char*)Asm[cur] + row * 128 + sl * 16);
      }
#pragma unroll
      for (int ni = 0; ni < 4; ++ni) {
        const int row = wc * 64 + ni * 16 + (lane & 15);
        const int sl = (ks * 4 + (lane >> 4)) ^ (row & 7);
        bfv[ni] = *(const bf16x8*)((const char*)Bsm[cur] + row * 128 + sl * 16);
      }
#pragma unroll
      for (int mi = 0; mi < 4; ++mi)
#pragma unroll
        for (int ni = 0; ni < 4; ++ni)
          acc[mi][ni] = __builtin_amdgcn_mfma_f32_16x16x32_bf16(af[mi], bfv[ni],
                                                                acc[mi][ni], 0, 0, 0);
    }
    __builtin_amdgcn_sched_barrier(0);
    __builtin_amdgcn_s_barrier();
  }
#pragma unroll
  for (int mi = 0; mi < 4; ++mi) {
#pragma unroll
    for (int ni = 0; ni < 4; ++ni) {
      const int col = n0 + wc * 64 + ni * 16 + (lane & 15);
#pragma unroll
      for (int e = 0; e < 4; ++e) {
        const int row = m0 + wr * 64 + mi * 16 + (lane >> 4) * 4 + e;
        if (row >= M) continue;
        float v = acc[mi][ni][e] + bias[col];
        if (MODE == 0) {
          v = gelu_f(v);
        } else {
          v += bf2f(resid[(size_t)row * 768 + col]);
        }
        outb[(size_t)row * 768 + col] = f2bf(v);
      }
    }
  }
}

}  // namespace

extern "C" void kernel_launch(void* const* d_in, const int* in_sizes, int n_in,
                              void* d_out, int out_size, void* d_ws, size_t ws_size,
                              hipStream_t stream) {
  (void)in_sizes; (void)n_in; (void)out_size; (void)ws_size;
  const float* ecg     = (const float*)d_in[0];
  const float* image   = (const float*)d_in[1];
  const float* ebank   = (const float*)d_in[2];
  const float* cbank   = (const float*)d_in[3];
  const float* gsel    = (const float*)d_in[4];
  const float* gw      = (const float*)d_in[5];
  const float* gb      = (const float*)d_in[6];
  const float* e_ln1_g = (const float*)d_in[7];
  const float* e_ln1_b = (const float*)d_in[8];
  const float* e_w1    = (const float*)d_in[9];
  const float* e_b1    = (const float*)d_in[10];
  const float* e_w2    = (const float*)d_in[11];
  const float* e_b2    = (const float*)d_in[12];
  const float* e_ln2_g = (const float*)d_in[13];
  const float* e_ln2_b = (const float*)d_in[14];
  const float* c_ln1_g = (const float*)d_in[15];
  const float* c_ln1_b = (const float*)d_in[16];
  const float* c_w1    = (const float*)d_in[17];
  const float* c_b1    = (const float*)d_in[18];
  const float* c_w2    = (const float*)d_in[19];
  const float* c_b2    = (const float*)d_in[20];
  const float* c_ln2_g = (const float*)d_in[21];
  const float* c_ln2_b = (const float*)d_in[22];

  float* out = (float*)d_out;
  float* ws = (float*)d_ws;

  constexpr size_t TXT = (size_t)8 * 2048 * 768;   // 12,582,912 floats
  constexpr size_t IMG = (size_t)8 * 196 * 768;    // 1,204,224 elems

  // ws layout: A | Bb | wbf | gatev | stats | gpart | twg
  float* A  = ws;
  float* Bb = A + TXT;
  unsigned short* wbf = (unsigned short*)(Bb + TXT);
  unsigned short* ew1b = wbf;
  unsigned short* ew2b = wbf + NW_;
  unsigned short* cw1b = wbf + 2 * NW_;
  unsigned short* cw2b = wbf + 3 * NW_;
  float* gatev = (float*)(wbf + 4 * (size_t)NW_);
  float2* stats = (float2*)(gatev + 8 * 768);
  float* gpart = (float*)(stats + 8 * 2048);   // 8*11*768 floats
  float2* twg = (float2*)(gpart + 8 * 11 * 768);

  float2* FcT = (float2*)out;  // parked in d_out (dead before final LN)

  // text buffers: A = xhat (first half, bf16) | y_tb (second half, bf16)
  unsigned short* xhat = (unsigned short*)A;
  unsigned short* y_tb = (unsigned short*)A + TXT;
  // Bb first half: xtT then h_t (bf16); second half: image scratch
  unsigned short* xtT = (unsigned short*)Bb;
  unsigned short* h_t = (unsigned short*)Bb;
  float* Bb2 = Bb + TXT / 2;
  float2* imgF = (float2*)Bb2;                               // 1,216,512 floats
  float* xi = Bb2 + 1216512;                                 // 1,204,224 floats
  unsigned short* xh_i = (unsigned short*)(xi + IMG);        // bf16 LN1 / resid
  unsigned short* h_i  = xh_i + IMG;
  unsigned short* y_ib = h_i + IMG;

  // ---- one-time prep (fused) ----
  k_prep<<<PREP_WALL + PREP_FC + 2, 256, 0, stream>>>(
      e_w1, e_w2, c_w1, c_w2, wbf, (const float2*)ebank, FcT, twg);

  // ---- image path front (produces gate + xh_i) ----
  k_img_dft_f<<<dim3(11, 3, 8), 256, 0, stream>>>(image, (const float2*)cbank,
                                                  (const float2*)gsel, imgF, gpart);
  k_gate_mm2<<<48, 256, 0, stream>>>(gpart, gw, gb, gatev);
  k_img_idft<<<dim3(14, 3, 8), 256, 0, stream>>>(imgF, image, xi);
  k_layernorm_f2b<<<1568, 256, 0, stream>>>(xi, c_ln1_g, c_ln1_b, xh_i);

  // ---- ecg path ----
  k_transpose_g<<<dim3(24, 64, 8), 256, 0, stream>>>(ecg, A, 2048, 768);
  k_ecg_fft<<<3072, 512, 0, stream>>>(A, FcT, gatev, twg, xtT);
  k_colstats_bf<<<dim3(16, 8), 256, 0, stream>>>(xtT, stats);
  k_transpose_ln<<<dim3(64, 24, 8), 256, 0, stream>>>(xtT, stats, e_ln1_g, e_ln1_b, xhat);

  // ---- combined FFN: text (128 by-blocks) + image (13 by-blocks) ----
  k_gemm_dual<0><<<dim3(6, 141), 256, 0, stream>>>(
      xhat, ew1b, e_b1, nullptr, h_t, 16384, 128,
      xh_i, cw1b, c_b1, nullptr, h_i, 1568);
  k_gemm_dual<1><<<dim3(6, 141), 256, 0, stream>>>(
      h_t, ew2b, e_b2, xhat, y_tb, 16384, 128,
      h_i, cw2b, c_b2, xh_i, y_ib, 1568);
  k_layernorm_dual<<<16384 + 1568, 256, 0, stream>>>(
      y_tb, e_ln2_g, e_ln2_b, out, 16384,
      y_ib, c_ln2_g, c_ln2_b, out + TXT);
}

// Round 13
// 450.503 us; speedup vs baseline: 1.0018x; 1.0018x over previous
//
#include <hip/hip_runtime.h>
#include <math.h>

namespace {

constexpr int B_ = 8;
constexpr int S_ = 2048;
constexpr int D_ = 768;
constexpr int N_ = 196;     // image spatial
constexpr int NF_ = 99;     // image freq bins
constexpr int NFREQ_ = 257;
constexpr int NSEG_ = 9;
constexpr int NBINS_ = NFREQ_ * NSEG_;  // 2313
constexpr int NW_ = D_ * D_;            // 589824
constexpr float TWOPI_ = 6.28318530717958647692f;

using bf16x8 = __attribute__((ext_vector_type(8))) short;
using f32x4  = __attribute__((ext_vector_type(4))) float;

__device__ __forceinline__ int rev9(int x) { return (int)(__brev((unsigned)x) >> 23); }
__device__ __forceinline__ int padz(int i) { return i + (i >> 4); }

__device__ __forceinline__ unsigned short f2bf(float x) {
  unsigned u = __float_as_uint(x);
  u = (u + 0x7FFFu + ((u >> 16) & 1u)) >> 16;
  return (unsigned short)u;
}
__device__ __forceinline__ float bf2f(unsigned short h) {
  return __uint_as_float(((unsigned)h) << 16);
}

// exact GELU via Abramowitz-Stegun 7.1.26 erf (|eps| <= 1.5e-7)
__device__ __forceinline__ float gelu_f(float v) {
  const float x = fabsf(v) * 0.70710678118654752440f;
  const float t = 1.0f / fmaf(0.3275911f, x, 1.0f);
  float p = fmaf(fmaf(fmaf(fmaf(1.061405429f, t, -1.453152027f), t, 1.421413741f),
                      t, -0.284496736f), t, 0.254829592f);
  const float e = __expf(-x * x);
  const float er = 1.0f - p * t * e;
  return 0.5f * v * (1.0f + ((v < 0.f) ? -er : er));
}

__device__ __forceinline__ void gload16(const void* g, void* l) {
  __builtin_amdgcn_global_load_lds((const __attribute__((address_space(1))) void*)g,
                                   (__attribute__((address_space(3))) void*)l, 16, 0, 0);
}

__device__ __forceinline__ float2 cmulf(float2 a, float2 b) {
  return make_float2(a.x * b.x - a.y * b.y, a.x * b.y + a.y * b.x);
}
__device__ __forceinline__ float2 cadd(float2 a, float2 b) {
  return make_float2(a.x + b.x, a.y + b.y);
}
__device__ __forceinline__ float2 csub(float2 a, float2 b) {
  return make_float2(a.x - b.x, a.y - b.y);
}

// ---------------- batched transpose (B,R,C) -> (B,C,R) ----------------
__global__ __launch_bounds__(256) void k_transpose_g(const float* __restrict__ src,
                                                     float* __restrict__ dst,
                                                     int R, int C) {
  __shared__ float tile[32][33];
  const int b = blockIdx.z;
  const int c0 = blockIdx.x * 32;
  const int r0 = blockIdx.y * 32;
  const int tx = threadIdx.x & 31, ty = threadIdx.x >> 5;
  for (int i = ty; i < 32; i += 8)
    tile[i][tx] = src[((size_t)b * R + r0 + i) * C + c0 + tx];
  __syncthreads();
  for (int i = ty; i < 32; i += 8)
    dst[((size_t)b * C + c0 + i) * R + r0 + tx] = tile[tx][i];
}

// ---- fused prep: weight bf16 conv (4 mats) + filter bank + twiddles ----
constexpr int PREP_W = (NW_ + 255) / 256;
constexpr int PREP_WALL = 4 * PREP_W;
constexpr int PREP_FC = (NBINS_ * D_ + 255) / 256;
__global__ __launch_bounds__(256) void k_prep(
    const float* __restrict__ w0, const float* __restrict__ w1,
    const float* __restrict__ w2, const float* __restrict__ w3,
    unsigned short* __restrict__ wbf, const float2* __restrict__ e2,
    float2* __restrict__ FcT, float2* __restrict__ twg) {
  const int bid = blockIdx.x;
  if (bid < PREP_WALL) {
    const int m = bid / PREP_W;
    const int i = (bid - m * PREP_W) * 256 + threadIdx.x;
    if (i >= NW_) return;
    const float* src = (m == 0) ? w0 : (m == 1) ? w1 : (m == 2) ? w2 : w3;
    wbf[(size_t)m * NW_ + i] = f2bf(src[i]);
  } else if (bid < PREP_WALL + PREP_FC) {
    const int o = (bid - PREP_WALL) * 256 + threadIdx.x;
    if (o >= NBINS_ * D_) return;
    const int d = o / NBINS_;
    const int r = o - d * NBINS_;
    const int f = r / NFREQ_;
    const int k = r - f * NFREQ_;
    const int s = k * 9 + f;
    const float2 a = e2[(size_t)s * D_ + d];
    const float2 b = e2[(size_t)(NBINS_ + s) * D_ + d];
    FcT[o] = make_float2(-(a.x + b.x), -(a.y + b.y));
  } else {
    const int i = (bid - PREP_WALL - PREP_FC) * 256 + threadIdx.x;
    if (i >= 511) return;
    const int v = i + 1;
    const int h = 1 << (31 - __clz(v));
    const int j = v - h;
    float sn, cs;
    sincosf((float)j * ((TWOPI_ * 0.5f) / (float)h), &sn, &cs);
    twg[i] = make_float2(cs, sn);
  }
}

// ---- image forward DFT + filter + gate partials ----
__global__ __launch_bounds__(256) void k_img_dft_f(
    const float* __restrict__ image, const float2* __restrict__ bank2,
    const float2* __restrict__ gsel2, float2* __restrict__ imgF,
    float* __restrict__ part) {
  const int fg = blockIdx.x;
  const int f0 = fg * 9;
  const int d = blockIdx.y * 256 + threadIdx.x;
  const int b = blockIdx.z;
  __shared__ float2 tws[9 * N_];
  for (int idx = threadIdx.x; idx < 9 * N_; idx += 256) {
    const int fi = idx / N_;
    const int t = idx - fi * N_;
    const int r = ((f0 + fi) * t) % N_;
    float sn, cs;
    sincosf(TWOPI_ * (float)r / (float)N_, &sn, &cs);
    tws[idx] = make_float2(cs, sn);
  }
  __syncthreads();
  float re[9] = {}, im[9] = {};
  const float* ip = image + (size_t)b * N_ * D_ + d;
  for (int t = 0; t < N_; ++t) {
    const float v = ip[(size_t)t * D_];
#pragma unroll
    for (int fi = 0; fi < 9; ++fi) {
      const float2 w = tws[fi * N_ + t];
      re[fi] = fmaf(v, w.x, re[fi]);
      im[fi] = fmaf(-v, w.y, im[fi]);
    }
  }
  const float sc = 1.0f / (196.0f * 99.0f);
  float gp = 0.f;
#pragma unroll
  for (int fi = 0; fi < 9; ++fi) {
    const int f = f0 + fi;
    const float pr = (re[fi] * re[fi] - im[fi] * im[fi]) * sc;
    const float pi2 = (2.f * re[fi] * im[fi]) * sc;
    const size_t fd = (size_t)f * D_ + d;
    const float2 c0 = bank2[fd];
    const float2 c1 = bank2[(size_t)NF_ * D_ + fd];
    const float fcr = -(c0.x + c1.x), fci = -(c0.y + c1.y);
    const float zr = pr * fcr - pi2 * fci;
    const float zi = pr * fci + pi2 * fcr;
    imgF[(size_t)(b * NF_ + f) * D_ + d] = make_float2(zr, zi);
    const float2 gw = gsel2[fd];
    gp += zr * gw.x - zi * gw.y;
  }
  part[((size_t)b * 11 + fg) * D_ + d] = gp;
}

// ---- gate matvec, folds 11 partials: gate[b][d0..d0+16) ----
__global__ __launch_bounds__(256) void k_gate_mm2(const float* __restrict__ part,
                                                  const float* __restrict__ W,
                                                  const float* __restrict__ bias,
                                                  float* __restrict__ gate) {
  __shared__ float row[8][D_];
  __shared__ float red[16][16][8];
  const int tid = threadIdx.x;
  const int d0 = blockIdx.x * 16;
  for (int i = tid; i < 8 * D_; i += 256) {
    const int b = i / D_, e = i - b * D_;
    float s = 0.f;
    for (int p = 0; p < 11; ++p) s += part[((size_t)b * 11 + p) * D_ + e];
    row[b][e] = s * (1.0f / 99.0f);
  }
  __syncthreads();
  const int dl = tid >> 4;
  const int ec = tid & 15;
  const float* w = W + (size_t)(d0 + dl) * D_ + ec * 48;
  float acc[8] = {};
  for (int e = 0; e < 48; e += 4) {
    const float4 wv = *reinterpret_cast<const float4*>(w + e);
    const int eg = ec * 48 + e;
#pragma unroll
    for (int b = 0; b < 8; ++b) {
      acc[b] = fmaf(row[b][eg], wv.x, acc[b]);
      acc[b] = fmaf(row[b][eg + 1], wv.y, acc[b]);
      acc[b] = fmaf(row[b][eg + 2], wv.z, acc[b]);
      acc[b] = fmaf(row[b][eg + 3], wv.w, acc[b]);
    }
  }
#pragma unroll
  for (int b = 0; b < 8; ++b) red[dl][ec][b] = acc[b];
  __syncthreads();
  if (tid < 128) {
    const int dl2 = tid >> 3, b = tid & 7;
    float s = bias[d0 + dl2];
    for (int c = 0; c < 16; ++c) s += red[dl2][c][b];
    gate[b * D_ + d0 + dl2] = s;
  }
}

// ---- image inverse DFT (ortho) + residual ----
__global__ __launch_bounds__(256) void k_img_idft(
    const float2* __restrict__ imgF, const float* __restrict__ image,
    float* __restrict__ xi) {
  const int t0 = blockIdx.x * 14;
  const int d = blockIdx.y * 256 + threadIdx.x;
  const int b = blockIdx.z;
  __shared__ float2 tws[14 * NF_];
  for (int idx = threadIdx.x; idx < 14 * NF_; idx += 256) {
    const int ti = idx / NF_;
    const int f = idx - ti * NF_;
    const int r = ((t0 + ti) * f) % N_;
    float sn, cs;
    sincosf(TWOPI_ * (float)r / (float)N_, &sn, &cs);
    tws[idx] = make_float2(cs, sn);
  }
  __syncthreads();
  const float2* zp = imgF + (size_t)b * NF_ * D_ + d;
  const float2 z0 = zp[0];
  const float2 zny = zp[(size_t)(NF_ - 1) * D_];
  float acc[14];
#pragma unroll
  for (int ti = 0; ti < 14; ++ti)
    acc[ti] = z0.x + (((t0 + ti) & 1) ? -zny.x : zny.x);
  for (int f = 1; f < NF_ - 1; ++f) {
    const float2 z = zp[(size_t)f * D_];
#pragma unroll
    for (int ti = 0; ti < 14; ++ti) {
      const float2 w = tws[ti * NF_ + f];
      acc[ti] += 2.f * (z.x * w.x - z.y * w.y);
    }
  }
#pragma unroll
  for (int ti = 0; ti < 14; ++ti) {
    const size_t idx = (size_t)(b * N_ + t0 + ti) * D_ + d;
    xi[idx] = acc[ti] * (1.0f / 14.0f) + image[idx];
  }
}

// ---------------- LayerNorm f32 in -> bf16 out ----------------
__global__ __launch_bounds__(256) void k_layernorm_f2b(const float* __restrict__ x,
                                                       const float* __restrict__ g,
                                                       const float* __restrict__ b,
                                                       unsigned short* __restrict__ out) {
  const int row = blockIdx.x;
  const int tid = threadIdx.x;
  const float* xr = x + (size_t)row * D_;
  const float v0 = xr[tid], v1 = xr[tid + 256], v2 = xr[tid + 512];
  float s = v0 + v1 + v2;
  float q = v0 * v0 + v1 * v1 + v2 * v2;
  __shared__ float red[8];
  for (int off = 32; off > 0; off >>= 1) {
    s += __shfl_down(s, off);
    q += __shfl_down(q, off);
  }
  if ((tid & 63) == 0) { red[tid >> 6] = s; red[4 + (tid >> 6)] = q; }
  __syncthreads();
  s = red[0] + red[1] + red[2] + red[3];
  q = red[4] + red[5] + red[6] + red[7];
  const float mean = s * (1.0f / 768.0f);
  const float var = q * (1.0f / 768.0f) - mean * mean;
  const float inv = rsqrtf(var + 1e-5f);
  unsigned short* orow = out + (size_t)row * D_;
  orow[tid]       = f2bf((v0 - mean) * inv * g[tid]       + b[tid]);
  orow[tid + 256] = f2bf((v1 - mean) * inv * g[tid + 256] + b[tid + 256]);
  orow[tid + 512] = f2bf((v2 - mean) * inv * g[tid + 512] + b[tid + 512]);
}

// ================= ecg fused FFT (radix-8, 512 thr, 2 signals/block) ===========
template <int H, int DIR, bool TRIV>
__device__ __forceinline__ void pass8(float2* z, int l,
                                      float2 wa, float2 wb, float2 wc) {
  asm volatile("s_waitcnt lgkmcnt(0)" ::: "memory");
  const float sg = (DIR < 0) ? -1.f : 1.f;
  const int base = (H == 1) ? (l << 3)
                 : (H == 8) ? (((l >> 3) << 6) | (l & 7))
                            : l;
  const float2 x0 = z[padz(base)],         x1 = z[padz(base + H)];
  const float2 x2 = z[padz(base + 2 * H)], x3 = z[padz(base + 3 * H)];
  const float2 x4 = z[padz(base + 4 * H)], x5 = z[padz(base + 5 * H)];
  const float2 x6 = z[padz(base + 6 * H)], x7 = z[padz(base + 7 * H)];
  const float2 WA = make_float2(wa.x, sg * wa.y);
  const float2 WB = make_float2(wb.x, sg * wb.y);
  const float2 WC = make_float2(wc.x, sg * wc.y);
  const float2 WBp = make_float2(-sg * WB.y, sg * WB.x);  // WB * W4
  float2 t, u;
  t = TRIV ? x1 : cmulf(x1, WA); const float2 A0 = cadd(x0, t), A1 = csub(x0, t);
  t = TRIV ? x3 : cmulf(x3, WA); const float2 A2 = cadd(x2, t), A3 = csub(x2, t);
  t = TRIV ? x5 : cmulf(x5, WA); const float2 A4 = cadd(x4, t), A5 = csub(x4, t);
  t = TRIV ? x7 : cmulf(x7, WA); const float2 A6 = cadd(x6, t), A7 = csub(x6, t);
  t = TRIV ? A2 : cmulf(A2, WB);
  u = TRIV ? make_float2(-sg * A3.y, sg * A3.x) : cmulf(A3, WBp);
  const float2 B0 = cadd(A0, t), B2 = csub(A0, t);
  const float2 B1 = cadd(A1, u), B3 = csub(A1, u);
  t = TRIV ? A6 : cmulf(A6, WB);
  u = TRIV ? make_float2(-sg * A7.y, sg * A7.x) : cmulf(A7, WBp);
  const float2 B4 = cadd(A4, t), B6 = csub(A4, t);
  const float2 B5 = cadd(A5, u), B7 = csub(A5, u);
  const float r_ = 0.70710678118654752440f;
  const float2 F1 = TRIV ? make_float2(r_, sg * r_)
                         : cmulf(WC, make_float2(r_, sg * r_));
  const float2 F2 = TRIV ? make_float2(0.f, sg)
                         : make_float2(-sg * WC.y, sg * WC.x);
  const float2 F3 = TRIV ? make_float2(-r_, sg * r_)
                         : cmulf(WC, make_float2(-r_, sg * r_));
  t = TRIV ? B4 : cmulf(B4, WC);
  z[padz(base)]         = cadd(B0, t);
  z[padz(base + 4 * H)] = csub(B0, t);
  t = cmulf(B5, F1);
  z[padz(base + H)]     = cadd(B1, t);
  z[padz(base + 5 * H)] = csub(B1, t);
  t = cmulf(B6, F2);
  z[padz(base + 2 * H)] = cadd(B2, t);
  z[padz(base + 6 * H)] = csub(B2, t);
  t = cmulf(B7, F3);
  z[padz(base + 3 * H)] = cadd(B3, t);
  z[padz(base + 7 * H)] = csub(B3, t);
}

template <int FA, int FB>
__device__ __forceinline__ void scatter_buf(float2* z, const float (&s)[8],
                                            float wlo, float whi, int rlo, int rhi) {
  constexpr int iAlo = (FA > 0) ? FA - 1 : 0;
  constexpr int iAhi = (FA < 8) ? FA : 0;
  constexpr int iBlo = (FB > 0) ? FB - 1 : 0;
  constexpr int iBhi = (FB >= 0 && FB < 8) ? FB : 0;
  const float aLo = (FA == 0) ? 0.f : s[iAlo] * wlo;
  const float aHi = (FA == 8) ? 0.f : s[iAhi] * whi;
  const float bLo = (FB <= 0) ? 0.f : s[iBlo] * wlo;
  const float bHi = (FB < 0 || FB == 8) ? 0.f : s[iBhi] * whi;
  z[rlo] = make_float2(aLo, bLo);
  z[rhi] = make_float2(aHi, bHi);
}

// A-part scaled by gA, B-part by gB
template <int FA, int FB>
__device__ __forceinline__ void filt_pack(const float2* z, int k, float gA, float gB,
                                          float2 cA, float2 cB,
                                          float2& Ck, float2& Cm) {
  const int q = (512 - k) & 511;
  const float2 Zk = z[padz(k)], Zq = z[padz(q)];
  const float sc = 0.5f / 256.f;
  const float ar = (Zk.x + Zq.x) * sc, ai = (Zk.y - Zq.y) * sc;
  float yar, yai, ybr = 0.f, ybi = 0.f;
  {
    const float pr = (ar * ar - ai * ai) * (1.f / 2313.f);
    const float pi = (2.f * ar * ai) * (1.f / 2313.f);
    yar = (pr * cA.x - pi * cA.y) * gA;
    yai = (pr * cA.y + pi * cA.x) * gA;
  }
  if (FB >= 0) {
    const float br = (Zk.y + Zq.y) * sc, bi = (Zq.x - Zk.x) * sc;
    const float pr = (br * br - bi * bi) * (1.f / 2313.f);
    const float pi = (2.f * br * bi) * (1.f / 2313.f);
    ybr = (pr * cB.x - pi * cB.y) * gB;
    ybi = (pr * cB.y + pi * cB.x) * gB;
  }
  if (k == 0 || k == 256) {
    Ck = make_float2(yar, ybr);
    Cm = Ck;
  } else {
    Ck = make_float2(yar - ybi, yai + ybr);
    Cm = make_float2(yar + ybi, ybr - yai);
  }
}

__global__ __launch_bounds__(512) void k_ecg_fft(
    const float* __restrict__ ecgT, const float2* __restrict__ FcT,
    const float* __restrict__ gate, const float2* __restrict__ twg,
    unsigned short* __restrict__ xtT) {
  const int bd = blockIdx.x;              // 0..3071
  const int b = bd / 384, d0 = bd - (bd / 384) * 384;
  const int tid = threadIdx.x;
  const int grp = tid >> 8;               // signal group 0/1
  const int lt = tid & 255;
  const int wid = tid >> 6;               // wave 0..7 <-> buffer
  const int l = tid & 63;
  const int d = d0 + grp * 384;
  const int myBD = b * 768 + d;

  __shared__ float2 z[8][544];            // 34.8 KB

  float s[8];
  const float* src = ecgT + (size_t)myBD * S_;
#pragma unroll
  for (int k = 0; k < 8; ++k) s[k] = src[k * 256 + lt];

  float2 ptw[6];
  ptw[0] = twg[7 + (l & 7)];
  ptw[1] = twg[15 + (l & 7)];
  ptw[2] = twg[31 + (l & 7)];
  ptw[3] = twg[63 + l];
  ptw[4] = twg[127 + l];
  ptw[5] = twg[255 + l];
  const float2 t8 = twg[255 + lt];
  const float c0 = t8.x;
  const float wlo = 0.5f - 0.5f * c0;
  const float whi = 0.5f + 0.5f * c0;
  const int rlo = padz(rev9(lt)), rhi = padz(rev9(lt + 256));

  const float gX = gate[b * 768 + d0];
  const float gY = gate[b * 768 + d0 + 384];
  const float gOwn = grp ? gY : gX;
  const float2* fc = FcT + (size_t)d * NBINS_;

  float accr[10];
#pragma unroll
  for (int i = 0; i < 10; ++i) accr[i] = 0.f;

  // ======== super A: frames (0,8),(1,2),(3,4),(5,6) of own signal ========
  const float2 cA0 = fc[0 * 257 + lt], cB0 = fc[8 * 257 + lt];
  const float2 cA1 = fc[1 * 257 + lt], cB1 = fc[2 * 257 + lt];
  const float2 cA2 = fc[3 * 257 + lt], cB2 = fc[4 * 257 + lt];
  const float2 cA3 = fc[5 * 257 + lt], cB3 = fc[6 * 257 + lt];
  float2* zg = z[grp * 4];
  scatter_buf<0, 8>(z[grp * 4 + 0], s, wlo, whi, rlo, rhi);
  scatter_buf<1, 2>(z[grp * 4 + 1], s, wlo, whi, rlo, rhi);
  scatter_buf<3, 4>(z[grp * 4 + 2], s, wlo, whi, rlo, rhi);
  scatter_buf<5, 6>(z[grp * 4 + 3], s, wlo, whi, rlo, rhi);
  __syncthreads();
  {  // forward FFT: wave w -> buffer w (all 8 busy)
    float2* zz = z[wid];
    pass8<1, -1, true>(zz, l, ptw[0], ptw[1], ptw[2]);
    pass8<8, -1, false>(zz, l, ptw[0], ptw[1], ptw[2]);
    pass8<64, -1, false>(zz, l, ptw[3], ptw[4], ptw[5]);
  }
  __syncthreads();
  float2 Ck0, Cm0, Ck1, Cm1, Ck2, Cm2, Ck3, Cm3;
  float2 Cn0, Cn1, Cn2, Cn3, dum;
  filt_pack<0, 8>(z[grp * 4 + 0], lt, gOwn, gOwn, cA0, cB0, Ck0, Cm0);
  filt_pack<1, 2>(z[grp * 4 + 1], lt, gOwn, gOwn, cA1, cB1, Ck1, Cm1);
  filt_pack<3, 4>(z[grp * 4 + 2], lt, gOwn, gOwn, cA2, cB2, Ck2, Cm2);
  filt_pack<5, 6>(z[grp * 4 + 3], lt, gOwn, gOwn, cA3, cB3, Ck3, Cm3);
  if (lt == 0) {
    float2 nA, nB;
    nA = fc[0 * 257 + 256]; nB = fc[8 * 257 + 256];
    filt_pack<0, 8>(z[grp * 4 + 0], 256, gOwn, gOwn, nA, nB, Cn0, dum);
    nA = fc[1 * 257 + 256]; nB = fc[2 * 257 + 256];
    filt_pack<1, 2>(z[grp * 4 + 1], 256, gOwn, gOwn, nA, nB, Cn1, dum);
    nA = fc[3 * 257 + 256]; nB = fc[4 * 257 + 256];
    filt_pack<3, 4>(z[grp * 4 + 2], 256, gOwn, gOwn, nA, nB, Cn2, dum);
    nA = fc[5 * 257 + 256]; nB = fc[6 * 257 + 256];
    filt_pack<5, 6>(z[grp * 4 + 3], 256, gOwn, gOwn, nA, nB, Cn3, dum);
  }
  __syncthreads();
  {
    zg[0 * 544 + rlo] = Ck0; zg[1 * 544 + rlo] = Ck1;
    zg[2 * 544 + rlo] = Ck2; zg[3 * 544 + rlo] = Ck3;
    if (lt == 0) {
      zg[0 * 544 + padz(1)] = Cn0; zg[1 * 544 + padz(1)] = Cn1;
      zg[2 * 544 + padz(1)] = Cn2; zg[3 * 544 + padz(1)] = Cn3;
    } else {
      const int rm = padz(rev9(512 - lt));
      zg[0 * 544 + rm] = Cm0; zg[1 * 544 + rm] = Cm1;
      zg[2 * 544 + rm] = Cm2; zg[3 * 544 + rm] = Cm3;
    }
  }
  __syncthreads();
  {  // inverse FFT
    float2* zz = z[wid];
    pass8<1, 1, true>(zz, l, ptw[0], ptw[1], ptw[2]);
    pass8<8, 1, false>(zz, l, ptw[0], ptw[1], ptw[2]);
    pass8<64, 1, false>(zz, l, ptw[3], ptw[4], ptw[5]);
  }
  __syncthreads();
  {  // overlap-add (own group's 4 buffers)
    float2 vLo, vHi;
    vLo = zg[0 * 544 + padz(lt)]; vHi = zg[0 * 544 + padz(lt + 256)];
    accr[0] += 0.5f * wlo * vLo.x; accr[1] += 0.5f * whi * vHi.x;
    accr[8] += 0.5f * wlo * vLo.y; accr[9] += 0.5f * whi * vHi.y;
    vLo = zg[1 * 544 + padz(lt)]; vHi = zg[1 * 544 + padz(lt + 256)];
    accr[1] += 0.5f * wlo * vLo.x; accr[2] += 0.5f * whi * vHi.x;
    accr[2] += 0.5f * wlo * vLo.y; accr[3] += 0.5f * whi * vHi.y;
    vLo = zg[2 * 544 + padz(lt)]; vHi = zg[2 * 544 + padz(lt + 256)];
    accr[3] += 0.5f * wlo * vLo.x; accr[4] += 0.5f * whi * vHi.x;
    accr[4] += 0.5f * wlo * vLo.y; accr[5] += 0.5f * whi * vHi.y;
    vLo = zg[3 * 544 + padz(lt)]; vHi = zg[3 * 544 + padz(lt + 256)];
    accr[5] += 0.5f * wlo * vLo.x; accr[6] += 0.5f * whi * vHi.x;
    accr[6] += 0.5f * wlo * vLo.y; accr[7] += 0.5f * whi * vHi.y;
  }
  __syncthreads();  // z[0] reads done before super C overwrites

  // ======== super C: (X7 re, Y7 im) in buffer 0 ========
  {
    float* z0f = (float*)z[0];
    z0f[2 * rlo + grp] = s[6] * wlo;   // frame 7 lo half
    z0f[2 * rhi + grp] = s[7] * whi;   // frame 7 hi half
  }
  __syncthreads();
  if (wid == 0) {
    pass8<1, -1, true>(z[0], l, ptw[0], ptw[1], ptw[2]);
    pass8<8, -1, false>(z[0], l, ptw[0], ptw[1], ptw[2]);
    pass8<64, -1, false>(z[0], l, ptw[3], ptw[4], ptw[5]);
  }
  __syncthreads();
  float2 CkC, CmC, CnC;
  if (grp == 0) {
    const float2* fcY = FcT + (size_t)(d0 + 384) * NBINS_;
    const float2 cA = fc[7 * 257 + lt];
    const float2 cB = fcY[7 * 257 + lt];
    filt_pack<7, 7>(z[0], lt, gX, gY, cA, cB, CkC, CmC);
    if (lt == 0) {
      const float2 nA = fc[7 * 257 + 256];
      const float2 nB = fcY[7 * 257 + 256];
      filt_pack<7, 7>(z[0], 256, gX, gY, nA, nB, CnC, dum);
    }
  }
  __syncthreads();
  if (grp == 0) {
    z[0][rlo] = CkC;
    if (lt == 0) z[0][padz(1)] = CnC;
    else z[0][padz(rev9(512 - lt))] = CmC;
  }
  __syncthreads();
  if (wid == 0) {
    pass8<1, 1, true>(z[0], l, ptw[0], ptw[1], ptw[2]);
    pass8<8, 1, false>(z[0], l, ptw[0], ptw[1], ptw[2]);
    pass8<64, 1, false>(z[0], l, ptw[3], ptw[4], ptw[5]);
  }
  __syncthreads();
  {
    const float2 vLo = z[0][padz(lt)], vHi = z[0][padz(lt + 256)];
    const float xlo = grp ? vLo.y : vLo.x;
    const float xhi = grp ? vHi.y : vHi.x;
    accr[7] += 0.5f * wlo * xlo;
    accr[8] += 0.5f * whi * xhi;
  }

  // ---- output: own signal ----
  const float rinv = 1.0f / (0.5f + 0.5f * c0 * c0);
  unsigned short* dst = xtT + (size_t)myBD * S_;
#pragma unroll
  for (int i2 = 0; i2 < 8; ++i2)
    dst[i2 * 256 + lt] = f2bf(accr[i2 + 1] * rinv + s[i2]);
}

// ---- per-(b,t) LN stats over d, reading bf16 xtT[b][d][t] as uint pairs ----
__global__ __launch_bounds__(256) void k_colstats_bf(const unsigned short* __restrict__ xtT,
                                                     float2* __restrict__ stats) {
  const int b = blockIdx.y;
  const int t0 = blockIdx.x * 128;
  const int tx = threadIdx.x & 63;
  const int ty = threadIdx.x >> 6;
  float s0 = 0.f, q0 = 0.f, s1 = 0.f, q1 = 0.f;
  const unsigned int* base = (const unsigned int*)(xtT + (size_t)b * D_ * S_);
  for (int dd = ty; dd < D_; dd += 4) {
    const unsigned int u = base[(size_t)dd * (S_ / 2) + (t0 >> 1) + tx];
    const float v0 = bf2f((unsigned short)(u & 0xffffu));
    const float v1 = bf2f((unsigned short)(u >> 16));
    s0 += v0; q0 = fmaf(v0, v0, q0);
    s1 += v1; q1 = fmaf(v1, v1, q1);
  }
  __shared__ float sh[4][64][4];
  sh[ty][tx][0] = s0; sh[ty][tx][1] = q0; sh[ty][tx][2] = s1; sh[ty][tx][3] = q1;
  __syncthreads();
  if (ty == 0) {
    s0 = sh[0][tx][0] + sh[1][tx][0] + sh[2][tx][0] + sh[3][tx][0];
    q0 = sh[0][tx][1] + sh[1][tx][1] + sh[2][tx][1] + sh[3][tx][1];
    s1 = sh[0][tx][2] + sh[1][tx][2] + sh[2][tx][2] + sh[3][tx][2];
    q1 = sh[0][tx][3] + sh[1][tx][3] + sh[2][tx][3] + sh[3][tx][3];
    stats[(size_t)b * S_ + t0 + 2 * tx]     = make_float2(s0, q0);
    stats[(size_t)b * S_ + t0 + 2 * tx + 1] = make_float2(s1, q1);
  }
}

// ---- transpose + LN apply, bf16 in -> bf16 out ----
__global__ __launch_bounds__(256) void k_transpose_ln(
    const unsigned short* __restrict__ xtT, const float2* __restrict__ stats,
    const float* __restrict__ g, const float* __restrict__ bia,
    unsigned short* __restrict__ xhat) {
  __shared__ float tile[32][33];
  const int b = blockIdx.z;
  const int t0 = blockIdx.x * 32;
  const int d0 = blockIdx.y * 32;
  const int tx = threadIdx.x & 31, ty = threadIdx.x >> 5;
  for (int i = ty; i < 32; i += 8)
    tile[i][tx] = bf2f(xtT[((size_t)b * D_ + d0 + i) * S_ + t0 + tx]);
  __syncthreads();
  const float gv = g[d0 + tx], bv = bia[d0 + tx];
  for (int i = ty; i < 32; i += 8) {
    const float2 st = stats[(size_t)b * S_ + t0 + i];
    const float mean = st.x * (1.0f / 768.0f);
    const float var = st.y * (1.0f / 768.0f) - mean * mean;
    const float inv = rsqrtf(var + 1e-5f);
    xhat[((size_t)b * S_ + t0 + i) * D_ + d0 + tx] =
        f2bf((tile[tx][i] - mean) * inv * gv + bv);
  }
}

// ---- dual-segment LayerNorm, bf16 in -> f32 out ----
__global__ __launch_bounds__(256) void k_layernorm_dual(
    const unsigned short* __restrict__ x1, const float* __restrict__ g1,
    const float* __restrict__ b1, float* __restrict__ o1, int n1,
    const unsigned short* __restrict__ x2, const float* __restrict__ g2,
    const float* __restrict__ b2, float* __restrict__ o2) {
  int row = blockIdx.x;
  const unsigned short* x; const float *g, *b; float* o;
  if (row < n1) { x = x1; g = g1; b = b1; o = o1; }
  else { row -= n1; x = x2; g = g2; b = b2; o = o2; }
  const int tid = threadIdx.x;
  const unsigned short* xr = x + (size_t)row * D_;
  const float v0 = bf2f(xr[tid]), v1 = bf2f(xr[tid + 256]), v2 = bf2f(xr[tid + 512]);
  float s = v0 + v1 + v2;
  float q = v0 * v0 + v1 * v1 + v2 * v2;
  __shared__ float red[8];
  for (int off = 32; off > 0; off >>= 1) {
    s += __shfl_down(s, off);
    q += __shfl_down(q, off);
  }
  if ((tid & 63) == 0) { red[tid >> 6] = s; red[4 + (tid >> 6)] = q; }
  __syncthreads();
  s = red[0] + red[1] + red[2] + red[3];
  q = red[4] + red[5] + red[6] + red[7];
  const float mean = s * (1.0f / 768.0f);
  const float var = q * (1.0f / 768.0f) - mean * mean;
  const float inv = rsqrtf(var + 1e-5f);
  float* orow = o + (size_t)row * D_;
  orow[tid]       = (v0 - mean) * inv * g[tid]       + b[tid];
  orow[tid + 256] = (v1 - mean) * inv * g[tid + 256] + b[tid + 256];
  orow[tid + 512] = (v2 - mean) * inv * g[tid + 512] + b[tid + 512];
}

// ---------- dual-segment MFMA GEMM, double-buffered pipeline ----------
// MODE 0: exact GELU -> bf16 ; MODE 1: +resid(bf16) -> bf16
template <int MODE>
__global__ __launch_bounds__(256) void k_gemm_dual(
    const unsigned short* __restrict__ A1, const unsigned short* __restrict__ W1,
    const float* __restrict__ b1, const unsigned short* __restrict__ r1,
    unsigned short* __restrict__ o1, int M1, int nby1,
    const unsigned short* __restrict__ A2, const unsigned short* __restrict__ W2,
    const float* __restrict__ b2, const unsigned short* __restrict__ r2,
    unsigned short* __restrict__ o2, int M2) {
  __shared__ unsigned short Asm[2][128 * 64];
  __shared__ unsigned short Bsm[2][128 * 64];
  const int tid = threadIdx.x;
  const int lane = tid & 63, wid = tid >> 6;
  const int wr = wid >> 1, wc = wid & 1;
  int bx, by;
  {
    const int nwg = gridDim.x * gridDim.y;
    const int bid = blockIdx.y * gridDim.x + blockIdx.x;
    const int xcd = bid & 7, lin = bid >> 3;
    const int qq = nwg >> 3, rr = nwg & 7;
    const int nbid = (xcd < rr) ? xcd * (qq + 1) + lin
                                : rr * (qq + 1) + (xcd - rr) * qq + lin;
    bx = nbid % gridDim.x;
    by = nbid / gridDim.x;
  }
  const unsigned short* Abf; const unsigned short* Wbf; const float* bias;
  const unsigned short* resid; unsigned short* outb; int M;
  if (by < nby1) { Abf = A1; Wbf = W1; bias = b1; resid = r1; outb = o1; M = M1; }
  else { by -= nby1; Abf = A2; Wbf = W2; bias = b2; resid = r2; outb = o2; M = M2; }
  const int n0 = bx * 128, m0 = by * 128;

  auto STAGE = [&](int buf, int kt) {
    const int k0 = kt * 64;
#pragma unroll
    for (int i = 0; i < 4; ++i) {
      const int c = tid + 256 * i;
      const int row = c >> 3, sl = c & 7;
      const int gsl = sl ^ (row & 7);
      gload16(Abf + (size_t)(m0 + row) * 768 + k0 + gsl * 8, &Asm[buf][c * 8]);
      gload16(Wbf + (size_t)(n0 + row) * 768 + k0 + gsl * 8, &Bsm[buf][c * 8]);
    }
  };

  f32x4 acc[4][4] = {};
  STAGE(0, 0);
  for (int kt = 0; kt < 12; ++kt) {
    const int cur = kt & 1;
    if (kt < 11) {
      STAGE(cur ^ 1, kt + 1);
      asm volatile("s_waitcnt vmcnt(8)" ::: "memory");
    } else {
      asm volatile("s_waitcnt vmcnt(0)" ::: "memory");
    }
    __builtin_amdgcn_sched_barrier(0);
    __builtin_amdgcn_s_barrier();
#pragma unroll
    for (int ks = 0; ks < 2; ++ks) {
      bf16x8 af[4], bfv[4];
#pragma unroll
      for (int mi = 0; mi < 4; ++mi) {
        const int row = wr * 64 + mi * 16 + (lane & 15);
        const int sl = (ks * 4 + (lane >> 4)) ^ (row & 7);
        af[mi] = *(const bf16x8*)((const char*)Asm[cur] + row * 128 + sl * 16);
      }
#pragma unroll
      for (int ni = 0; ni < 4; ++ni) {
        const int row = wc * 64 + ni * 16 + (lane & 15);
        const int sl = (ks * 4 + (lane >> 4)) ^ (row & 7);
        bfv[ni] = *(const bf16x8*)((const char*)Bsm[cur] + row * 128 + sl * 16);
      }
#pragma unroll
      for (int mi = 0; mi < 4; ++mi)
#pragma unroll
        for (int ni = 0; ni < 4; ++ni)
          acc[mi][ni] = __builtin_amdgcn_mfma_f32_16x16x32_bf16(af[mi], bfv[ni],
                                                                acc[mi][ni], 0, 0, 0);
    }
    __builtin_amdgcn_sched_barrier(0);
    __builtin_amdgcn_s_barrier();
  }
#pragma unroll
  for (int mi = 0; mi < 4; ++mi) {
#pragma unroll
    for (int ni = 0; ni < 4; ++ni) {
      const int col = n0 + wc * 64 + ni * 16 + (lane & 15);
#pragma unroll
      for (int e = 0; e < 4; ++e) {
        const int row = m0 + wr * 64 + mi * 16 + (lane >> 4) * 4 + e;
        if (row >= M) continue;
        float v = acc[mi][ni][e] + bias[col];
        if (MODE == 0) {
          v = gelu_f(v);
        } else {
          v += bf2f(resid[(size_t)row * 768 + col]);
        }
        outb[(size_t)row * 768 + col] = f2bf(v);
      }
    }
  }
}

}  // namespace

extern "C" void kernel_launch(void* const* d_in, const int* in_sizes, int n_in,
                              void* d_out, int out_size, void* d_ws, size_t ws_size,
                              hipStream_t stream) {
  (void)in_sizes; (void)n_in; (void)out_size; (void)ws_size;
  const float* ecg     = (const float*)d_in[0];
  const float* image   = (const float*)d_in[1];
  const float* ebank   = (const float*)d_in[2];
  const float* cbank   = (const float*)d_in[3];
  const float* gsel    = (const float*)d_in[4];
  const float* gw      = (const float*)d_in[5];
  const float* gb      = (const float*)d_in[6];
  const float* e_ln1_g = (const float*)d_in[7];
  const float* e_ln1_b = (const float*)d_in[8];
  const float* e_w1    = (const float*)d_in[9];
  const float* e_b1    = (const float*)d_in[10];
  const float* e_w2    = (const float*)d_in[11];
  const float* e_b2    = (const float*)d_in[12];
  const float* e_ln2_g = (const float*)d_in[13];
  const float* e_ln2_b = (const float*)d_in[14];
  const float* c_ln1_g = (const float*)d_in[15];
  const float* c_ln1_b = (const float*)d_in[16];
  const float* c_w1    = (const float*)d_in[17];
  const float* c_b1    = (const float*)d_in[18];
  const float* c_w2    = (const float*)d_in[19];
  const float* c_b2    = (const float*)d_in[20];
  const float* c_ln2_g = (const float*)d_in[21];
  const float* c_ln2_b = (const float*)d_in[22];

  float* out = (float*)d_out;
  float* ws = (float*)d_ws;

  constexpr size_t TXT = (size_t)8 * 2048 * 768;   // 12,582,912 floats
  constexpr size_t IMG = (size_t)8 * 196 * 768;    // 1,204,224 elems

  // ws layout: A | Bb | wbf | gatev | stats | gpart | twg
  float* A  = ws;
  float* Bb = A + TXT;
  unsigned short* wbf = (unsigned short*)(Bb + TXT);
  unsigned short* ew1b = wbf;
  unsigned short* ew2b = wbf + NW_;
  unsigned short* cw1b = wbf + 2 * NW_;
  unsigned short* cw2b = wbf + 3 * NW_;
  float* gatev = (float*)(wbf + 4 * (size_t)NW_);
  float2* stats = (float2*)(gatev + 8 * 768);
  float* gpart = (float*)(stats + 8 * 2048);   // 8*11*768 floats
  float2* twg = (float2*)(gpart + 8 * 11 * 768);

  float2* FcT = (float2*)out;  // parked in d_out (dead before final LN)

  // text buffers: A = xhat (first half, bf16) | y_tb (second half, bf16)
  unsigned short* xhat = (unsigned short*)A;
  unsigned short* y_tb = (unsigned short*)A + TXT;
  // Bb first half: xtT then h_t (bf16); second half: image scratch
  unsigned short* xtT = (unsigned short*)Bb;
  unsigned short* h_t = (unsigned short*)Bb;
  float* Bb2 = Bb + TXT / 2;
  float2* imgF = (float2*)Bb2;                               // 1,216,512 floats
  float* xi = Bb2 + 1216512;                                 // 1,204,224 floats
  unsigned short* xh_i = (unsigned short*)(xi + IMG);        // bf16 LN1 / resid
  unsigned short* h_i  = xh_i + IMG;
  unsigned short* y_ib = h_i + IMG;

  // ---- one-time prep (fused) ----
  k_prep<<<PREP_WALL + PREP_FC + 2, 256, 0, stream>>>(
      e_w1, e_w2, c_w1, c_w2, wbf, (const float2*)ebank, FcT, twg);

  // ---- image path front (produces gate + xh_i) ----
  k_img_dft_f<<<dim3(11, 3, 8), 256, 0, stream>>>(image, (const float2*)cbank,
                                                  (const float2*)gsel, imgF, gpart);
  k_gate_mm2<<<48, 256, 0, stream>>>(gpart, gw, gb, gatev);
  k_img_idft<<<dim3(14, 3, 8), 256, 0, stream>>>(imgF, image, xi);
  k_layernorm_f2b<<<1568, 256, 0, stream>>>(xi, c_ln1_g, c_ln1_b, xh_i);

  // ---- ecg path ----
  k_transpose_g<<<dim3(24, 64, 8), 256, 0, stream>>>(ecg, A, 2048, 768);
  k_ecg_fft<<<3072, 512, 0, stream>>>(A, FcT, gatev, twg, xtT);
  k_colstats_bf<<<dim3(16, 8), 256, 0, stream>>>(xtT, stats);
  k_transpose_ln<<<dim3(64, 24, 8), 256, 0, stream>>>(xtT, stats, e_ln1_g, e_ln1_b, xhat);

  // ---- combined FFN: text (128 by-blocks) + image (13 by-blocks) ----
  k_gemm_dual<0><<<dim3(6, 141), 256, 0, stream>>>(
      xhat, ew1b, e_b1, nullptr, h_t, 16384, 128,
      xh_i, cw1b, c_b1, nullptr, h_i, 1568);
  k_gemm_dual<1><<<dim3(6, 141), 256, 0, stream>>>(
      h_t, ew2b, e_b2, xhat, y_tb, 16384, 128,
      h_i, cw2b, c_b2, xh_i, y_ib, 1568);
  k_layernorm_dual<<<16384 + 1568, 256, 0, stream>>>(
      y_tb, e_ln2_g, e_ln2_b, out, 16384,
      y_ib, c_ln2_g, c_ln2_b, out + TXT);
}

// Round 14
// 449.145 us; speedup vs baseline: 1.0048x; 1.0030x over previous
//
#include <hip/hip_runtime.h>
#include <math.h>

namespace {

constexpr int B_ = 8;
constexpr int S_ = 2048;
constexpr int D_ = 768;
constexpr int N_ = 196;     // image spatial
constexpr int NF_ = 99;     // image freq bins
constexpr int NFREQ_ = 257;
constexpr int NSEG_ = 9;
constexpr int NBINS_ = NFREQ_ * NSEG_;  // 2313
constexpr int NW_ = D_ * D_;            // 589824
constexpr float TWOPI_ = 6.28318530717958647692f;

using bf16x8 = __attribute__((ext_vector_type(8))) short;
using f32x4  = __attribute__((ext_vector_type(4))) float;

__device__ __forceinline__ int rev9(int x) { return (int)(__brev((unsigned)x) >> 23); }
__device__ __forceinline__ int padz(int i) { return i + (i >> 4); }

__device__ __forceinline__ unsigned short f2bf(float x) {
  unsigned u = __float_as_uint(x);
  u = (u + 0x7FFFu + ((u >> 16) & 1u)) >> 16;
  return (unsigned short)u;
}
__device__ __forceinline__ float bf2f(unsigned short h) {
  return __uint_as_float(((unsigned)h) << 16);
}

// exact GELU via Abramowitz-Stegun 7.1.26 erf (|eps| <= 1.5e-7)
__device__ __forceinline__ float gelu_f(float v) {
  const float x = fabsf(v) * 0.70710678118654752440f;
  const float t = 1.0f / fmaf(0.3275911f, x, 1.0f);
  float p = fmaf(fmaf(fmaf(fmaf(1.061405429f, t, -1.453152027f), t, 1.421413741f),
                      t, -0.284496736f), t, 0.254829592f);
  const float e = __expf(-x * x);
  const float er = 1.0f - p * t * e;
  return 0.5f * v * (1.0f + ((v < 0.f) ? -er : er));
}

__device__ __forceinline__ void gload16(const void* g, void* l) {
  __builtin_amdgcn_global_load_lds((const __attribute__((address_space(1))) void*)g,
                                   (__attribute__((address_space(3))) void*)l, 16, 0, 0);
}

__device__ __forceinline__ float2 cmulf(float2 a, float2 b) {
  return make_float2(a.x * b.x - a.y * b.y, a.x * b.y + a.y * b.x);
}
__device__ __forceinline__ float2 cadd(float2 a, float2 b) {
  return make_float2(a.x + b.x, a.y + b.y);
}
__device__ __forceinline__ float2 csub(float2 a, float2 b) {
  return make_float2(a.x - b.x, a.y - b.y);
}

// ---------------- batched transpose (B,R,C) -> (B,C,R) ----------------
__global__ __launch_bounds__(256) void k_transpose_g(const float* __restrict__ src,
                                                     float* __restrict__ dst,
                                                     int R, int C) {
  __shared__ float tile[32][33];
  const int b = blockIdx.z;
  const int c0 = blockIdx.x * 32;
  const int r0 = blockIdx.y * 32;
  const int tx = threadIdx.x & 31, ty = threadIdx.x >> 5;
  for (int i = ty; i < 32; i += 8)
    tile[i][tx] = src[((size_t)b * R + r0 + i) * C + c0 + tx];
  __syncthreads();
  for (int i = ty; i < 32; i += 8)
    dst[((size_t)b * C + c0 + i) * R + r0 + tx] = tile[tx][i];
}

// ---- fused prep: weight bf16 conv (4 mats) + filter bank + twiddles ----
constexpr int PREP_W = (NW_ + 255) / 256;
constexpr int PREP_WALL = 4 * PREP_W;
constexpr int PREP_FC = (NBINS_ * D_ + 255) / 256;
__global__ __launch_bounds__(256) void k_prep(
    const float* __restrict__ w0, const float* __restrict__ w1,
    const float* __restrict__ w2, const float* __restrict__ w3,
    unsigned short* __restrict__ wbf, const float2* __restrict__ e2,
    float2* __restrict__ FcT, float2* __restrict__ twg) {
  const int bid = blockIdx.x;
  if (bid < PREP_WALL) {
    const int m = bid / PREP_W;
    const int i = (bid - m * PREP_W) * 256 + threadIdx.x;
    if (i >= NW_) return;
    const float* src = (m == 0) ? w0 : (m == 1) ? w1 : (m == 2) ? w2 : w3;
    wbf[(size_t)m * NW_ + i] = f2bf(src[i]);
  } else if (bid < PREP_WALL + PREP_FC) {
    const int o = (bid - PREP_WALL) * 256 + threadIdx.x;
    if (o >= NBINS_ * D_) return;
    const int d = o / NBINS_;
    const int r = o - d * NBINS_;
    const int f = r / NFREQ_;
    const int k = r - f * NFREQ_;
    const int s = k * 9 + f;
    const float2 a = e2[(size_t)s * D_ + d];
    const float2 b = e2[(size_t)(NBINS_ + s) * D_ + d];
    FcT[o] = make_float2(-(a.x + b.x), -(a.y + b.y));
  } else {
    const int i = (bid - PREP_WALL - PREP_FC) * 256 + threadIdx.x;
    if (i >= 511) return;
    const int v = i + 1;
    const int h = 1 << (31 - __clz(v));
    const int j = v - h;
    float sn, cs;
    sincosf((float)j * ((TWOPI_ * 0.5f) / (float)h), &sn, &cs);
    twg[i] = make_float2(cs, sn);
  }
}

// ---- image forward DFT + filter + gate partials ----
__global__ __launch_bounds__(256) void k_img_dft_f(
    const float* __restrict__ image, const float2* __restrict__ bank2,
    const float2* __restrict__ gsel2, float2* __restrict__ imgF,
    float* __restrict__ part) {
  const int fg = blockIdx.x;
  const int f0 = fg * 9;
  const int d = blockIdx.y * 256 + threadIdx.x;
  const int b = blockIdx.z;
  __shared__ float2 tws[9 * N_];
  for (int idx = threadIdx.x; idx < 9 * N_; idx += 256) {
    const int fi = idx / N_;
    const int t = idx - fi * N_;
    const int r = ((f0 + fi) * t) % N_;
    float sn, cs;
    sincosf(TWOPI_ * (float)r / (float)N_, &sn, &cs);
    tws[idx] = make_float2(cs, sn);
  }
  __syncthreads();
  float re[9] = {}, im[9] = {};
  const float* ip = image + (size_t)b * N_ * D_ + d;
  for (int t = 0; t < N_; ++t) {
    const float v = ip[(size_t)t * D_];
#pragma unroll
    for (int fi = 0; fi < 9; ++fi) {
      const float2 w = tws[fi * N_ + t];
      re[fi] = fmaf(v, w.x, re[fi]);
      im[fi] = fmaf(-v, w.y, im[fi]);
    }
  }
  const float sc = 1.0f / (196.0f * 99.0f);
  float gp = 0.f;
#pragma unroll
  for (int fi = 0; fi < 9; ++fi) {
    const int f = f0 + fi;
    const float pr = (re[fi] * re[fi] - im[fi] * im[fi]) * sc;
    const float pi2 = (2.f * re[fi] * im[fi]) * sc;
    const size_t fd = (size_t)f * D_ + d;
    const float2 c0 = bank2[fd];
    const float2 c1 = bank2[(size_t)NF_ * D_ + fd];
    const float fcr = -(c0.x + c1.x), fci = -(c0.y + c1.y);
    const float zr = pr * fcr - pi2 * fci;
    const float zi = pr * fci + pi2 * fcr;
    imgF[(size_t)(b * NF_ + f) * D_ + d] = make_float2(zr, zi);
    const float2 gw = gsel2[fd];
    gp += zr * gw.x - zi * gw.y;
  }
  part[((size_t)b * 11 + fg) * D_ + d] = gp;
}

// ---- gate matvec, folds 11 partials: gate[b][d0..d0+16) ----
__global__ __launch_bounds__(256) void k_gate_mm2(const float* __restrict__ part,
                                                  const float* __restrict__ W,
                                                  const float* __restrict__ bias,
                                                  float* __restrict__ gate) {
  __shared__ float row[8][D_];
  __shared__ float red[16][16][8];
  const int tid = threadIdx.x;
  const int d0 = blockIdx.x * 16;
  for (int i = tid; i < 8 * D_; i += 256) {
    const int b = i / D_, e = i - b * D_;
    float s = 0.f;
    for (int p = 0; p < 11; ++p) s += part[((size_t)b * 11 + p) * D_ + e];
    row[b][e] = s * (1.0f / 99.0f);
  }
  __syncthreads();
  const int dl = tid >> 4;
  const int ec = tid & 15;
  const float* w = W + (size_t)(d0 + dl) * D_ + ec * 48;
  float acc[8] = {};
  for (int e = 0; e < 48; e += 4) {
    const float4 wv = *reinterpret_cast<const float4*>(w + e);
    const int eg = ec * 48 + e;
#pragma unroll
    for (int b = 0; b < 8; ++b) {
      acc[b] = fmaf(row[b][eg], wv.x, acc[b]);
      acc[b] = fmaf(row[b][eg + 1], wv.y, acc[b]);
      acc[b] = fmaf(row[b][eg + 2], wv.z, acc[b]);
      acc[b] = fmaf(row[b][eg + 3], wv.w, acc[b]);
    }
  }
#pragma unroll
  for (int b = 0; b < 8; ++b) red[dl][ec][b] = acc[b];
  __syncthreads();
  if (tid < 128) {
    const int dl2 = tid >> 3, b = tid & 7;
    float s = bias[d0 + dl2];
    for (int c = 0; c < 16; ++c) s += red[dl2][c][b];
    gate[b * D_ + d0 + dl2] = s;
  }
}

// ---- image inverse DFT (ortho) + residual ----
__global__ __launch_bounds__(256) void k_img_idft(
    const float2* __restrict__ imgF, const float* __restrict__ image,
    float* __restrict__ xi) {
  const int t0 = blockIdx.x * 14;
  const int d = blockIdx.y * 256 + threadIdx.x;
  const int b = blockIdx.z;
  __shared__ float2 tws[14 * NF_];
  for (int idx = threadIdx.x; idx < 14 * NF_; idx += 256) {
    const int ti = idx / NF_;
    const int f = idx - ti * NF_;
    const int r = ((t0 + ti) * f) % N_;
    float sn, cs;
    sincosf(TWOPI_ * (float)r / (float)N_, &sn, &cs);
    tws[idx] = make_float2(cs, sn);
  }
  __syncthreads();
  const float2* zp = imgF + (size_t)b * NF_ * D_ + d;
  const float2 z0 = zp[0];
  const float2 zny = zp[(size_t)(NF_ - 1) * D_];
  float acc[14];
#pragma unroll
  for (int ti = 0; ti < 14; ++ti)
    acc[ti] = z0.x + (((t0 + ti) & 1) ? -zny.x : zny.x);
  for (int f = 1; f < NF_ - 1; ++f) {
    const float2 z = zp[(size_t)f * D_];
#pragma unroll
    for (int ti = 0; ti < 14; ++ti) {
      const float2 w = tws[ti * NF_ + f];
      acc[ti] += 2.f * (z.x * w.x - z.y * w.y);
    }
  }
#pragma unroll
  for (int ti = 0; ti < 14; ++ti) {
    const size_t idx = (size_t)(b * N_ + t0 + ti) * D_ + d;
    xi[idx] = acc[ti] * (1.0f / 14.0f) + image[idx];
  }
}

// ---------------- LayerNorm f32 in -> bf16 out ----------------
__global__ __launch_bounds__(256) void k_layernorm_f2b(const float* __restrict__ x,
                                                       const float* __restrict__ g,
                                                       const float* __restrict__ b,
                                                       unsigned short* __restrict__ out) {
  const int row = blockIdx.x;
  const int tid = threadIdx.x;
  const float* xr = x + (size_t)row * D_;
  const float v0 = xr[tid], v1 = xr[tid + 256], v2 = xr[tid + 512];
  float s = v0 + v1 + v2;
  float q = v0 * v0 + v1 * v1 + v2 * v2;
  __shared__ float red[8];
  for (int off = 32; off > 0; off >>= 1) {
    s += __shfl_down(s, off);
    q += __shfl_down(q, off);
  }
  if ((tid & 63) == 0) { red[tid >> 6] = s; red[4 + (tid >> 6)] = q; }
  __syncthreads();
  s = red[0] + red[1] + red[2] + red[3];
  q = red[4] + red[5] + red[6] + red[7];
  const float mean = s * (1.0f / 768.0f);
  const float var = q * (1.0f / 768.0f) - mean * mean;
  const float inv = rsqrtf(var + 1e-5f);
  unsigned short* orow = out + (size_t)row * D_;
  orow[tid]       = f2bf((v0 - mean) * inv * g[tid]       + b[tid]);
  orow[tid + 256] = f2bf((v1 - mean) * inv * g[tid + 256] + b[tid + 256]);
  orow[tid + 512] = f2bf((v2 - mean) * inv * g[tid + 512] + b[tid + 512]);
}

// ================= ecg fused FFT (radix-8, 512 thr, 2 signals/block) ===========
template <int H, int DIR, bool TRIV>
__device__ __forceinline__ void pass8(float2* z, int l,
                                      float2 wa, float2 wb, float2 wc) {
  asm volatile("s_waitcnt lgkmcnt(0)" ::: "memory");
  const float sg = (DIR < 0) ? -1.f : 1.f;
  const int base = (H == 1) ? (l << 3)
                 : (H == 8) ? (((l >> 3) << 6) | (l & 7))
                            : l;
  const float2 x0 = z[padz(base)],         x1 = z[padz(base + H)];
  const float2 x2 = z[padz(base + 2 * H)], x3 = z[padz(base + 3 * H)];
  const float2 x4 = z[padz(base + 4 * H)], x5 = z[padz(base + 5 * H)];
  const float2 x6 = z[padz(base + 6 * H)], x7 = z[padz(base + 7 * H)];
  const float2 WA = make_float2(wa.x, sg * wa.y);
  const float2 WB = make_float2(wb.x, sg * wb.y);
  const float2 WC = make_float2(wc.x, sg * wc.y);
  const float2 WBp = make_float2(-sg * WB.y, sg * WB.x);  // WB * W4
  float2 t, u;
  t = TRIV ? x1 : cmulf(x1, WA); const float2 A0 = cadd(x0, t), A1 = csub(x0, t);
  t = TRIV ? x3 : cmulf(x3, WA); const float2 A2 = cadd(x2, t), A3 = csub(x2, t);
  t = TRIV ? x5 : cmulf(x5, WA); const float2 A4 = cadd(x4, t), A5 = csub(x4, t);
  t = TRIV ? x7 : cmulf(x7, WA); const float2 A6 = cadd(x6, t), A7 = csub(x6, t);
  t = TRIV ? A2 : cmulf(A2, WB);
  u = TRIV ? make_float2(-sg * A3.y, sg * A3.x) : cmulf(A3, WBp);
  const float2 B0 = cadd(A0, t), B2 = csub(A0, t);
  const float2 B1 = cadd(A1, u), B3 = csub(A1, u);
  t = TRIV ? A6 : cmulf(A6, WB);
  u = TRIV ? make_float2(-sg * A7.y, sg * A7.x) : cmulf(A7, WBp);
  const float2 B4 = cadd(A4, t), B6 = csub(A4, t);
  const float2 B5 = cadd(A5, u), B7 = csub(A5, u);
  const float r_ = 0.70710678118654752440f;
  const float2 F1 = TRIV ? make_float2(r_, sg * r_)
                         : cmulf(WC, make_float2(r_, sg * r_));
  const float2 F2 = TRIV ? make_float2(0.f, sg)
                         : make_float2(-sg * WC.y, sg * WC.x);
  const float2 F3 = TRIV ? make_float2(-r_, sg * r_)
                         : cmulf(WC, make_float2(-r_, sg * r_));
  t = TRIV ? B4 : cmulf(B4, WC);
  z[padz(base)]         = cadd(B0, t);
  z[padz(base + 4 * H)] = csub(B0, t);
  t = cmulf(B5, F1);
  z[padz(base + H)]     = cadd(B1, t);
  z[padz(base + 5 * H)] = csub(B1, t);
  t = cmulf(B6, F2);
  z[padz(base + 2 * H)] = cadd(B2, t);
  z[padz(base + 6 * H)] = csub(B2, t);
  t = cmulf(B7, F3);
  z[padz(base + 3 * H)] = cadd(B3, t);
  z[padz(base + 7 * H)] = csub(B3, t);
}

template <int FA, int FB>
__device__ __forceinline__ void scatter_buf(float2* z, const float (&s)[8],
                                            float wlo, float whi, int rlo, int rhi) {
  constexpr int iAlo = (FA > 0) ? FA - 1 : 0;
  constexpr int iAhi = (FA < 8) ? FA : 0;
  constexpr int iBlo = (FB > 0) ? FB - 1 : 0;
  constexpr int iBhi = (FB >= 0 && FB < 8) ? FB : 0;
  const float aLo = (FA == 0) ? 0.f : s[iAlo] * wlo;
  const float aHi = (FA == 8) ? 0.f : s[iAhi] * whi;
  const float bLo = (FB <= 0) ? 0.f : s[iBlo] * wlo;
  const float bHi = (FB < 0 || FB == 8) ? 0.f : s[iBhi] * whi;
  z[rlo] = make_float2(aLo, bLo);
  z[rhi] = make_float2(aHi, bHi);
}

// A-part scaled by gA, B-part by gB
template <int FA, int FB>
__device__ __forceinline__ void filt_pack(const float2* z, int k, float gA, float gB,
                                          float2 cA, float2 cB,
                                          float2& Ck, float2& Cm) {
  const int q = (512 - k) & 511;
  const float2 Zk = z[padz(k)], Zq = z[padz(q)];
  const float sc = 0.5f / 256.f;
  const float ar = (Zk.x + Zq.x) * sc, ai = (Zk.y - Zq.y) * sc;
  float yar, yai, ybr = 0.f, ybi = 0.f;
  {
    const float pr = (ar * ar - ai * ai) * (1.f / 2313.f);
    const float pi = (2.f * ar * ai) * (1.f / 2313.f);
    yar = (pr * cA.x - pi * cA.y) * gA;
    yai = (pr * cA.y + pi * cA.x) * gA;
  }
  if (FB >= 0) {
    const float br = (Zk.y + Zq.y) * sc, bi = (Zq.x - Zk.x) * sc;
    const float pr = (br * br - bi * bi) * (1.f / 2313.f);
    const float pi = (2.f * br * bi) * (1.f / 2313.f);
    ybr = (pr * cB.x - pi * cB.y) * gB;
    ybi = (pr * cB.y + pi * cB.x) * gB;
  }
  if (k == 0 || k == 256) {
    Ck = make_float2(yar, ybr);
    Cm = Ck;
  } else {
    Ck = make_float2(yar - ybi, yai + ybr);
    Cm = make_float2(yar + ybi, ybr - yai);
  }
}

__global__ __launch_bounds__(512) void k_ecg_fft(
    const float* __restrict__ ecgT, const float2* __restrict__ FcT,
    const float* __restrict__ gate, const float2* __restrict__ twg,
    unsigned short* __restrict__ xtT) {
  const int bd = blockIdx.x;              // 0..3071
  const int b = bd / 384, d0 = bd - (bd / 384) * 384;
  const int tid = threadIdx.x;
  const int grp = tid >> 8;               // signal group 0/1
  const int lt = tid & 255;
  const int wid = tid >> 6;               // wave 0..7 <-> buffer
  const int l = tid & 63;
  const int d = d0 + grp * 384;
  const int myBD = b * 768 + d;

  __shared__ float2 z[8][544];            // 34.8 KB

  float s[8];
  const float* src = ecgT + (size_t)myBD * S_;
#pragma unroll
  for (int k = 0; k < 8; ++k) s[k] = src[k * 256 + lt];

  float2 ptw[6];
  ptw[0] = twg[7 + (l & 7)];
  ptw[1] = twg[15 + (l & 7)];
  ptw[2] = twg[31 + (l & 7)];
  ptw[3] = twg[63 + l];
  ptw[4] = twg[127 + l];
  ptw[5] = twg[255 + l];
  const float2 t8 = twg[255 + lt];
  const float c0 = t8.x;
  const float wlo = 0.5f - 0.5f * c0;
  const float whi = 0.5f + 0.5f * c0;
  const int rlo = padz(rev9(lt)), rhi = padz(rev9(lt + 256));

  const float gX = gate[b * 768 + d0];
  const float gY = gate[b * 768 + d0 + 384];
  const float gOwn = grp ? gY : gX;
  const float2* fc = FcT + (size_t)d * NBINS_;

  float accr[10];
#pragma unroll
  for (int i = 0; i < 10; ++i) accr[i] = 0.f;

  // ======== super A: frames (0,8),(1,2),(3,4),(5,6) of own signal ========
  const float2 cA0 = fc[0 * 257 + lt], cB0 = fc[8 * 257 + lt];
  const float2 cA1 = fc[1 * 257 + lt], cB1 = fc[2 * 257 + lt];
  const float2 cA2 = fc[3 * 257 + lt], cB2 = fc[4 * 257 + lt];
  const float2 cA3 = fc[5 * 257 + lt], cB3 = fc[6 * 257 + lt];
  float2* zg = z[grp * 4];
  scatter_buf<0, 8>(z[grp * 4 + 0], s, wlo, whi, rlo, rhi);
  scatter_buf<1, 2>(z[grp * 4 + 1], s, wlo, whi, rlo, rhi);
  scatter_buf<3, 4>(z[grp * 4 + 2], s, wlo, whi, rlo, rhi);
  scatter_buf<5, 6>(z[grp * 4 + 3], s, wlo, whi, rlo, rhi);
  __syncthreads();
  {  // forward FFT: wave w -> buffer w (all 8 busy)
    float2* zz = z[wid];
    pass8<1, -1, true>(zz, l, ptw[0], ptw[1], ptw[2]);
    pass8<8, -1, false>(zz, l, ptw[0], ptw[1], ptw[2]);
    pass8<64, -1, false>(zz, l, ptw[3], ptw[4], ptw[5]);
  }
  __syncthreads();
  float2 Ck0, Cm0, Ck1, Cm1, Ck2, Cm2, Ck3, Cm3;
  float2 Cn0, Cn1, Cn2, Cn3, dum;
  filt_pack<0, 8>(z[grp * 4 + 0], lt, gOwn, gOwn, cA0, cB0, Ck0, Cm0);
  filt_pack<1, 2>(z[grp * 4 + 1], lt, gOwn, gOwn, cA1, cB1, Ck1, Cm1);
  filt_pack<3, 4>(z[grp * 4 + 2], lt, gOwn, gOwn, cA2, cB2, Ck2, Cm2);
  filt_pack<5, 6>(z[grp * 4 + 3], lt, gOwn, gOwn, cA3, cB3, Ck3, Cm3);
  if (lt == 0) {
    float2 nA, nB;
    nA = fc[0 * 257 + 256]; nB = fc[8 * 257 + 256];
    filt_pack<0, 8>(z[grp * 4 + 0], 256, gOwn, gOwn, nA, nB, Cn0, dum);
    nA = fc[1 * 257 + 256]; nB = fc[2 * 257 + 256];
    filt_pack<1, 2>(z[grp * 4 + 1], 256, gOwn, gOwn, nA, nB, Cn1, dum);
    nA = fc[3 * 257 + 256]; nB = fc[4 * 257 + 256];
    filt_pack<3, 4>(z[grp * 4 + 2], 256, gOwn, gOwn, nA, nB, Cn2, dum);
    nA = fc[5 * 257 + 256]; nB = fc[6 * 257 + 256];
    filt_pack<5, 6>(z[grp * 4 + 3], 256, gOwn, gOwn, nA, nB, Cn3, dum);
  }
  __syncthreads();
  {
    zg[0 * 544 + rlo] = Ck0; zg[1 * 544 + rlo] = Ck1;
    zg[2 * 544 + rlo] = Ck2; zg[3 * 544 + rlo] = Ck3;
    if (lt == 0) {
      zg[0 * 544 + padz(1)] = Cn0; zg[1 * 544 + padz(1)] = Cn1;
      zg[2 * 544 + padz(1)] = Cn2; zg[3 * 544 + padz(1)] = Cn3;
    } else {
      const int rm = padz(rev9(512 - lt));
      zg[0 * 544 + rm] = Cm0; zg[1 * 544 + rm] = Cm1;
      zg[2 * 544 + rm] = Cm2; zg[3 * 544 + rm] = Cm3;
    }
  }
  __syncthreads();
  {  // inverse FFT
    float2* zz = z[wid];
    pass8<1, 1, true>(zz, l, ptw[0], ptw[1], ptw[2]);
    pass8<8, 1, false>(zz, l, ptw[0], ptw[1], ptw[2]);
    pass8<64, 1, false>(zz, l, ptw[3], ptw[4], ptw[5]);
  }
  __syncthreads();
  {  // overlap-add (own group's 4 buffers)
    float2 vLo, vHi;
    vLo = zg[0 * 544 + padz(lt)]; vHi = zg[0 * 544 + padz(lt + 256)];
    accr[0] += 0.5f * wlo * vLo.x; accr[1] += 0.5f * whi * vHi.x;
    accr[8] += 0.5f * wlo * vLo.y; accr[9] += 0.5f * whi * vHi.y;
    vLo = zg[1 * 544 + padz(lt)]; vHi = zg[1 * 544 + padz(lt + 256)];
    accr[1] += 0.5f * wlo * vLo.x; accr[2] += 0.5f * whi * vHi.x;
    accr[2] += 0.5f * wlo * vLo.y; accr[3] += 0.5f * whi * vHi.y;
    vLo = zg[2 * 544 + padz(lt)]; vHi = zg[2 * 544 + padz(lt + 256)];
    accr[3] += 0.5f * wlo * vLo.x; accr[4] += 0.5f * whi * vHi.x;
    accr[4] += 0.5f * wlo * vLo.y; accr[5] += 0.5f * whi * vHi.y;
    vLo = zg[3 * 544 + padz(lt)]; vHi = zg[3 * 544 + padz(lt + 256)];
    accr[5] += 0.5f * wlo * vLo.x; accr[6] += 0.5f * whi * vHi.x;
    accr[6] += 0.5f * wlo * vLo.y; accr[7] += 0.5f * whi * vHi.y;
  }
  __syncthreads();  // z[0] reads done before super C overwrites

  // ======== super C: (X7 re, Y7 im) in buffer 0 ========
  {
    float* z0f = (float*)z[0];
    z0f[2 * rlo + grp] = s[6] * wlo;   // frame 7 lo half
    z0f[2 * rhi + grp] = s[7] * whi;   // frame 7 hi half
  }
  __syncthreads();
  if (wid == 0) {
    pass8<1, -1, true>(z[0], l, ptw[0], ptw[1], ptw[2]);
    pass8<8, -1, false>(z[0], l, ptw[0], ptw[1], ptw[2]);
    pass8<64, -1, false>(z[0], l, ptw[3], ptw[4], ptw[5]);
  }
  __syncthreads();
  float2 CkC, CmC, CnC;
  if (grp == 0) {
    const float2* fcY = FcT + (size_t)(d0 + 384) * NBINS_;
    const float2 cA = fc[7 * 257 + lt];
    const float2 cB = fcY[7 * 257 + lt];
    filt_pack<7, 7>(z[0], lt, gX, gY, cA, cB, CkC, CmC);
    if (lt == 0) {
      const float2 nA = fc[7 * 257 + 256];
      const float2 nB = fcY[7 * 257 + 256];
      filt_pack<7, 7>(z[0], 256, gX, gY, nA, nB, CnC, dum);
    }
  }
  __syncthreads();
  if (grp == 0) {
    z[0][rlo] = CkC;
    if (lt == 0) z[0][padz(1)] = CnC;
    else z[0][padz(rev9(512 - lt))] = CmC;
  }
  __syncthreads();
  if (wid == 0) {
    pass8<1, 1, true>(z[0], l, ptw[0], ptw[1], ptw[2]);
    pass8<8, 1, false>(z[0], l, ptw[0], ptw[1], ptw[2]);
    pass8<64, 1, false>(z[0], l, ptw[3], ptw[4], ptw[5]);
  }
  __syncthreads();
  {
    const float2 vLo = z[0][padz(lt)], vHi = z[0][padz(lt + 256)];
    const float xlo = grp ? vLo.y : vLo.x;
    const float xhi = grp ? vHi.y : vHi.x;
    accr[7] += 0.5f * wlo * xlo;
    accr[8] += 0.5f * whi * xhi;
  }

  // ---- output: own signal ----
  const float rinv = 1.0f / (0.5f + 0.5f * c0 * c0);
  unsigned short* dst = xtT + (size_t)myBD * S_;
#pragma unroll
  for (int i2 = 0; i2 < 8; ++i2)
    dst[i2 * 256 + lt] = f2bf(accr[i2 + 1] * rinv + s[i2]);
}

// ---- per-(b,t) LN stats over d, reading bf16 xtT[b][d][t] as uint pairs ----
__global__ __launch_bounds__(256) void k_colstats_bf(const unsigned short* __restrict__ xtT,
                                                     float2* __restrict__ stats) {
  const int b = blockIdx.y;
  const int t0 = blockIdx.x * 128;
  const int tx = threadIdx.x & 63;
  const int ty = threadIdx.x >> 6;
  float s0 = 0.f, q0 = 0.f, s1 = 0.f, q1 = 0.f;
  const unsigned int* base = (const unsigned int*)(xtT + (size_t)b * D_ * S_);
  for (int dd = ty; dd < D_; dd += 4) {
    const unsigned int u = base[(size_t)dd * (S_ / 2) + (t0 >> 1) + tx];
    const float v0 = bf2f((unsigned short)(u & 0xffffu));
    const float v1 = bf2f((unsigned short)(u >> 16));
    s0 += v0; q0 = fmaf(v0, v0, q0);
    s1 += v1; q1 = fmaf(v1, v1, q1);
  }
  __shared__ float sh[4][64][4];
  sh[ty][tx][0] = s0; sh[ty][tx][1] = q0; sh[ty][tx][2] = s1; sh[ty][tx][3] = q1;
  __syncthreads();
  if (ty == 0) {
    s0 = sh[0][tx][0] + sh[1][tx][0] + sh[2][tx][0] + sh[3][tx][0];
    q0 = sh[0][tx][1] + sh[1][tx][1] + sh[2][tx][1] + sh[3][tx][1];
    s1 = sh[0][tx][2] + sh[1][tx][2] + sh[2][tx][2] + sh[3][tx][2];
    q1 = sh[0][tx][3] + sh[1][tx][3] + sh[2][tx][3] + sh[3][tx][3];
    stats[(size_t)b * S_ + t0 + 2 * tx]     = make_float2(s0, q0);
    stats[(size_t)b * S_ + t0 + 2 * tx + 1] = make_float2(s1, q1);
  }
}

// ---- transpose + LN apply, bf16 in -> bf16 out ----
__global__ __launch_bounds__(256) void k_transpose_ln(
    const unsigned short* __restrict__ xtT, const float2* __restrict__ stats,
    const float* __restrict__ g, const float* __restrict__ bia,
    unsigned short* __restrict__ xhat) {
  __shared__ float tile[32][33];
  const int b = blockIdx.z;
  const int t0 = blockIdx.x * 32;
  const int d0 = blockIdx.y * 32;
  const int tx = threadIdx.x & 31, ty = threadIdx.x >> 5;
  for (int i = ty; i < 32; i += 8)
    tile[i][tx] = bf2f(xtT[((size_t)b * D_ + d0 + i) * S_ + t0 + tx]);
  __syncthreads();
  const float gv = g[d0 + tx], bv = bia[d0 + tx];
  for (int i = ty; i < 32; i += 8) {
    const float2 st = stats[(size_t)b * S_ + t0 + i];
    const float mean = st.x * (1.0f / 768.0f);
    const float var = st.y * (1.0f / 768.0f) - mean * mean;
    const float inv = rsqrtf(var + 1e-5f);
    xhat[((size_t)b * S_ + t0 + i) * D_ + d0 + tx] =
        f2bf((tile[tx][i] - mean) * inv * gv + bv);
  }
}

// ---- dual-segment LayerNorm, bf16 in -> f32 out ----
__global__ __launch_bounds__(256) void k_layernorm_dual(
    const unsigned short* __restrict__ x1, const float* __restrict__ g1,
    const float* __restrict__ b1, float* __restrict__ o1, int n1,
    const unsigned short* __restrict__ x2, const float* __restrict__ g2,
    const float* __restrict__ b2, float* __restrict__ o2) {
  int row = blockIdx.x;
  const unsigned short* x; const float *g, *b; float* o;
  if (row < n1) { x = x1; g = g1; b = b1; o = o1; }
  else { row -= n1; x = x2; g = g2; b = b2; o = o2; }
  const int tid = threadIdx.x;
  const unsigned short* xr = x + (size_t)row * D_;
  const float v0 = bf2f(xr[tid]), v1 = bf2f(xr[tid + 256]), v2 = bf2f(xr[tid + 512]);
  float s = v0 + v1 + v2;
  float q = v0 * v0 + v1 * v1 + v2 * v2;
  __shared__ float red[8];
  for (int off = 32; off > 0; off >>= 1) {
    s += __shfl_down(s, off);
    q += __shfl_down(q, off);
  }
  if ((tid & 63) == 0) { red[tid >> 6] = s; red[4 + (tid >> 6)] = q; }
  __syncthreads();
  s = red[0] + red[1] + red[2] + red[3];
  q = red[4] + red[5] + red[6] + red[7];
  const float mean = s * (1.0f / 768.0f);
  const float var = q * (1.0f / 768.0f) - mean * mean;
  const float inv = rsqrtf(var + 1e-5f);
  float* orow = o + (size_t)row * D_;
  orow[tid]       = (v0 - mean) * inv * g[tid]       + b[tid];
  orow[tid + 256] = (v1 - mean) * inv * g[tid + 256] + b[tid + 256];
  orow[tid + 512] = (v2 - mean) * inv * g[tid + 512] + b[tid + 512];
}

// ---------- dual-segment MFMA GEMM, double-buffered pipeline ----------
// MODE 0: exact GELU -> bf16 ; MODE 1: +resid(bf16) -> bf16
template <int MODE>
__global__ __launch_bounds__(256) void k_gemm_dual(
    const unsigned short* __restrict__ A1, const unsigned short* __restrict__ W1,
    const float* __restrict__ b1, const unsigned short* __restrict__ r1,
    unsigned short* __restrict__ o1, int M1, int nby1,
    const unsigned short* __restrict__ A2, const unsigned short* __restrict__ W2,
    const float* __restrict__ b2, const unsigned short* __restrict__ r2,
    unsigned short* __restrict__ o2, int M2) {
  __shared__ unsigned short Asm[2][128 * 64];
  __shared__ unsigned short Bsm[2][128 * 64];
  const int tid = threadIdx.x;
  const int lane = tid & 63, wid = tid >> 6;
  const int wr = wid >> 1, wc = wid & 1;
  int bx, by;
  {
    const int nwg = gridDim.x * gridDim.y;
    const int bid = blockIdx.y * gridDim.x + blockIdx.x;
    const int xcd = bid & 7, lin = bid >> 3;
    const int qq = nwg >> 3, rr = nwg & 7;
    const int nbid = (xcd < rr) ? xcd * (qq + 1) + lin
                                : rr * (qq + 1) + (xcd - rr) * qq + lin;
    bx = nbid % gridDim.x;
    by = nbid / gridDim.x;
  }
  const unsigned short* Abf; const unsigned short* Wbf; const float* bias;
  const unsigned short* resid; unsigned short* outb; int M;
  if (by < nby1) { Abf = A1; Wbf = W1; bias = b1; resid = r1; outb = o1; M = M1; }
  else { by -= nby1; Abf = A2; Wbf = W2; bias = b2; resid = r2; outb = o2; M = M2; }
  const int n0 = bx * 128, m0 = by * 128;

  auto STAGE = [&](int buf, int kt) {
    const int k0 = kt * 64;
#pragma unroll
    for (int i = 0; i < 4; ++i) {
      const int c = tid + 256 * i;
      const int row = c >> 3, sl = c & 7;
      const int gsl = sl ^ (row & 7);
      gload16(Abf + (size_t)(m0 + row) * 768 + k0 + gsl * 8, &Asm[buf][c * 8]);
      gload16(Wbf + (size_t)(n0 + row) * 768 + k0 + gsl * 8, &Bsm[buf][c * 8]);
    }
  };

  f32x4 acc[4][4] = {};
  STAGE(0, 0);
  for (int kt = 0; kt < 12; ++kt) {
    const int cur = kt & 1;
    if (kt < 11) {
      STAGE(cur ^ 1, kt + 1);
      asm volatile("s_waitcnt vmcnt(8)" ::: "memory");
    } else {
      asm volatile("s_waitcnt vmcnt(0)" ::: "memory");
    }
    __builtin_amdgcn_sched_barrier(0);
    __builtin_amdgcn_s_barrier();
#pragma unroll
    for (int ks = 0; ks < 2; ++ks) {
      bf16x8 af[4], bfv[4];
#pragma unroll
      for (int mi = 0; mi < 4; ++mi) {
        const int row = wr * 64 + mi * 16 + (lane & 15);
        const int sl = (ks * 4 + (lane >> 4)) ^ (row & 7);
        af[mi] = *(const bf16x8*)((const char*)Asm[cur] + row * 128 + sl * 16);
      }
#pragma unroll
      for (int ni = 0; ni < 4; ++ni) {
        const int row = wc * 64 + ni * 16 + (lane & 15);
        const int sl = (ks * 4 + (lane >> 4)) ^ (row & 7);
        bfv[ni] = *(const bf16x8*)((const char*)Bsm[cur] + row * 128 + sl * 16);
      }
#pragma unroll
      for (int mi = 0; mi < 4; ++mi)
#pragma unroll
        for (int ni = 0; ni < 4; ++ni)
          acc[mi][ni] = __builtin_amdgcn_mfma_f32_16x16x32_bf16(af[mi], bfv[ni],
                                                                acc[mi][ni], 0, 0, 0);
    }
    __builtin_amdgcn_sched_barrier(0);
    __builtin_amdgcn_s_barrier();
  }
#pragma unroll
  for (int mi = 0; mi < 4; ++mi) {
#pragma unroll
    for (int ni = 0; ni < 4; ++ni) {
      const int col = n0 + wc * 64 + ni * 16 + (lane & 15);
#pragma unroll
      for (int e = 0; e < 4; ++e) {
        const int row = m0 + wr * 64 + mi * 16 + (lane >> 4) * 4 + e;
        if (row >= M) continue;
        float v = acc[mi][ni][e] + bias[col];
        if (MODE == 0) {
          v = gelu_f(v);
        } else {
          v += bf2f(resid[(size_t)row * 768 + col]);
        }
        outb[(size_t)row * 768 + col] = f2bf(v);
      }
    }
  }
}

}  // namespace

extern "C" void kernel_launch(void* const* d_in, const int* in_sizes, int n_in,
                              void* d_out, int out_size, void* d_ws, size_t ws_size,
                              hipStream_t stream) {
  (void)in_sizes; (void)n_in; (void)out_size; (void)ws_size;
  const float* ecg     = (const float*)d_in[0];
  const float* image   = (const float*)d_in[1];
  const float* ebank   = (const float*)d_in[2];
  const float* cbank   = (const float*)d_in[3];
  const float* gsel    = (const float*)d_in[4];
  const float* gw      = (const float*)d_in[5];
  const float* gb      = (const float*)d_in[6];
  const float* e_ln1_g = (const float*)d_in[7];
  const float* e_ln1_b = (const float*)d_in[8];
  const float* e_w1    = (const float*)d_in[9];
  const float* e_b1    = (const float*)d_in[10];
  const float* e_w2    = (const float*)d_in[11];
  const float* e_b2    = (const float*)d_in[12];
  const float* e_ln2_g = (const float*)d_in[13];
  const float* e_ln2_b = (const float*)d_in[14];
  const float* c_ln1_g = (const float*)d_in[15];
  const float* c_ln1_b = (const float*)d_in[16];
  const float* c_w1    = (const float*)d_in[17];
  const float* c_b1    = (const float*)d_in[18];
  const float* c_w2    = (const float*)d_in[19];
  const float* c_b2    = (const float*)d_in[20];
  const float* c_ln2_g = (const float*)d_in[21];
  const float* c_ln2_b = (const float*)d_in[22];

  float* out = (float*)d_out;
  float* ws = (float*)d_ws;

  constexpr size_t TXT = (size_t)8 * 2048 * 768;   // 12,582,912 floats
  constexpr size_t IMG = (size_t)8 * 196 * 768;    // 1,204,224 elems

  // ws layout: A | Bb | wbf | gatev | stats | gpart | twg
  float* A  = ws;
  float* Bb = A + TXT;
  unsigned short* wbf = (unsigned short*)(Bb + TXT);
  unsigned short* ew1b = wbf;
  unsigned short* ew2b = wbf + NW_;
  unsigned short* cw1b = wbf + 2 * NW_;
  unsigned short* cw2b = wbf + 3 * NW_;
  float* gatev = (float*)(wbf + 4 * (size_t)NW_);
  float2* stats = (float2*)(gatev + 8 * 768);
  float* gpart = (float*)(stats + 8 * 2048);   // 8*11*768 floats
  float2* twg = (float2*)(gpart + 8 * 11 * 768);

  float2* FcT = (float2*)out;  // parked in d_out (dead before final LN)

  // text buffers: A = xhat (first half, bf16) | y_tb (second half, bf16)
  unsigned short* xhat = (unsigned short*)A;
  unsigned short* y_tb = (unsigned short*)A + TXT;
  // Bb first half: xtT then h_t (bf16); second half: image scratch
  unsigned short* xtT = (unsigned short*)Bb;
  unsigned short* h_t = (unsigned short*)Bb;
  float* Bb2 = Bb + TXT / 2;
  float2* imgF = (float2*)Bb2;                               // 1,216,512 floats
  float* xi = Bb2 + 1216512;                                 // 1,204,224 floats
  unsigned short* xh_i = (unsigned short*)(xi + IMG);        // bf16 LN1 / resid
  unsigned short* h_i  = xh_i + IMG;
  unsigned short* y_ib = h_i + IMG;

  // ---- one-time prep (fused) ----
  k_prep<<<PREP_WALL + PREP_FC + 2, 256, 0, stream>>>(
      e_w1, e_w2, c_w1, c_w2, wbf, (const float2*)ebank, FcT, twg);

  // ---- image path front (produces gate + xh_i) ----
  k_img_dft_f<<<dim3(11, 3, 8), 256, 0, stream>>>(image, (const float2*)cbank,
                                                  (const float2*)gsel, imgF, gpart);
  k_gate_mm2<<<48, 256, 0, stream>>>(gpart, gw, gb, gatev);
  k_img_idft<<<dim3(14, 3, 8), 256, 0, stream>>>(imgF, image, xi);
  k_layernorm_f2b<<<1568, 256, 0, stream>>>(xi, c_ln1_g, c_ln1_b, xh_i);

  // ---- ecg path ----
  k_transpose_g<<<dim3(24, 64, 8), 256, 0, stream>>>(ecg, A, 2048, 768);
  k_ecg_fft<<<3072, 512, 0, stream>>>(A, FcT, gatev, twg, xtT);
  k_colstats_bf<<<dim3(16, 8), 256, 0, stream>>>(xtT, stats);
  k_transpose_ln<<<dim3(64, 24, 8), 256, 0, stream>>>(xtT, stats, e_ln1_g, e_ln1_b, xhat);

  // ---- combined FFN: text (128 by-blocks) + image (13 by-blocks) ----
  k_gemm_dual<0><<<dim3(6, 141), 256, 0, stream>>>(
      xhat, ew1b, e_b1, nullptr, h_t, 16384, 128,
      xh_i, cw1b, c_b1, nullptr, h_i, 1568);
  k_gemm_dual<1><<<dim3(6, 141), 256, 0, stream>>>(
      h_t, ew2b, e_b2, xhat, y_tb, 16384, 128,
      h_i, cw2b, c_b2, xh_i, y_ib, 1568);
  k_layernorm_dual<<<16384 + 1568, 256, 0, stream>>>(
      y_tb, e_ln2_g, e_ln2_b, out, 16384,
      y_ib, c_ln2_g, c_ln2_b, out + TXT);
}

// Round 15
// 412.629 us; speedup vs baseline: 1.0938x; 1.0885x over previous
//
#include <hip/hip_runtime.h>
#include <math.h>

namespace {

constexpr int B_ = 8;
constexpr int S_ = 2048;
constexpr int D_ = 768;
constexpr int N_ = 196;     // image spatial
constexpr int NF_ = 99;     // image freq bins
constexpr int NFREQ_ = 257;
constexpr int NSEG_ = 9;
constexpr int NBINS_ = NFREQ_ * NSEG_;  // 2313
constexpr int NW_ = D_ * D_;            // 589824
constexpr float TWOPI_ = 6.28318530717958647692f;

using bf16x8 = __attribute__((ext_vector_type(8))) short;
using f32x4  = __attribute__((ext_vector_type(4))) float;

__device__ __forceinline__ int rev9(int x) { return (int)(__brev((unsigned)x) >> 23); }
__device__ __forceinline__ int padz(int i) { return i + (i >> 4); }

__device__ __forceinline__ unsigned short f2bf(float x) {
  unsigned u = __float_as_uint(x);
  u = (u + 0x7FFFu + ((u >> 16) & 1u)) >> 16;
  return (unsigned short)u;
}
__device__ __forceinline__ float bf2f(unsigned short h) {
  return __uint_as_float(((unsigned)h) << 16);
}

// exact GELU via Abramowitz-Stegun 7.1.26 erf (|eps| <= 1.5e-7)
__device__ __forceinline__ float gelu_f(float v) {
  const float x = fabsf(v) * 0.70710678118654752440f;
  const float t = 1.0f / fmaf(0.3275911f, x, 1.0f);
  float p = fmaf(fmaf(fmaf(fmaf(1.061405429f, t, -1.453152027f), t, 1.421413741f),
                      t, -0.284496736f), t, 0.254829592f);
  const float e = __expf(-x * x);
  const float er = 1.0f - p * t * e;
  return 0.5f * v * (1.0f + ((v < 0.f) ? -er : er));
}

__device__ __forceinline__ void gload16(const void* g, void* l) {
  __builtin_amdgcn_global_load_lds((const __attribute__((address_space(1))) void*)g,
                                   (__attribute__((address_space(3))) void*)l, 16, 0, 0);
}

__device__ __forceinline__ float2 cmulf(float2 a, float2 b) {
  return make_float2(a.x * b.x - a.y * b.y, a.x * b.y + a.y * b.x);
}
__device__ __forceinline__ float2 cadd(float2 a, float2 b) {
  return make_float2(a.x + b.x, a.y + b.y);
}
__device__ __forceinline__ float2 csub(float2 a, float2 b) {
  return make_float2(a.x - b.x, a.y - b.y);
}

// ---------------- batched transpose (B,R,C) -> (B,C,R) ----------------
__global__ __launch_bounds__(256) void k_transpose_g(const float* __restrict__ src,
                                                     float* __restrict__ dst,
                                                     int R, int C) {
  __shared__ float tile[32][33];
  const int b = blockIdx.z;
  const int c0 = blockIdx.x * 32;
  const int r0 = blockIdx.y * 32;
  const int tx = threadIdx.x & 31, ty = threadIdx.x >> 5;
  for (int i = ty; i < 32; i += 8)
    tile[i][tx] = src[((size_t)b * R + r0 + i) * C + c0 + tx];
  __syncthreads();
  for (int i = ty; i < 32; i += 8)
    dst[((size_t)b * C + c0 + i) * R + r0 + tx] = tile[tx][i];
}

// ---- fused prep: weight bf16 conv + filter bank + twiddles + 196-root table ----
constexpr int PREP_W = (NW_ + 255) / 256;
constexpr int PREP_WALL = 4 * PREP_W;
constexpr int PREP_FC = (NBINS_ * D_ + 255) / 256;
__global__ __launch_bounds__(256) void k_prep(
    const float* __restrict__ w0, const float* __restrict__ w1,
    const float* __restrict__ w2, const float* __restrict__ w3,
    unsigned short* __restrict__ wbf, const float2* __restrict__ e2,
    float2* __restrict__ FcT, float2* __restrict__ twg,
    float2* __restrict__ twN) {
  const int bid = blockIdx.x;
  if (bid < PREP_WALL) {
    const int m = bid / PREP_W;
    const int i = (bid - m * PREP_W) * 256 + threadIdx.x;
    if (i >= NW_) return;
    const float* src = (m == 0) ? w0 : (m == 1) ? w1 : (m == 2) ? w2 : w3;
    wbf[(size_t)m * NW_ + i] = f2bf(src[i]);
  } else if (bid < PREP_WALL + PREP_FC) {
    const int o = (bid - PREP_WALL) * 256 + threadIdx.x;
    if (o >= NBINS_ * D_) return;
    const int d = o / NBINS_;
    const int r = o - d * NBINS_;
    const int f = r / NFREQ_;
    const int k = r - f * NFREQ_;
    const int s = k * 9 + f;
    const float2 a = e2[(size_t)s * D_ + d];
    const float2 b = e2[(size_t)(NBINS_ + s) * D_ + d];
    FcT[o] = make_float2(-(a.x + b.x), -(a.y + b.y));
  } else if (bid < PREP_WALL + PREP_FC + 2) {
    const int i = (bid - PREP_WALL - PREP_FC) * 256 + threadIdx.x;
    if (i >= 511) return;
    const int v = i + 1;
    const int h = 1 << (31 - __clz(v));
    const int j = v - h;
    float sn, cs;
    sincosf((float)j * ((TWOPI_ * 0.5f) / (float)h), &sn, &cs);
    twg[i] = make_float2(cs, sn);
  } else {
    const int i = threadIdx.x;
    if (i >= N_) return;
    float sn, cs;
    sincosf(TWOPI_ * (float)i / (float)N_, &sn, &cs);
    twN[i] = make_float2(cs, sn);
  }
}

// ---- image forward DFT + filter + gate partials ----
__global__ __launch_bounds__(256) void k_img_dft_f(
    const float* __restrict__ image, const float2* __restrict__ bank2,
    const float2* __restrict__ gsel2, const float2* __restrict__ twN,
    float2* __restrict__ imgF, float* __restrict__ part) {
  const int fg = blockIdx.x;
  const int f0 = fg * 9;
  const int d = blockIdx.y * 256 + threadIdx.x;
  const int b = blockIdx.z;
  __shared__ float2 tws[9 * N_];
  for (int idx = threadIdx.x; idx < 9 * N_; idx += 256) {
    const int fi = idx / N_;
    const int t = idx - fi * N_;
    tws[idx] = twN[((f0 + fi) * t) % N_];
  }
  __syncthreads();
  float re[9] = {}, im[9] = {};
  const float* ip = image + (size_t)b * N_ * D_ + d;
  for (int t = 0; t < N_; ++t) {
    const float v = ip[(size_t)t * D_];
#pragma unroll
    for (int fi = 0; fi < 9; ++fi) {
      const float2 w = tws[fi * N_ + t];
      re[fi] = fmaf(v, w.x, re[fi]);
      im[fi] = fmaf(-v, w.y, im[fi]);
    }
  }
  const float sc = 1.0f / (196.0f * 99.0f);
  float gp = 0.f;
#pragma unroll
  for (int fi = 0; fi < 9; ++fi) {
    const int f = f0 + fi;
    const float pr = (re[fi] * re[fi] - im[fi] * im[fi]) * sc;
    const float pi2 = (2.f * re[fi] * im[fi]) * sc;
    const size_t fd = (size_t)f * D_ + d;
    const float2 c0 = bank2[fd];
    const float2 c1 = bank2[(size_t)NF_ * D_ + fd];
    const float fcr = -(c0.x + c1.x), fci = -(c0.y + c1.y);
    const float zr = pr * fcr - pi2 * fci;
    const float zi = pr * fci + pi2 * fcr;
    imgF[(size_t)(b * NF_ + f) * D_ + d] = make_float2(zr, zi);
    const float2 gw = gsel2[fd];
    gp += zr * gw.x - zi * gw.y;
  }
  part[((size_t)b * 11 + fg) * D_ + d] = gp;
}

// ---- gate matvec, folds 11 partials: gate[b][d0..d0+16) ----
__global__ __launch_bounds__(256) void k_gate_mm2(const float* __restrict__ part,
                                                  const float* __restrict__ W,
                                                  const float* __restrict__ bias,
                                                  float* __restrict__ gate) {
  __shared__ float row[8][D_];
  __shared__ float red[16][16][8];
  const int tid = threadIdx.x;
  const int d0 = blockIdx.x * 16;
  for (int i = tid; i < 8 * D_; i += 256) {
    const int b = i / D_, e = i - b * D_;
    float s = 0.f;
    for (int p = 0; p < 11; ++p) s += part[((size_t)b * 11 + p) * D_ + e];
    row[b][e] = s * (1.0f / 99.0f);
  }
  __syncthreads();
  const int dl = tid >> 4;
  const int ec = tid & 15;
  const float* w = W + (size_t)(d0 + dl) * D_ + ec * 48;
  float acc[8] = {};
  for (int e = 0; e < 48; e += 4) {
    const float4 wv = *reinterpret_cast<const float4*>(w + e);
    const int eg = ec * 48 + e;
#pragma unroll
    for (int b = 0; b < 8; ++b) {
      acc[b] = fmaf(row[b][eg], wv.x, acc[b]);
      acc[b] = fmaf(row[b][eg + 1], wv.y, acc[b]);
      acc[b] = fmaf(row[b][eg + 2], wv.z, acc[b]);
      acc[b] = fmaf(row[b][eg + 3], wv.w, acc[b]);
    }
  }
#pragma unroll
  for (int b = 0; b < 8; ++b) red[dl][ec][b] = acc[b];
  __syncthreads();
  if (tid < 128) {
    const int dl2 = tid >> 3, b = tid & 7;
    float s = bias[d0 + dl2];
    for (int c = 0; c < 16; ++c) s += red[dl2][c][b];
    gate[b * D_ + d0 + dl2] = s;
  }
}

// ---- image inverse DFT (ortho) + residual ----
__global__ __launch_bounds__(256) void k_img_idft(
    const float2* __restrict__ imgF, const float* __restrict__ image,
    const float2* __restrict__ twN, float* __restrict__ xi) {
  const int t0 = blockIdx.x * 14;
  const int d = blockIdx.y * 256 + threadIdx.x;
  const int b = blockIdx.z;
  __shared__ float2 tws[14 * NF_];
  for (int idx = threadIdx.x; idx < 14 * NF_; idx += 256) {
    const int ti = idx / NF_;
    const int f = idx - ti * NF_;
    tws[idx] = twN[((t0 + ti) * f) % N_];
  }
  __syncthreads();
  const float2* zp = imgF + (size_t)b * NF_ * D_ + d;
  const float2 z0 = zp[0];
  const float2 zny = zp[(size_t)(NF_ - 1) * D_];
  float acc[14];
#pragma unroll
  for (int ti = 0; ti < 14; ++ti)
    acc[ti] = z0.x + (((t0 + ti) & 1) ? -zny.x : zny.x);
  for (int f = 1; f < NF_ - 1; ++f) {
    const float2 z = zp[(size_t)f * D_];
#pragma unroll
    for (int ti = 0; ti < 14; ++ti) {
      const float2 w = tws[ti * NF_ + f];
      acc[ti] += 2.f * (z.x * w.x - z.y * w.y);
    }
  }
#pragma unroll
  for (int ti = 0; ti < 14; ++ti) {
    const size_t idx = (size_t)(b * N_ + t0 + ti) * D_ + d;
    xi[idx] = acc[ti] * (1.0f / 14.0f) + image[idx];
  }
}

// ---------------- LayerNorm f32 in -> bf16 out ----------------
__global__ __launch_bounds__(256) void k_layernorm_f2b(const float* __restrict__ x,
                                                       const float* __restrict__ g,
                                                       const float* __restrict__ b,
                                                       unsigned short* __restrict__ out) {
  const int row = blockIdx.x;
  const int tid = threadIdx.x;
  const float* xr = x + (size_t)row * D_;
  const float v0 = xr[tid], v1 = xr[tid + 256], v2 = xr[tid + 512];
  float s = v0 + v1 + v2;
  float q = v0 * v0 + v1 * v1 + v2 * v2;
  __shared__ float red[8];
  for (int off = 32; off > 0; off >>= 1) {
    s += __shfl_down(s, off);
    q += __shfl_down(q, off);
  }
  if ((tid & 63) == 0) { red[tid >> 6] = s; red[4 + (tid >> 6)] = q; }
  __syncthreads();
  s = red[0] + red[1] + red[2] + red[3];
  q = red[4] + red[5] + red[6] + red[7];
  const float mean = s * (1.0f / 768.0f);
  const float var = q * (1.0f / 768.0f) - mean * mean;
  const float inv = rsqrtf(var + 1e-5f);
  unsigned short* orow = out + (size_t)row * D_;
  orow[tid]       = f2bf((v0 - mean) * inv * g[tid]       + b[tid]);
  orow[tid + 256] = f2bf((v1 - mean) * inv * g[tid + 256] + b[tid + 256]);
  orow[tid + 512] = f2bf((v2 - mean) * inv * g[tid + 512] + b[tid + 512]);
}

// ================= ecg fused FFT pipeline (radix-8, 4 buffers/block) ===========
template <int H, int DIR, bool TRIV>
__device__ __forceinline__ void pass8(float2* z, int l,
                                      float2 wa, float2 wb, float2 wc) {
  asm volatile("s_waitcnt lgkmcnt(0)" ::: "memory");
  const float sg = (DIR < 0) ? -1.f : 1.f;
  const int base = (H == 1) ? (l << 3)
                 : (H == 8) ? (((l >> 3) << 6) | (l & 7))
                            : l;
  const float2 x0 = z[padz(base)],         x1 = z[padz(base + H)];
  const float2 x2 = z[padz(base + 2 * H)], x3 = z[padz(base + 3 * H)];
  const float2 x4 = z[padz(base + 4 * H)], x5 = z[padz(base + 5 * H)];
  const float2 x6 = z[padz(base + 6 * H)], x7 = z[padz(base + 7 * H)];
  const float2 WA = make_float2(wa.x, sg * wa.y);
  const float2 WB = make_float2(wb.x, sg * wb.y);
  const float2 WC = make_float2(wc.x, sg * wc.y);
  const float2 WBp = make_float2(-sg * WB.y, sg * WB.x);  // WB * W4
  float2 t, u;
  t = TRIV ? x1 : cmulf(x1, WA); const float2 A0 = cadd(x0, t), A1 = csub(x0, t);
  t = TRIV ? x3 : cmulf(x3, WA); const float2 A2 = cadd(x2, t), A3 = csub(x2, t);
  t = TRIV ? x5 : cmulf(x5, WA); const float2 A4 = cadd(x4, t), A5 = csub(x4, t);
  t = TRIV ? x7 : cmulf(x7, WA); const float2 A6 = cadd(x6, t), A7 = csub(x6, t);
  t = TRIV ? A2 : cmulf(A2, WB);
  u = TRIV ? make_float2(-sg * A3.y, sg * A3.x) : cmulf(A3, WBp);
  const float2 B0 = cadd(A0, t), B2 = csub(A0, t);
  const float2 B1 = cadd(A1, u), B3 = csub(A1, u);
  t = TRIV ? A6 : cmulf(A6, WB);
  u = TRIV ? make_float2(-sg * A7.y, sg * A7.x) : cmulf(A7, WBp);
  const float2 B4 = cadd(A4, t), B6 = csub(A4, t);
  const float2 B5 = cadd(A5, u), B7 = csub(A5, u);
  const float r_ = 0.70710678118654752440f;
  const float2 F1 = TRIV ? make_float2(r_, sg * r_)
                         : cmulf(WC, make_float2(r_, sg * r_));
  const float2 F2 = TRIV ? make_float2(0.f, sg)
                         : make_float2(-sg * WC.y, sg * WC.x);
  const float2 F3 = TRIV ? make_float2(-r_, sg * r_)
                         : cmulf(WC, make_float2(-r_, sg * r_));
  t = TRIV ? B4 : cmulf(B4, WC);
  z[padz(base)]         = cadd(B0, t);
  z[padz(base + 4 * H)] = csub(B0, t);
  t = cmulf(B5, F1);
  z[padz(base + H)]     = cadd(B1, t);
  z[padz(base + 5 * H)] = csub(B1, t);
  t = cmulf(B6, F2);
  z[padz(base + 2 * H)] = cadd(B2, t);
  z[padz(base + 6 * H)] = csub(B2, t);
  t = cmulf(B7, F3);
  z[padz(base + 3 * H)] = cadd(B3, t);
  z[padz(base + 7 * H)] = csub(B3, t);
}

template <int FA, int FB>
__device__ __forceinline__ void scatter_buf(float2* z, const float (&s)[8],
                                            float wlo, float whi, int rlo, int rhi) {
  constexpr int iAlo = (FA > 0) ? FA - 1 : 0;
  constexpr int iAhi = (FA < 8) ? FA : 0;
  constexpr int iBlo = (FB > 0) ? FB - 1 : 0;
  constexpr int iBhi = (FB >= 0 && FB < 8) ? FB : 0;
  const float aLo = (FA == 0) ? 0.f : s[iAlo] * wlo;
  const float aHi = (FA == 8) ? 0.f : s[iAhi] * whi;
  const float bLo = (FB <= 0) ? 0.f : s[iBlo] * wlo;
  const float bHi = (FB < 0 || FB == 8) ? 0.f : s[iBhi] * whi;
  z[rlo] = make_float2(aLo, bLo);
  z[rhi] = make_float2(aHi, bHi);
}

template <int FA, int FB>
__device__ __forceinline__ void filt_pack(const float2* z, int k, float g,
                                          float2 cA, float2 cB,
                                          float2& Ck, float2& Cm) {
  const int q = (512 - k) & 511;
  const float2 Zk = z[padz(k)], Zq = z[padz(q)];
  const float sc = 0.5f / 256.f;
  const float ar = (Zk.x + Zq.x) * sc, ai = (Zk.y - Zq.y) * sc;
  float yar, yai, ybr = 0.f, ybi = 0.f;
  {
    const float pr = (ar * ar - ai * ai) * (1.f / 2313.f);
    const float pi = (2.f * ar * ai) * (1.f / 2313.f);
    yar = (pr * cA.x - pi * cA.y) * g;
    yai = (pr * cA.y + pi * cA.x) * g;
  }
  if (FB >= 0) {
    const float br = (Zk.y + Zq.y) * sc, bi = (Zq.x - Zk.x) * sc;
    const float pr = (br * br - bi * bi) * (1.f / 2313.f);
    const float pi = (2.f * br * bi) * (1.f / 2313.f);
    ybr = (pr * cB.x - pi * cB.y) * g;
    ybi = (pr * cB.y + pi * cB.x) * g;
  }
  if (k == 0 || k == 256) {
    Ck = make_float2(yar, ybr);
    Cm = Ck;
  } else {
    Ck = make_float2(yar - ybi, yai + ybr);
    Cm = make_float2(yar + ybi, ybr - yai);
  }
}

// one super-pass over up to 4 packed FFT buffers; wave w owns buffer w
template <int FA0, int FB0, int FA1, int FB1, int FA2, int FB2, int FA3, int FB3,
          int NBUF>
__device__ __forceinline__ void ecg_super4(int tid, float g,
                                           const float2* __restrict__ fc,
                                           const float (&s)[8], const float2 (&ptw)[6],
                                           float2 t8, float2* zA, float2* zB,
                                           float2* zC, float2* zD, float* accr) {
  const float c0 = t8.x;
  const float wlo = 0.5f - 0.5f * c0;
  const float whi = 0.5f + 0.5f * c0;
  float2 cA0 = fc[FA0 * 257 + tid];
  float2 cB0 = make_float2(0.f, 0.f), cA1 = cB0, cB1 = cB0;
  float2 cA2 = cB0, cB2 = cB0, cA3 = cB0, cB3 = cB0;
  if (FB0 >= 0) cB0 = fc[FB0 * 257 + tid];
  if (NBUF > 1) { cA1 = fc[FA1 * 257 + tid]; cB1 = fc[FB1 * 257 + tid]; }
  if (NBUF > 2) { cA2 = fc[FA2 * 257 + tid]; cB2 = fc[FB2 * 257 + tid]; }
  if (NBUF > 3) { cA3 = fc[FA3 * 257 + tid]; cB3 = fc[FB3 * 257 + tid]; }
  __syncthreads();  // prior OA reads done before scatter overwrites
  const int rlo = padz(rev9(tid)), rhi = padz(rev9(tid + 256));
  scatter_buf<FA0, FB0>(zA, s, wlo, whi, rlo, rhi);
  if (NBUF > 1) scatter_buf<FA1, FB1>(zB, s, wlo, whi, rlo, rhi);
  if (NBUF > 2) scatter_buf<FA2, FB2>(zC, s, wlo, whi, rlo, rhi);
  if (NBUF > 3) scatter_buf<FA3, FB3>(zD, s, wlo, whi, rlo, rhi);
  __syncthreads();
  const int wid = tid >> 6, l = tid & 63;
  if (wid < NBUF) {
    float2* zz = (wid == 0) ? zA : (wid == 1) ? zB : (wid == 2) ? zC : zD;
    pass8<1, -1, true>(zz, l, ptw[0], ptw[1], ptw[2]);
    pass8<8, -1, false>(zz, l, ptw[0], ptw[1], ptw[2]);
    pass8<64, -1, false>(zz, l, ptw[3], ptw[4], ptw[5]);
  }
  __syncthreads();
  float2 Ck0, Cm0, Ck1, Cm1, Ck2, Cm2, Ck3, Cm3;
  float2 Cn0, Cn1, Cn2, Cn3, dum;
  filt_pack<FA0, FB0>(zA, tid, g, cA0, cB0, Ck0, Cm0);
  if (NBUF > 1) filt_pack<FA1, FB1>(zB, tid, g, cA1, cB1, Ck1, Cm1);
  if (NBUF > 2) filt_pack<FA2, FB2>(zC, tid, g, cA2, cB2, Ck2, Cm2);
  if (NBUF > 3) filt_pack<FA3, FB3>(zD, tid, g, cA3, cB3, Ck3, Cm3);
  if (tid == 0) {
    float2 nA, nB = make_float2(0.f, 0.f);
    nA = fc[FA0 * 257 + 256];
    if (FB0 >= 0) nB = fc[FB0 * 257 + 256];
    filt_pack<FA0, FB0>(zA, 256, g, nA, nB, Cn0, dum);
    if (NBUF > 1) {
      nA = fc[FA1 * 257 + 256]; nB = fc[FB1 * 257 + 256];
      filt_pack<FA1, FB1>(zB, 256, g, nA, nB, Cn1, dum);
    }
    if (NBUF > 2) {
      nA = fc[FA2 * 257 + 256]; nB = fc[FB2 * 257 + 256];
      filt_pack<FA2, FB2>(zC, 256, g, nA, nB, Cn2, dum);
    }
    if (NBUF > 3) {
      nA = fc[FA3 * 257 + 256]; nB = fc[FB3 * 257 + 256];
      filt_pack<FA3, FB3>(zD, 256, g, nA, nB, Cn3, dum);
    }
  }
  __syncthreads();  // all Z reads done before pack-scatter
  {
    zA[rlo] = Ck0;
    if (NBUF > 1) zB[rlo] = Ck1;
    if (NBUF > 2) zC[rlo] = Ck2;
    if (NBUF > 3) zD[rlo] = Ck3;
    if (tid == 0) {
      zA[padz(1)] = Cn0;               // rev9(256) = 1
      if (NBUF > 1) zB[padz(1)] = Cn1;
      if (NBUF > 2) zC[padz(1)] = Cn2;
      if (NBUF > 3) zD[padz(1)] = Cn3;
    } else {
      const int rm = padz(rev9(512 - tid));
      zA[rm] = Cm0;
      if (NBUF > 1) zB[rm] = Cm1;
      if (NBUF > 2) zC[rm] = Cm2;
      if (NBUF > 3) zD[rm] = Cm3;
    }
  }
  __syncthreads();
  if (wid < NBUF) {
    float2* zz = (wid == 0) ? zA : (wid == 1) ? zB : (wid == 2) ? zC : zD;
    pass8<1, 1, true>(zz, l, ptw[0], ptw[1], ptw[2]);
    pass8<8, 1, false>(zz, l, ptw[0], ptw[1], ptw[2]);
    pass8<64, 1, false>(zz, l, ptw[3], ptw[4], ptw[5]);
  }
  __syncthreads();
  {
    const float2 vLo = zA[padz(tid)], vHi = zA[padz(tid + 256)];
    accr[FA0] += 0.5f * wlo * vLo.x;
    accr[FA0 + 1] += 0.5f * whi * vHi.x;
    if (FB0 >= 0) {
      accr[FB0] += 0.5f * wlo * vLo.y;
      accr[FB0 + 1] += 0.5f * whi * vHi.y;
    }
    if (NBUF > 1) {
      const float2 uLo = zB[padz(tid)], uHi = zB[padz(tid + 256)];
      accr[FA1] += 0.5f * wlo * uLo.x;
      accr[FA1 + 1] += 0.5f * whi * uHi.x;
      accr[FB1] += 0.5f * wlo * uLo.y;
      accr[FB1 + 1] += 0.5f * whi * uHi.y;
    }
    if (NBUF > 2) {
      const float2 uLo = zC[padz(tid)], uHi = zC[padz(tid + 256)];
      accr[FA2] += 0.5f * wlo * uLo.x;
      accr[FA2 + 1] += 0.5f * whi * uHi.x;
      accr[FB2] += 0.5f * wlo * uLo.y;
      accr[FB2 + 1] += 0.5f * whi * uHi.y;
    }
    if (NBUF > 3) {
      const float2 uLo = zD[padz(tid)], uHi = zD[padz(tid + 256)];
      accr[FA3] += 0.5f * wlo * uLo.x;
      accr[FA3 + 1] += 0.5f * whi * uHi.x;
      accr[FB3] += 0.5f * wlo * uLo.y;
      accr[FB3 + 1] += 0.5f * whi * uHi.y;
    }
  }
}

__global__ __launch_bounds__(256) void k_ecg_fft(
    const float* __restrict__ ecgT, const float2* __restrict__ FcT,
    const float* __restrict__ gate, const float2* __restrict__ twg,
    unsigned short* __restrict__ xtT) {
  const int bd = blockIdx.x;
  const int d = bd % D_;
  const int tid = threadIdx.x;

  __shared__ float2 zA[544], zB[544], zC[544], zD[544];  // 17 KB

  float s[8];
  const float* src = ecgT + (size_t)bd * S_;
#pragma unroll
  for (int k = 0; k < 8; ++k) s[k] = src[k * 256 + tid];

  const int l6 = tid & 63;
  float2 ptw[6];
  ptw[0] = twg[7 + (l6 & 7)];     // H=8:  W_16^j
  ptw[1] = twg[15 + (l6 & 7)];    // H=8:  W_32^j
  ptw[2] = twg[31 + (l6 & 7)];    // H=8:  W_64^j
  ptw[3] = twg[63 + l6];          // H=64: W_128^j
  ptw[4] = twg[127 + l6];         // H=64: W_256^j
  ptw[5] = twg[255 + l6];         // H=64: W_512^j
  const float2 t8 = twg[255 + tid];  // window / norm only

  const float g = gate[bd];
  const float2* fc = FcT + (size_t)d * NBINS_;
  float accr[10];
#pragma unroll
  for (int i = 0; i < 10; ++i) accr[i] = 0.f;

  ecg_super4<0, 8, 1, 2, 3, 4, 5, 6, 4>(tid, g, fc, s, ptw, t8, zA, zB, zC, zD, accr);
  ecg_super4<7, -1, 0, 0, 0, 0, 0, 0, 1>(tid, g, fc, s, ptw, t8, zA, zB, zC, zD, accr);

  const float c0 = t8.x;
  const float rinv = 1.0f / (0.5f + 0.5f * c0 * c0);
  unsigned short* dst = xtT + (size_t)bd * S_;
#pragma unroll
  for (int i2 = 0; i2 < 8; ++i2)
    dst[i2 * 256 + tid] = f2bf(accr[i2 + 1] * rinv + s[i2]);
}

// ---- per-(b,t) LN stats over d, reading bf16 xtT[b][d][t] as uint pairs ----
__global__ __launch_bounds__(256) void k_colstats_bf(const unsigned short* __restrict__ xtT,
                                                     float2* __restrict__ stats) {
  const int b = blockIdx.y;
  const int t0 = blockIdx.x * 128;
  const int tx = threadIdx.x & 63;
  const int ty = threadIdx.x >> 6;
  float s0 = 0.f, q0 = 0.f, s1 = 0.f, q1 = 0.f;
  const unsigned int* base = (const unsigned int*)(xtT + (size_t)b * D_ * S_);
  for (int dd = ty; dd < D_; dd += 4) {
    const unsigned int u = base[(size_t)dd * (S_ / 2) + (t0 >> 1) + tx];
    const float v0 = bf2f((unsigned short)(u & 0xffffu));
    const float v1 = bf2f((unsigned short)(u >> 16));
    s0 += v0; q0 = fmaf(v0, v0, q0);
    s1 += v1; q1 = fmaf(v1, v1, q1);
  }
  __shared__ float sh[4][64][4];
  sh[ty][tx][0] = s0; sh[ty][tx][1] = q0; sh[ty][tx][2] = s1; sh[ty][tx][3] = q1;
  __syncthreads();
  if (ty == 0) {
    s0 = sh[0][tx][0] + sh[1][tx][0] + sh[2][tx][0] + sh[3][tx][0];
    q0 = sh[0][tx][1] + sh[1][tx][1] + sh[2][tx][1] + sh[3][tx][1];
    s1 = sh[0][tx][2] + sh[1][tx][2] + sh[2][tx][2] + sh[3][tx][2];
    q1 = sh[0][tx][3] + sh[1][tx][3] + sh[2][tx][3] + sh[3][tx][3];
    stats[(size_t)b * S_ + t0 + 2 * tx]     = make_float2(s0, q0);
    stats[(size_t)b * S_ + t0 + 2 * tx + 1] = make_float2(s1, q1);
  }
}

// ---- transpose + LN apply, bf16 in -> bf16 out ----
__global__ __launch_bounds__(256) void k_transpose_ln(
    const unsigned short* __restrict__ xtT, const float2* __restrict__ stats,
    const float* __restrict__ g, const float* __restrict__ bia,
    unsigned short* __restrict__ xhat) {
  __shared__ float tile[32][33];
  const int b = blockIdx.z;
  const int t0 = blockIdx.x * 32;
  const int d0 = blockIdx.y * 32;
  const int tx = threadIdx.x & 31, ty = threadIdx.x >> 5;
  for (int i = ty; i < 32; i += 8)
    tile[i][tx] = bf2f(xtT[((size_t)b * D_ + d0 + i) * S_ + t0 + tx]);
  __syncthreads();
  const float gv = g[d0 + tx], bv = bia[d0 + tx];
  for (int i = ty; i < 32; i += 8) {
    const float2 st = stats[(size_t)b * S_ + t0 + i];
    const float mean = st.x * (1.0f / 768.0f);
    const float var = st.y * (1.0f / 768.0f) - mean * mean;
    const float inv = rsqrtf(var + 1e-5f);
    xhat[((size_t)b * S_ + t0 + i) * D_ + d0 + tx] =
        f2bf((tile[tx][i] - mean) * inv * gv + bv);
  }
}

// ---- dual-segment LayerNorm, bf16 in -> f32 out ----
__global__ __launch_bounds__(256) void k_layernorm_dual(
    const unsigned short* __restrict__ x1, const float* __restrict__ g1,
    const float* __restrict__ b1, float* __restrict__ o1, int n1,
    const unsigned short* __restrict__ x2, const float* __restrict__ g2,
    const float* __restrict__ b2, float* __restrict__ o2) {
  int row = blockIdx.x;
  const unsigned short* x; const float *g, *b; float* o;
  if (row < n1) { x = x1; g = g1; b = b1; o = o1; }
  else { row -= n1; x = x2; g = g2; b = b2; o = o2; }
  const int tid = threadIdx.x;
  const unsigned short* xr = x + (size_t)row * D_;
  const float v0 = bf2f(xr[tid]), v1 = bf2f(xr[tid + 256]), v2 = bf2f(xr[tid + 512]);
  float s = v0 + v1 + v2;
  float q = v0 * v0 + v1 * v1 + v2 * v2;
  __shared__ float red[8];
  for (int off = 32; off > 0; off >>= 1) {
    s += __shfl_down(s, off);
    q += __shfl_down(q, off);
  }
  if ((tid & 63) == 0) { red[tid >> 6] = s; red[4 + (tid >> 6)] = q; }
  __syncthreads();
  s = red[0] + red[1] + red[2] + red[3];
  q = red[4] + red[5] + red[6] + red[7];
  const float mean = s * (1.0f / 768.0f);
  const float var = q * (1.0f / 768.0f) - mean * mean;
  const float inv = rsqrtf(var + 1e-5f);
  float* orow = o + (size_t)row * D_;
  orow[tid]       = (v0 - mean) * inv * g[tid]       + b[tid];
  orow[tid + 256] = (v1 - mean) * inv * g[tid + 256] + b[tid + 256];
  orow[tid + 512] = (v2 - mean) * inv * g[tid + 512] + b[tid + 512];
}

// ---------- dual-segment MFMA GEMM, double-buffered pipeline ----------
// MODE 0: exact GELU -> bf16 ; MODE 1: +resid(bf16) -> bf16
template <int MODE>
__global__ __launch_bounds__(256) void k_gemm_dual(
    const unsigned short* __restrict__ A1, const unsigned short* __restrict__ W1,
    const float* __restrict__ b1, const unsigned short* __restrict__ r1,
    unsigned short* __restrict__ o1, int M1, int nby1,
    const unsigned short* __restrict__ A2, const unsigned short* __restrict__ W2,
    const float* __restrict__ b2, const unsigned short* __restrict__ r2,
    unsigned short* __restrict__ o2, int M2) {
  __shared__ unsigned short Asm[2][128 * 64];
  __shared__ unsigned short Bsm[2][128 * 64];
  const int tid = threadIdx.x;
  const int lane = tid & 63, wid = tid >> 6;
  const int wr = wid >> 1, wc = wid & 1;
  int bx, by;
  {
    const int nwg = gridDim.x * gridDim.y;
    const int bid = blockIdx.y * gridDim.x + blockIdx.x;
    const int xcd = bid & 7, lin = bid >> 3;
    const int qq = nwg >> 3, rr = nwg & 7;
    const int nbid = (xcd < rr) ? xcd * (qq + 1) + lin
                                : rr * (qq + 1) + (xcd - rr) * qq + lin;
    bx = nbid % gridDim.x;
    by = nbid / gridDim.x;
  }
  const unsigned short* Abf; const unsigned short* Wbf; const float* bias;
  const unsigned short* resid; unsigned short* outb; int M;
  if (by < nby1) { Abf = A1; Wbf = W1; bias = b1; resid = r1; outb = o1; M = M1; }
  else { by -= nby1; Abf = A2; Wbf = W2; bias = b2; resid = r2; outb = o2; M = M2; }
  const int n0 = bx * 128, m0 = by * 128;

  auto STAGE = [&](int buf, int kt) {
    const int k0 = kt * 64;
#pragma unroll
    for (int i = 0; i < 4; ++i) {
      const int c = tid + 256 * i;
      const int row = c >> 3, sl = c & 7;
      const int gsl = sl ^ (row & 7);
      gload16(Abf + (size_t)(m0 + row) * 768 + k0 + gsl * 8, &Asm[buf][c * 8]);
      gload16(Wbf + (size_t)(n0 + row) * 768 + k0 + gsl * 8, &Bsm[buf][c * 8]);
    }
  };

  f32x4 acc[4][4] = {};
  STAGE(0, 0);
  for (int kt = 0; kt < 12; ++kt) {
    const int cur = kt & 1;
    if (kt < 11) {
      STAGE(cur ^ 1, kt + 1);
      asm volatile("s_waitcnt vmcnt(8)" ::: "memory");
    } else {
      asm volatile("s_waitcnt vmcnt(0)" ::: "memory");
    }
    __builtin_amdgcn_sched_barrier(0);
    __builtin_amdgcn_s_barrier();
#pragma unroll
    for (int ks = 0; ks < 2; ++ks) {
      bf16x8 af[4], bfv[4];
#pragma unroll
      for (int mi = 0; mi < 4; ++mi) {
        const int row = wr * 64 + mi * 16 + (lane & 15);
        const int sl = (ks * 4 + (lane >> 4)) ^ (row & 7);
        af[mi] = *(const bf16x8*)((const char*)Asm[cur] + row * 128 + sl * 16);
      }
#pragma unroll
      for (int ni = 0; ni < 4; ++ni) {
        const int row = wc * 64 + ni * 16 + (lane & 15);
        const int sl = (ks * 4 + (lane >> 4)) ^ (row & 7);
        bfv[ni] = *(const bf16x8*)((const char*)Bsm[cur] + row * 128 + sl * 16);
      }
#pragma unroll
      for (int mi = 0; mi < 4; ++mi)
#pragma unroll
        for (int ni = 0; ni < 4; ++ni)
          acc[mi][ni] = __builtin_amdgcn_mfma_f32_16x16x32_bf16(af[mi], bfv[ni],
                                                                acc[mi][ni], 0, 0, 0);
    }
    __builtin_amdgcn_sched_barrier(0);
    __builtin_amdgcn_s_barrier();
  }
#pragma unroll
  for (int mi = 0; mi < 4; ++mi) {
#pragma unroll
    for (int ni = 0; ni < 4; ++ni) {
      const int col = n0 + wc * 64 + ni * 16 + (lane & 15);
#pragma unroll
      for (int e = 0; e < 4; ++e) {
        const int row = m0 + wr * 64 + mi * 16 + (lane >> 4) * 4 + e;
        if (row >= M) continue;
        float v = acc[mi][ni][e] + bias[col];
        if (MODE == 0) {
          v = gelu_f(v);
        } else {
          v += bf2f(resid[(size_t)row * 768 + col]);
        }
        outb[(size_t)row * 768 + col] = f2bf(v);
      }
    }
  }
}

}  // namespace

extern "C" void kernel_launch(void* const* d_in, const int* in_sizes, int n_in,
                              void* d_out, int out_size, void* d_ws, size_t ws_size,
                              hipStream_t stream) {
  (void)in_sizes; (void)n_in; (void)out_size; (void)ws_size;
  const float* ecg     = (const float*)d_in[0];
  const float* image   = (const float*)d_in[1];
  const float* ebank   = (const float*)d_in[2];
  const float* cbank   = (const float*)d_in[3];
  const float* gsel    = (const float*)d_in[4];
  const float* gw      = (const float*)d_in[5];
  const float* gb      = (const float*)d_in[6];
  const float* e_ln1_g = (const float*)d_in[7];
  const float* e_ln1_b = (const float*)d_in[8];
  const float* e_w1    = (const float*)d_in[9];
  const float* e_b1    = (const float*)d_in[10];
  const float* e_w2    = (const float*)d_in[11];
  const float* e_b2    = (const float*)d_in[12];
  const float* e_ln2_g = (const float*)d_in[13];
  const float* e_ln2_b = (const float*)d_in[14];
  const float* c_ln1_g = (const float*)d_in[15];
  const float* c_ln1_b = (const float*)d_in[16];
  const float* c_w1    = (const float*)d_in[17];
  const float* c_b1    = (const float*)d_in[18];
  const float* c_w2    = (const float*)d_in[19];
  const float* c_b2    = (const float*)d_in[20];
  const float* c_ln2_g = (const float*)d_in[21];
  const float* c_ln2_b = (const float*)d_in[22];

  float* out = (float*)d_out;
  float* ws = (float*)d_ws;

  constexpr size_t TXT = (size_t)8 * 2048 * 768;   // 12,582,912 floats
  constexpr size_t IMG = (size_t)8 * 196 * 768;    // 1,204,224 elems

  // ws layout: A | Bb | wbf | gatev | stats | gpart | twg | twN
  float* A  = ws;
  float* Bb = A + TXT;
  unsigned short* wbf = (unsigned short*)(Bb + TXT);
  unsigned short* ew1b = wbf;
  unsigned short* ew2b = wbf + NW_;
  unsigned short* cw1b = wbf + 2 * NW_;
  unsigned short* cw2b = wbf + 3 * NW_;
  float* gatev = (float*)(wbf + 4 * (size_t)NW_);
  float2* stats = (float2*)(gatev + 8 * 768);
  float* gpart = (float*)(stats + 8 * 2048);   // 8*11*768 floats
  float2* twg = (float2*)(gpart + 8 * 11 * 768);
  float2* twN = twg + 511;

  float2* FcT = (float2*)out;  // parked in d_out (dead before final LN)

  // text buffers: A = xhat (first half, bf16) | y_tb (second half, bf16)
  unsigned short* xhat = (unsigned short*)A;
  unsigned short* y_tb = (unsigned short*)A + TXT;
  // Bb first half: xtT then h_t (bf16); second half: image scratch
  unsigned short* xtT = (unsigned short*)Bb;
  unsigned short* h_t = (unsigned short*)Bb;
  float* Bb2 = Bb + TXT / 2;
  float2* imgF = (float2*)Bb2;                               // 1,216,512 floats
  float* xi = Bb2 + 1216512;                                 // 1,204,224 floats
  unsigned short* xh_i = (unsigned short*)(xi + IMG);        // bf16 LN1 / resid
  unsigned short* h_i  = xh_i + IMG;
  unsigned short* y_ib = h_i + IMG;

  // ---- one-time prep (fused) ----
  k_prep<<<PREP_WALL + PREP_FC + 3, 256, 0, stream>>>(
      e_w1, e_w2, c_w1, c_w2, wbf, (const float2*)ebank, FcT, twg, twN);

  // ---- image path front (produces gate + xh_i) ----
  k_img_dft_f<<<dim3(11, 3, 8), 256, 0, stream>>>(image, (const float2*)cbank,
                                                  (const float2*)gsel, twN, imgF, gpart);
  k_gate_mm2<<<48, 256, 0, stream>>>(gpart, gw, gb, gatev);
  k_img_idft<<<dim3(14, 3, 8), 256, 0, stream>>>(imgF, image, twN, xi);
  k_layernorm_f2b<<<1568, 256, 0, stream>>>(xi, c_ln1_g, c_ln1_b, xh_i);

  // ---- ecg path ----
  k_transpose_g<<<dim3(24, 64, 8), 256, 0, stream>>>(ecg, A, 2048, 768);
  k_ecg_fft<<<8 * 768, 256, 0, stream>>>(A, FcT, gatev, twg, xtT);
  k_colstats_bf<<<dim3(16, 8), 256, 0, stream>>>(xtT, stats);
  k_transpose_ln<<<dim3(64, 24, 8), 256, 0, stream>>>(xtT, stats, e_ln1_g, e_ln1_b, xhat);

  // ---- combined FFN: text (128 by-blocks) + image (13 by-blocks) ----
  k_gemm_dual<0><<<dim3(6, 141), 256, 0, stream>>>(
      xhat, ew1b, e_b1, nullptr, h_t, 16384, 128,
      xh_i, cw1b, c_b1, nullptr, h_i, 1568);
  k_gemm_dual<1><<<dim3(6, 141), 256, 0, stream>>>(
      h_t, ew2b, e_b2, xhat, y_tb, 16384, 128,
      h_i, cw2b, c_b2, xh_i, y_ib, 1568);
  k_layernorm_dual<<<16384 + 1568, 256, 0, stream>>>(
      y_tb, e_ln2_g, e_ln2_b, out, 16384,
      y_ib, c_ln2_g, c_ln2_b, out + TXT);
}

// Round 16
// 389.917 us; speedup vs baseline: 1.1575x; 1.0582x over previous
//
#include <hip/hip_runtime.h>
#include <math.h>

namespace {

constexpr int B_ = 8;
constexpr int S_ = 2048;
constexpr int D_ = 768;
constexpr int N_ = 196;     // image spatial
constexpr int NF_ = 99;     // image freq bins
constexpr int NFREQ_ = 257;
constexpr int NSEG_ = 9;
constexpr int NBINS_ = NFREQ_ * NSEG_;  // 2313
constexpr int NW_ = D_ * D_;            // 589824
constexpr float TWOPI_ = 6.28318530717958647692f;

using bf16x8 = __attribute__((ext_vector_type(8))) short;
using f32x4  = __attribute__((ext_vector_type(4))) float;

__device__ __forceinline__ int rev9(int x) { return (int)(__brev((unsigned)x) >> 23); }
__device__ __forceinline__ int padz(int i) { return i + (i >> 4); }

__device__ __forceinline__ unsigned short f2bf(float x) {
  unsigned u = __float_as_uint(x);
  u = (u + 0x7FFFu + ((u >> 16) & 1u)) >> 16;
  return (unsigned short)u;
}
__device__ __forceinline__ float bf2f(unsigned short h) {
  return __uint_as_float(((unsigned)h) << 16);
}

// exact GELU via Abramowitz-Stegun 7.1.26 erf (|eps| <= 1.5e-7)
__device__ __forceinline__ float gelu_f(float v) {
  const float x = fabsf(v) * 0.70710678118654752440f;
  const float t = 1.0f / fmaf(0.3275911f, x, 1.0f);
  float p = fmaf(fmaf(fmaf(fmaf(1.061405429f, t, -1.453152027f), t, 1.421413741f),
                      t, -0.284496736f), t, 0.254829592f);
  const float e = __expf(-x * x);
  const float er = 1.0f - p * t * e;
  return 0.5f * v * (1.0f + ((v < 0.f) ? -er : er));
}

__device__ __forceinline__ void gload16(const void* g, void* l) {
  __builtin_amdgcn_global_load_lds((const __attribute__((address_space(1))) void*)g,
                                   (__attribute__((address_space(3))) void*)l, 16, 0, 0);
}

__device__ __forceinline__ float2 cmulf(float2 a, float2 b) {
  return make_float2(a.x * b.x - a.y * b.y, a.x * b.y + a.y * b.x);
}
__device__ __forceinline__ float2 cadd(float2 a, float2 b) {
  return make_float2(a.x + b.x, a.y + b.y);
}
__device__ __forceinline__ float2 csub(float2 a, float2 b) {
  return make_float2(a.x - b.x, a.y - b.y);
}

// ---------------- batched transpose (B,R,C) -> (B,C,R) ----------------
__global__ __launch_bounds__(256) void k_transpose_g(const float* __restrict__ src,
                                                     float* __restrict__ dst,
                                                     int R, int C) {
  __shared__ float tile[32][33];
  const int b = blockIdx.z;
  const int c0 = blockIdx.x * 32;
  const int r0 = blockIdx.y * 32;
  const int tx = threadIdx.x & 31, ty = threadIdx.x >> 5;
  for (int i = ty; i < 32; i += 8)
    tile[i][tx] = src[((size_t)b * R + r0 + i) * C + c0 + tx];
  __syncthreads();
  for (int i = ty; i < 32; i += 8)
    dst[((size_t)b * C + c0 + i) * R + r0 + tx] = tile[tx][i];
}

// ---- prep: weight bf16 conv (4 mats) + twiddle tables ----
constexpr int PREP_W = (NW_ + 255) / 256;
constexpr int PREP_WALL = 4 * PREP_W;
__global__ __launch_bounds__(256) void k_prep(
    const float* __restrict__ w0, const float* __restrict__ w1,
    const float* __restrict__ w2, const float* __restrict__ w3,
    unsigned short* __restrict__ wbf, float2* __restrict__ twg,
    float2* __restrict__ twN) {
  const int bid = blockIdx.x;
  if (bid < PREP_WALL) {
    const int m = bid / PREP_W;
    const int i = (bid - m * PREP_W) * 256 + threadIdx.x;
    if (i >= NW_) return;
    const float* src = (m == 0) ? w0 : (m == 1) ? w1 : (m == 2) ? w2 : w3;
    wbf[(size_t)m * NW_ + i] = f2bf(src[i]);
  } else if (bid < PREP_WALL + 2) {
    const int i = (bid - PREP_WALL) * 256 + threadIdx.x;
    if (i >= 511) return;
    const int v = i + 1;
    const int h = 1 << (31 - __clz(v));
    const int j = v - h;
    float sn, cs;
    sincosf((float)j * ((TWOPI_ * 0.5f) / (float)h), &sn, &cs);
    twg[i] = make_float2(cs, sn);
  } else {
    const int i = threadIdx.x;
    if (i >= N_) return;
    float sn, cs;
    sincosf(TWOPI_ * (float)i / (float)N_, &sn, &cs);
    twN[i] = make_float2(cs, sn);
  }
}

// ---- filter-bank combine + transpose, both sides coalesced ----
// FcT[d][f][k] = -(e0[k*9+f][d] + e1[k*9+f][d]);  grid (d0:24, k0:9, f:9)
__global__ __launch_bounds__(256) void k_fc_t(const float2* __restrict__ e2,
                                              float2* __restrict__ FcT) {
  __shared__ float2 tile[32][33];
  const int d0 = blockIdx.x * 32;
  const int k0 = blockIdx.y * 32;
  const int f = blockIdx.z;
  const int tx = threadIdx.x & 31, ty = threadIdx.x >> 5;
  for (int i = ty; i < 32; i += 8) {
    const int k = k0 + i;
    if (k < NFREQ_) {
      const size_t s = (size_t)(k * 9 + f) * D_ + d0 + tx;
      const float2 a = e2[s];
      const float2 b = e2[(size_t)NBINS_ * D_ + s];
      tile[i][tx] = make_float2(-(a.x + b.x), -(a.y + b.y));
    }
  }
  __syncthreads();
  const int k = k0 + tx;
  if (k < NFREQ_) {
    for (int i = ty; i < 32; i += 8)
      FcT[(size_t)(d0 + i) * NBINS_ + f * 257 + k] = tile[tx][i];
  }
}

// ---- image forward DFT + filter + gate partials ----
__global__ __launch_bounds__(256) void k_img_dft_f(
    const float* __restrict__ image, const float2* __restrict__ bank2,
    const float2* __restrict__ gsel2, const float2* __restrict__ twN,
    float2* __restrict__ imgF, float* __restrict__ part) {
  const int fg = blockIdx.x;
  const int f0 = fg * 9;
  const int d = blockIdx.y * 256 + threadIdx.x;
  const int b = blockIdx.z;
  __shared__ float2 tws[9 * N_];
  for (int idx = threadIdx.x; idx < 9 * N_; idx += 256) {
    const int fi = idx / N_;
    const int t = idx - fi * N_;
    tws[idx] = twN[((f0 + fi) * t) % N_];
  }
  __syncthreads();
  float re[9] = {}, im[9] = {};
  const float* ip = image + (size_t)b * N_ * D_ + d;
  for (int t = 0; t < N_; ++t) {
    const float v = ip[(size_t)t * D_];
#pragma unroll
    for (int fi = 0; fi < 9; ++fi) {
      const float2 w = tws[fi * N_ + t];
      re[fi] = fmaf(v, w.x, re[fi]);
      im[fi] = fmaf(-v, w.y, im[fi]);
    }
  }
  const float sc = 1.0f / (196.0f * 99.0f);
  float gp = 0.f;
#pragma unroll
  for (int fi = 0; fi < 9; ++fi) {
    const int f = f0 + fi;
    const float pr = (re[fi] * re[fi] - im[fi] * im[fi]) * sc;
    const float pi2 = (2.f * re[fi] * im[fi]) * sc;
    const size_t fd = (size_t)f * D_ + d;
    const float2 c0 = bank2[fd];
    const float2 c1 = bank2[(size_t)NF_ * D_ + fd];
    const float fcr = -(c0.x + c1.x), fci = -(c0.y + c1.y);
    const float zr = pr * fcr - pi2 * fci;
    const float zi = pr * fci + pi2 * fcr;
    imgF[(size_t)(b * NF_ + f) * D_ + d] = make_float2(zr, zi);
    const float2 gw = gsel2[fd];
    gp += zr * gw.x - zi * gw.y;
  }
  part[((size_t)b * 11 + fg) * D_ + d] = gp;
}

// ---- gate matvec, folds 11 partials: gate[b][d0..d0+16) ----
__global__ __launch_bounds__(256) void k_gate_mm2(const float* __restrict__ part,
                                                  const float* __restrict__ W,
                                                  const float* __restrict__ bias,
                                                  float* __restrict__ gate) {
  __shared__ float row[8][D_];
  __shared__ float red[16][16][8];
  const int tid = threadIdx.x;
  const int d0 = blockIdx.x * 16;
  for (int i = tid; i < 8 * D_; i += 256) {
    const int b = i / D_, e = i - b * D_;
    float s = 0.f;
    for (int p = 0; p < 11; ++p) s += part[((size_t)b * 11 + p) * D_ + e];
    row[b][e] = s * (1.0f / 99.0f);
  }
  __syncthreads();
  const int dl = tid >> 4;
  const int ec = tid & 15;
  const float* w = W + (size_t)(d0 + dl) * D_ + ec * 48;
  float acc[8] = {};
  for (int e = 0; e < 48; e += 4) {
    const float4 wv = *reinterpret_cast<const float4*>(w + e);
    const int eg = ec * 48 + e;
#pragma unroll
    for (int b = 0; b < 8; ++b) {
      acc[b] = fmaf(row[b][eg], wv.x, acc[b]);
      acc[b] = fmaf(row[b][eg + 1], wv.y, acc[b]);
      acc[b] = fmaf(row[b][eg + 2], wv.z, acc[b]);
      acc[b] = fmaf(row[b][eg + 3], wv.w, acc[b]);
    }
  }
#pragma unroll
  for (int b = 0; b < 8; ++b) red[dl][ec][b] = acc[b];
  __syncthreads();
  if (tid < 128) {
    const int dl2 = tid >> 3, b = tid & 7;
    float s = bias[d0 + dl2];
    for (int c = 0; c < 16; ++c) s += red[dl2][c][b];
    gate[b * D_ + d0 + dl2] = s;
  }
}

// ---- image inverse DFT (ortho) + residual ----
__global__ __launch_bounds__(256) void k_img_idft(
    const float2* __restrict__ imgF, const float* __restrict__ image,
    const float2* __restrict__ twN, float* __restrict__ xi) {
  const int t0 = blockIdx.x * 14;
  const int d = blockIdx.y * 256 + threadIdx.x;
  const int b = blockIdx.z;
  __shared__ float2 tws[14 * NF_];
  for (int idx = threadIdx.x; idx < 14 * NF_; idx += 256) {
    const int ti = idx / NF_;
    const int f = idx - ti * NF_;
    tws[idx] = twN[((t0 + ti) * f) % N_];
  }
  __syncthreads();
  const float2* zp = imgF + (size_t)b * NF_ * D_ + d;
  const float2 z0 = zp[0];
  const float2 zny = zp[(size_t)(NF_ - 1) * D_];
  float acc[14];
#pragma unroll
  for (int ti = 0; ti < 14; ++ti)
    acc[ti] = z0.x + (((t0 + ti) & 1) ? -zny.x : zny.x);
  for (int f = 1; f < NF_ - 1; ++f) {
    const float2 z = zp[(size_t)f * D_];
#pragma unroll
    for (int ti = 0; ti < 14; ++ti) {
      const float2 w = tws[ti * NF_ + f];
      acc[ti] += 2.f * (z.x * w.x - z.y * w.y);
    }
  }
#pragma unroll
  for (int ti = 0; ti < 14; ++ti) {
    const size_t idx = (size_t)(b * N_ + t0 + ti) * D_ + d;
    xi[idx] = acc[ti] * (1.0f / 14.0f) + image[idx];
  }
}

// ---------------- LayerNorm f32 in -> bf16 out ----------------
__global__ __launch_bounds__(256) void k_layernorm_f2b(const float* __restrict__ x,
                                                       const float* __restrict__ g,
                                                       const float* __restrict__ b,
                                                       unsigned short* __restrict__ out) {
  const int row = blockIdx.x;
  const int tid = threadIdx.x;
  const float* xr = x + (size_t)row * D_;
  const float v0 = xr[tid], v1 = xr[tid + 256], v2 = xr[tid + 512];
  float s = v0 + v1 + v2;
  float q = v0 * v0 + v1 * v1 + v2 * v2;
  __shared__ float red[8];
  for (int off = 32; off > 0; off >>= 1) {
    s += __shfl_down(s, off);
    q += __shfl_down(q, off);
  }
  if ((tid & 63) == 0) { red[tid >> 6] = s; red[4 + (tid >> 6)] = q; }
  __syncthreads();
  s = red[0] + red[1] + red[2] + red[3];
  q = red[4] + red[5] + red[6] + red[7];
  const float mean = s * (1.0f / 768.0f);
  const float var = q * (1.0f / 768.0f) - mean * mean;
  const float inv = rsqrtf(var + 1e-5f);
  unsigned short* orow = out + (size_t)row * D_;
  orow[tid]       = f2bf((v0 - mean) * inv * g[tid]       + b[tid]);
  orow[tid + 256] = f2bf((v1 - mean) * inv * g[tid + 256] + b[tid + 256]);
  orow[tid + 512] = f2bf((v2 - mean) * inv * g[tid + 512] + b[tid + 512]);
}

// ================= ecg fused FFT pipeline (radix-8, 4 buffers/block) ===========
template <int H, int DIR, bool TRIV>
__device__ __forceinline__ void pass8(float2* z, int l,
                                      float2 wa, float2 wb, float2 wc) {
  asm volatile("s_waitcnt lgkmcnt(0)" ::: "memory");
  const float sg = (DIR < 0) ? -1.f : 1.f;
  const int base = (H == 1) ? (l << 3)
                 : (H == 8) ? (((l >> 3) << 6) | (l & 7))
                            : l;
  const float2 x0 = z[padz(base)],         x1 = z[padz(base + H)];
  const float2 x2 = z[padz(base + 2 * H)], x3 = z[padz(base + 3 * H)];
  const float2 x4 = z[padz(base + 4 * H)], x5 = z[padz(base + 5 * H)];
  const float2 x6 = z[padz(base + 6 * H)], x7 = z[padz(base + 7 * H)];
  const float2 WA = make_float2(wa.x, sg * wa.y);
  const float2 WB = make_float2(wb.x, sg * wb.y);
  const float2 WC = make_float2(wc.x, sg * wc.y);
  const float2 WBp = make_float2(-sg * WB.y, sg * WB.x);  // WB * W4
  float2 t, u;
  t = TRIV ? x1 : cmulf(x1, WA); const float2 A0 = cadd(x0, t), A1 = csub(x0, t);
  t = TRIV ? x3 : cmulf(x3, WA); const float2 A2 = cadd(x2, t), A3 = csub(x2, t);
  t = TRIV ? x5 : cmulf(x5, WA); const float2 A4 = cadd(x4, t), A5 = csub(x4, t);
  t = TRIV ? x7 : cmulf(x7, WA); const float2 A6 = cadd(x6, t), A7 = csub(x6, t);
  t = TRIV ? A2 : cmulf(A2, WB);
  u = TRIV ? make_float2(-sg * A3.y, sg * A3.x) : cmulf(A3, WBp);
  const float2 B0 = cadd(A0, t), B2 = csub(A0, t);
  const float2 B1 = cadd(A1, u), B3 = csub(A1, u);
  t = TRIV ? A6 : cmulf(A6, WB);
  u = TRIV ? make_float2(-sg * A7.y, sg * A7.x) : cmulf(A7, WBp);
  const float2 B4 = cadd(A4, t), B6 = csub(A4, t);
  const float2 B5 = cadd(A5, u), B7 = csub(A5, u);
  const float r_ = 0.70710678118654752440f;
  const float2 F1 = TRIV ? make_float2(r_, sg * r_)
                         : cmulf(WC, make_float2(r_, sg * r_));
  const float2 F2 = TRIV ? make_float2(0.f, sg)
                         : make_float2(-sg * WC.y, sg * WC.x);
  const float2 F3 = TRIV ? make_float2(-r_, sg * r_)
                         : cmulf(WC, make_float2(-r_, sg * r_));
  t = TRIV ? B4 : cmulf(B4, WC);
  z[padz(base)]         = cadd(B0, t);
  z[padz(base + 4 * H)] = csub(B0, t);
  t = cmulf(B5, F1);
  z[padz(base + H)]     = cadd(B1, t);
  z[padz(base + 5 * H)] = csub(B1, t);
  t = cmulf(B6, F2);
  z[padz(base + 2 * H)] = cadd(B2, t);
  z[padz(base + 6 * H)] = csub(B2, t);
  t = cmulf(B7, F3);
  z[padz(base + 3 * H)] = cadd(B3, t);
  z[padz(base + 7 * H)] = csub(B3, t);
}

template <int FA, int FB>
__device__ __forceinline__ void scatter_buf(float2* z, const float (&s)[8],
                                            float wlo, float whi, int rlo, int rhi) {
  constexpr int iAlo = (FA > 0) ? FA - 1 : 0;
  constexpr int iAhi = (FA < 8) ? FA : 0;
  constexpr int iBlo = (FB > 0) ? FB - 1 : 0;
  constexpr int iBhi = (FB >= 0 && FB < 8) ? FB : 0;
  const float aLo = (FA == 0) ? 0.f : s[iAlo] * wlo;
  const float aHi = (FA == 8) ? 0.f : s[iAhi] * whi;
  const float bLo = (FB <= 0) ? 0.f : s[iBlo] * wlo;
  const float bHi = (FB < 0 || FB == 8) ? 0.f : s[iBhi] * whi;
  z[rlo] = make_float2(aLo, bLo);
  z[rhi] = make_float2(aHi, bHi);
}

template <int FA, int FB>
__device__ __forceinline__ void filt_pack(const float2* z, int k, float g,
                                          float2 cA, float2 cB,
                                          float2& Ck, float2& Cm) {
  const int q = (512 - k) & 511;
  const float2 Zk = z[padz(k)], Zq = z[padz(q)];
  const float sc = 0.5f / 256.f;
  const float ar = (Zk.x + Zq.x) * sc, ai = (Zk.y - Zq.y) * sc;
  float yar, yai, ybr = 0.f, ybi = 0.f;
  {
    const float pr = (ar * ar - ai * ai) * (1.f / 2313.f);
    const float pi = (2.f * ar * ai) * (1.f / 2313.f);
    yar = (pr * cA.x - pi * cA.y) * g;
    yai = (pr * cA.y + pi * cA.x) * g;
  }
  if (FB >= 0) {
    const float br = (Zk.y + Zq.y) * sc, bi = (Zq.x - Zk.x) * sc;
    const float pr = (br * br - bi * bi) * (1.f / 2313.f);
    const float pi = (2.f * br * bi) * (1.f / 2313.f);
    ybr = (pr * cB.x - pi * cB.y) * g;
    ybi = (pr * cB.y + pi * cB.x) * g;
  }
  if (k == 0 || k == 256) {
    Ck = make_float2(yar, ybr);
    Cm = Ck;
  } else {
    Ck = make_float2(yar - ybi, yai + ybr);
    Cm = make_float2(yar + ybi, ybr - yai);
  }
}

// one super-pass over up to 4 packed FFT buffers; wave w owns buffer w
template <int FA0, int FB0, int FA1, int FB1, int FA2, int FB2, int FA3, int FB3,
          int NBUF>
__device__ __forceinline__ void ecg_super4(int tid, float g,
                                           const float2* __restrict__ fc,
                                           const float (&s)[8], const float2 (&ptw)[6],
                                           float2 t8, float2* zA, float2* zB,
                                           float2* zC, float2* zD, float* accr) {
  const float c0 = t8.x;
  const float wlo = 0.5f - 0.5f * c0;
  const float whi = 0.5f + 0.5f * c0;
  float2 cA0 = fc[FA0 * 257 + tid];
  float2 cB0 = make_float2(0.f, 0.f), cA1 = cB0, cB1 = cB0;
  float2 cA2 = cB0, cB2 = cB0, cA3 = cB0, cB3 = cB0;
  if (FB0 >= 0) cB0 = fc[FB0 * 257 + tid];
  if (NBUF > 1) { cA1 = fc[FA1 * 257 + tid]; cB1 = fc[FB1 * 257 + tid]; }
  if (NBUF > 2) { cA2 = fc[FA2 * 257 + tid]; cB2 = fc[FB2 * 257 + tid]; }
  if (NBUF > 3) { cA3 = fc[FA3 * 257 + tid]; cB3 = fc[FB3 * 257 + tid]; }
  __syncthreads();  // prior OA reads done before scatter overwrites
  const int rlo = padz(rev9(tid)), rhi = padz(rev9(tid + 256));
  scatter_buf<FA0, FB0>(zA, s, wlo, whi, rlo, rhi);
  if (NBUF > 1) scatter_buf<FA1, FB1>(zB, s, wlo, whi, rlo, rhi);
  if (NBUF > 2) scatter_buf<FA2, FB2>(zC, s, wlo, whi, rlo, rhi);
  if (NBUF > 3) scatter_buf<FA3, FB3>(zD, s, wlo, whi, rlo, rhi);
  __syncthreads();
  const int wid = tid >> 6, l = tid & 63;
  if (wid < NBUF) {
    float2* zz = (wid == 0) ? zA : (wid == 1) ? zB : (wid == 2) ? zC : zD;
    pass8<1, -1, true>(zz, l, ptw[0], ptw[1], ptw[2]);
    pass8<8, -1, false>(zz, l, ptw[0], ptw[1], ptw[2]);
    pass8<64, -1, false>(zz, l, ptw[3], ptw[4], ptw[5]);
  }
  __syncthreads();
  float2 Ck0, Cm0, Ck1, Cm1, Ck2, Cm2, Ck3, Cm3;
  float2 Cn0, Cn1, Cn2, Cn3, dum;
  filt_pack<FA0, FB0>(zA, tid, g, cA0, cB0, Ck0, Cm0);
  if (NBUF > 1) filt_pack<FA1, FB1>(zB, tid, g, cA1, cB1, Ck1, Cm1);
  if (NBUF > 2) filt_pack<FA2, FB2>(zC, tid, g, cA2, cB2, Ck2, Cm2);
  if (NBUF > 3) filt_pack<FA3, FB3>(zD, tid, g, cA3, cB3, Ck3, Cm3);
  if (tid == 0) {
    float2 nA, nB = make_float2(0.f, 0.f);
    nA = fc[FA0 * 257 + 256];
    if (FB0 >= 0) nB = fc[FB0 * 257 + 256];
    filt_pack<FA0, FB0>(zA, 256, g, nA, nB, Cn0, dum);
    if (NBUF > 1) {
      nA = fc[FA1 * 257 + 256]; nB = fc[FB1 * 257 + 256];
      filt_pack<FA1, FB1>(zB, 256, g, nA, nB, Cn1, dum);
    }
    if (NBUF > 2) {
      nA = fc[FA2 * 257 + 256]; nB = fc[FB2 * 257 + 256];
      filt_pack<FA2, FB2>(zC, 256, g, nA, nB, Cn2, dum);
    }
    if (NBUF > 3) {
      nA = fc[FA3 * 257 + 256]; nB = fc[FB3 * 257 + 256];
      filt_pack<FA3, FB3>(zD, 256, g, nA, nB, Cn3, dum);
    }
  }
  __syncthreads();  // all Z reads done before pack-scatter
  {
    zA[rlo] = Ck0;
    if (NBUF > 1) zB[rlo] = Ck1;
    if (NBUF > 2) zC[rlo] = Ck2;
    if (NBUF > 3) zD[rlo] = Ck3;
    if (tid == 0) {
      zA[padz(1)] = Cn0;               // rev9(256) = 1
      if (NBUF > 1) zB[padz(1)] = Cn1;
      if (NBUF > 2) zC[padz(1)] = Cn2;
      if (NBUF > 3) zD[padz(1)] = Cn3;
    } else {
      const int rm = padz(rev9(512 - tid));
      zA[rm] = Cm0;
      if (NBUF > 1) zB[rm] = Cm1;
      if (NBUF > 2) zC[rm] = Cm2;
      if (NBUF > 3) zD[rm] = Cm3;
    }
  }
  __syncthreads();
  if (wid < NBUF) {
    float2* zz = (wid == 0) ? zA : (wid == 1) ? zB : (wid == 2) ? zC : zD;
    pass8<1, 1, true>(zz, l, ptw[0], ptw[1], ptw[2]);
    pass8<8, 1, false>(zz, l, ptw[0], ptw[1], ptw[2]);
    pass8<64, 1, false>(zz, l, ptw[3], ptw[4], ptw[5]);
  }
  __syncthreads();
  {
    const float2 vLo = zA[padz(tid)], vHi = zA[padz(tid + 256)];
    accr[FA0] += 0.5f * wlo * vLo.x;
    accr[FA0 + 1] += 0.5f * whi * vHi.x;
    if (FB0 >= 0) {
      accr[FB0] += 0.5f * wlo * vLo.y;
      accr[FB0 + 1] += 0.5f * whi * vHi.y;
    }
    if (NBUF > 1) {
      const float2 uLo = zB[padz(tid)], uHi = zB[padz(tid + 256)];
      accr[FA1] += 0.5f * wlo * uLo.x;
      accr[FA1 + 1] += 0.5f * whi * uHi.x;
      accr[FB1] += 0.5f * wlo * uLo.y;
      accr[FB1 + 1] += 0.5f * whi * uHi.y;
    }
    if (NBUF > 2) {
      const float2 uLo = zC[padz(tid)], uHi = zC[padz(tid + 256)];
      accr[FA2] += 0.5f * wlo * uLo.x;
      accr[FA2 + 1] += 0.5f * whi * uHi.x;
      accr[FB2] += 0.5f * wlo * uLo.y;
      accr[FB2 + 1] += 0.5f * whi * uHi.y;
    }
    if (NBUF > 3) {
      const float2 uLo = zD[padz(tid)], uHi = zD[padz(tid + 256)];
      accr[FA3] += 0.5f * wlo * uLo.x;
      accr[FA3 + 1] += 0.5f * whi * uHi.x;
      accr[FB3] += 0.5f * wlo * uLo.y;
      accr[FB3 + 1] += 0.5f * whi * uHi.y;
    }
  }
}

__global__ __launch_bounds__(256) void k_ecg_fft(
    const float* __restrict__ ecgT, const float2* __restrict__ FcT,
    const float* __restrict__ gate, const float2* __restrict__ twg,
    unsigned short* __restrict__ xtT) {
  const int bd = blockIdx.x;
  const int d = bd % D_;
  const int tid = threadIdx.x;

  __shared__ float2 zA[544], zB[544], zC[544], zD[544];  // 17 KB

  float s[8];
  const float* src = ecgT + (size_t)bd * S_;
#pragma unroll
  for (int k = 0; k < 8; ++k) s[k] = src[k * 256 + tid];

  const int l6 = tid & 63;
  float2 ptw[6];
  ptw[0] = twg[7 + (l6 & 7)];     // H=8:  W_16^j
  ptw[1] = twg[15 + (l6 & 7)];    // H=8:  W_32^j
  ptw[2] = twg[31 + (l6 & 7)];    // H=8:  W_64^j
  ptw[3] = twg[63 + l6];          // H=64: W_128^j
  ptw[4] = twg[127 + l6];         // H=64: W_256^j
  ptw[5] = twg[255 + l6];         // H=64: W_512^j
  const float2 t8 = twg[255 + tid];  // window / norm only

  const float g = gate[bd];
  const float2* fc = FcT + (size_t)d * NBINS_;
  float accr[10];
#pragma unroll
  for (int i = 0; i < 10; ++i) accr[i] = 0.f;

  ecg_super4<0, 8, 1, 2, 3, 4, 5, 6, 4>(tid, g, fc, s, ptw, t8, zA, zB, zC, zD, accr);
  ecg_super4<7, -1, 0, 0, 0, 0, 0, 0, 1>(tid, g, fc, s, ptw, t8, zA, zB, zC, zD, accr);

  const float c0 = t8.x;
  const float rinv = 1.0f / (0.5f + 0.5f * c0 * c0);
  unsigned short* dst = xtT + (size_t)bd * S_;
#pragma unroll
  for (int i2 = 0; i2 < 8; ++i2)
    dst[i2 * 256 + tid] = f2bf(accr[i2 + 1] * rinv + s[i2]);
}

// ---- per-(b,t) LN stats over d, reading bf16 xtT[b][d][t] as uint pairs ----
__global__ __launch_bounds__(256) void k_colstats_bf(const unsigned short* __restrict__ xtT,
                                                     float2* __restrict__ stats) {
  const int b = blockIdx.y;
  const int t0 = blockIdx.x * 128;
  const int tx = threadIdx.x & 63;
  const int ty = threadIdx.x >> 6;
  float s0 = 0.f, q0 = 0.f, s1 = 0.f, q1 = 0.f;
  const unsigned int* base = (const unsigned int*)(xtT + (size_t)b * D_ * S_);
  for (int dd = ty; dd < D_; dd += 4) {
    const unsigned int u = base[(size_t)dd * (S_ / 2) + (t0 >> 1) + tx];
    const float v0 = bf2f((unsigned short)(u & 0xffffu));
    const float v1 = bf2f((unsigned short)(u >> 16));
    s0 += v0; q0 = fmaf(v0, v0, q0);
    s1 += v1; q1 = fmaf(v1, v1, q1);
  }
  __shared__ float sh[4][64][4];
  sh[ty][tx][0] = s0; sh[ty][tx][1] = q0; sh[ty][tx][2] = s1; sh[ty][tx][3] = q1;
  __syncthreads();
  if (ty == 0) {
    s0 = sh[0][tx][0] + sh[1][tx][0] + sh[2][tx][0] + sh[3][tx][0];
    q0 = sh[0][tx][1] + sh[1][tx][1] + sh[2][tx][1] + sh[3][tx][1];
    s1 = sh[0][tx][2] + sh[1][tx][2] + sh[2][tx][2] + sh[3][tx][2];
    q1 = sh[0][tx][3] + sh[1][tx][3] + sh[2][tx][3] + sh[3][tx][3];
    stats[(size_t)b * S_ + t0 + 2 * tx]     = make_float2(s0, q0);
    stats[(size_t)b * S_ + t0 + 2 * tx + 1] = make_float2(s1, q1);
  }
}

// ---- transpose + LN apply, bf16 in -> bf16 out ----
__global__ __launch_bounds__(256) void k_transpose_ln(
    const unsigned short* __restrict__ xtT, const float2* __restrict__ stats,
    const float* __restrict__ g, const float* __restrict__ bia,
    unsigned short* __restrict__ xhat) {
  __shared__ float tile[32][33];
  const int b = blockIdx.z;
  const int t0 = blockIdx.x * 32;
  const int d0 = blockIdx.y * 32;
  const int tx = threadIdx.x & 31, ty = threadIdx.x >> 5;
  for (int i = ty; i < 32; i += 8)
    tile[i][tx] = bf2f(xtT[((size_t)b * D_ + d0 + i) * S_ + t0 + tx]);
  __syncthreads();
  const float gv = g[d0 + tx], bv = bia[d0 + tx];
  for (int i = ty; i < 32; i += 8) {
    const float2 st = stats[(size_t)b * S_ + t0 + i];
    const float mean = st.x * (1.0f / 768.0f);
    const float var = st.y * (1.0f / 768.0f) - mean * mean;
    const float inv = rsqrtf(var + 1e-5f);
    xhat[((size_t)b * S_ + t0 + i) * D_ + d0 + tx] =
        f2bf((tile[tx][i] - mean) * inv * gv + bv);
  }
}

// ---- dual-segment LayerNorm, bf16 in -> f32 out ----
__global__ __launch_bounds__(256) void k_layernorm_dual(
    const unsigned short* __restrict__ x1, const float* __restrict__ g1,
    const float* __restrict__ b1, float* __restrict__ o1, int n1,
    const unsigned short* __restrict__ x2, const float* __restrict__ g2,
    const float* __restrict__ b2, float* __restrict__ o2) {
  int row = blockIdx.x;
  const unsigned short* x; const float *g, *b; float* o;
  if (row < n1) { x = x1; g = g1; b = b1; o = o1; }
  else { row -= n1; x = x2; g = g2; b = b2; o = o2; }
  const int tid = threadIdx.x;
  const unsigned short* xr = x + (size_t)row * D_;
  const float v0 = bf2f(xr[tid]), v1 = bf2f(xr[tid + 256]), v2 = bf2f(xr[tid + 512]);
  float s = v0 + v1 + v2;
  float q = v0 * v0 + v1 * v1 + v2 * v2;
  __shared__ float red[8];
  for (int off = 32; off > 0; off >>= 1) {
    s += __shfl_down(s, off);
    q += __shfl_down(q, off);
  }
  if ((tid & 63) == 0) { red[tid >> 6] = s; red[4 + (tid >> 6)] = q; }
  __syncthreads();
  s = red[0] + red[1] + red[2] + red[3];
  q = red[4] + red[5] + red[6] + red[7];
  const float mean = s * (1.0f / 768.0f);
  const float var = q * (1.0f / 768.0f) - mean * mean;
  const float inv = rsqrtf(var + 1e-5f);
  float* orow = o + (size_t)row * D_;
  orow[tid]       = (v0 - mean) * inv * g[tid]       + b[tid];
  orow[tid + 256] = (v1 - mean) * inv * g[tid + 256] + b[tid + 256];
  orow[tid + 512] = (v2 - mean) * inv * g[tid + 512] + b[tid + 512];
}

// ---------- dual-segment MFMA GEMM, double-buffered pipeline ----------
// MODE 0: exact GELU -> bf16 ; MODE 1: +resid(bf16) -> bf16
template <int MODE>
__global__ __launch_bounds__(256) void k_gemm_dual(
    const unsigned short* __restrict__ A1, const unsigned short* __restrict__ W1,
    const float* __restrict__ b1, const unsigned short* __restrict__ r1,
    unsigned short* __restrict__ o1, int M1, int nby1,
    const unsigned short* __restrict__ A2, const unsigned short* __restrict__ W2,
    const float* __restrict__ b2, const unsigned short* __restrict__ r2,
    unsigned short* __restrict__ o2, int M2) {
  __shared__ unsigned short Asm[2][128 * 64];
  __shared__ unsigned short Bsm[2][128 * 64];
  const int tid = threadIdx.x;
  const int lane = tid & 63, wid = tid >> 6;
  const int wr = wid >> 1, wc = wid & 1;
  int bx, by;
  {
    const int nwg = gridDim.x * gridDim.y;
    const int bid = blockIdx.y * gridDim.x + blockIdx.x;
    const int xcd = bid & 7, lin = bid >> 3;
    const int qq = nwg >> 3, rr = nwg & 7;
    const int nbid = (xcd < rr) ? xcd * (qq + 1) + lin
                                : rr * (qq + 1) + (xcd - rr) * qq + lin;
    bx = nbid % gridDim.x;
    by = nbid / gridDim.x;
  }
  const unsigned short* Abf; const unsigned short* Wbf; const float* bias;
  const unsigned short* resid; unsigned short* outb; int M;
  if (by < nby1) { Abf = A1; Wbf = W1; bias = b1; resid = r1; outb = o1; M = M1; }
  else { by -= nby1; Abf = A2; Wbf = W2; bias = b2; resid = r2; outb = o2; M = M2; }
  const int n0 = bx * 128, m0 = by * 128;

  auto STAGE = [&](int buf, int kt) {
    const int k0 = kt * 64;
#pragma unroll
    for (int i = 0; i < 4; ++i) {
      const int c = tid + 256 * i;
      const int row = c >> 3, sl = c & 7;
      const int gsl = sl ^ (row & 7);
      gload16(Abf + (size_t)(m0 + row) * 768 + k0 + gsl * 8, &Asm[buf][c * 8]);
      gload16(Wbf + (size_t)(n0 + row) * 768 + k0 + gsl * 8, &Bsm[buf][c * 8]);
    }
  };

  f32x4 acc[4][4] = {};
  STAGE(0, 0);
  for (int kt = 0; kt < 12; ++kt) {
    const int cur = kt & 1;
    if (kt < 11) {
      STAGE(cur ^ 1, kt + 1);
      asm volatile("s_waitcnt vmcnt(8)" ::: "memory");
    } else {
      asm volatile("s_waitcnt vmcnt(0)" ::: "memory");
    }
    __builtin_amdgcn_sched_barrier(0);
    __builtin_amdgcn_s_barrier();
#pragma unroll
    for (int ks = 0; ks < 2; ++ks) {
      bf16x8 af[4], bfv[4];
#pragma unroll
      for (int mi = 0; mi < 4; ++mi) {
        const int row = wr * 64 + mi * 16 + (lane & 15);
        const int sl = (ks * 4 + (lane >> 4)) ^ (row & 7);
        af[mi] = *(const bf16x8*)((const char*)Asm[cur] + row * 128 + sl * 16);
      }
#pragma unroll
      for (int ni = 0; ni < 4; ++ni) {
        const int row = wc * 64 + ni * 16 + (lane & 15);
        const int sl = (ks * 4 + (lane >> 4)) ^ (row & 7);
        bfv[ni] = *(const bf16x8*)((const char*)Bsm[cur] + row * 128 + sl * 16);
      }
#pragma unroll
      for (int mi = 0; mi < 4; ++mi)
#pragma unroll
        for (int ni = 0; ni < 4; ++ni)
          acc[mi][ni] = __builtin_amdgcn_mfma_f32_16x16x32_bf16(af[mi], bfv[ni],
                                                                acc[mi][ni], 0, 0, 0);
    }
    __builtin_amdgcn_sched_barrier(0);
    __builtin_amdgcn_s_barrier();
  }
#pragma unroll
  for (int mi = 0; mi < 4; ++mi) {
#pragma unroll
    for (int ni = 0; ni < 4; ++ni) {
      const int col = n0 + wc * 64 + ni * 16 + (lane & 15);
#pragma unroll
      for (int e = 0; e < 4; ++e) {
        const int row = m0 + wr * 64 + mi * 16 + (lane >> 4) * 4 + e;
        if (row >= M) continue;
        float v = acc[mi][ni][e] + bias[col];
        if (MODE == 0) {
          v = gelu_f(v);
        } else {
          v += bf2f(resid[(size_t)row * 768 + col]);
        }
        outb[(size_t)row * 768 + col] = f2bf(v);
      }
    }
  }
}

}  // namespace

extern "C" void kernel_launch(void* const* d_in, const int* in_sizes, int n_in,
                              void* d_out, int out_size, void* d_ws, size_t ws_size,
                              hipStream_t stream) {
  (void)in_sizes; (void)n_in; (void)out_size; (void)ws_size;
  const float* ecg     = (const float*)d_in[0];
  const float* image   = (const float*)d_in[1];
  const float* ebank   = (const float*)d_in[2];
  const float* cbank   = (const float*)d_in[3];
  const float* gsel    = (const float*)d_in[4];
  const float* gw      = (const float*)d_in[5];
  const float* gb      = (const float*)d_in[6];
  const float* e_ln1_g = (const float*)d_in[7];
  const float* e_ln1_b = (const float*)d_in[8];
  const float* e_w1    = (const float*)d_in[9];
  const float* e_b1    = (const float*)d_in[10];
  const float* e_w2    = (const float*)d_in[11];
  const float* e_b2    = (const float*)d_in[12];
  const float* e_ln2_g = (const float*)d_in[13];
  const float* e_ln2_b = (const float*)d_in[14];
  const float* c_ln1_g = (const float*)d_in[15];
  const float* c_ln1_b = (const float*)d_in[16];
  const float* c_w1    = (const float*)d_in[17];
  const float* c_b1    = (const float*)d_in[18];
  const float* c_w2    = (const float*)d_in[19];
  const float* c_b2    = (const float*)d_in[20];
  const float* c_ln2_g = (const float*)d_in[21];
  const float* c_ln2_b = (const float*)d_in[22];

  float* out = (float*)d_out;
  float* ws = (float*)d_ws;

  constexpr size_t TXT = (size_t)8 * 2048 * 768;   // 12,582,912 floats
  constexpr size_t IMG = (size_t)8 * 196 * 768;    // 1,204,224 elems

  // ws layout: A | Bb | wbf | gatev | stats | gpart | twg | twN
  float* A  = ws;
  float* Bb = A + TXT;
  unsigned short* wbf = (unsigned short*)(Bb + TXT);
  unsigned short* ew1b = wbf;
  unsigned short* ew2b = wbf + NW_;
  unsigned short* cw1b = wbf + 2 * NW_;
  unsigned short* cw2b = wbf + 3 * NW_;
  float* gatev = (float*)(wbf + 4 * (size_t)NW_);
  float2* stats = (float2*)(gatev + 8 * 768);
  float* gpart = (float*)(stats + 8 * 2048);   // 8*11*768 floats
  float2* twg = (float2*)(gpart + 8 * 11 * 768);
  float2* twN = twg + 511;

  float2* FcT = (float2*)out;  // parked in d_out (dead before final LN)

  // text buffers: A = xhat (first half, bf16) | y_tb (second half, bf16)
  unsigned short* xhat = (unsigned short*)A;
  unsigned short* y_tb = (unsigned short*)A + TXT;
  // Bb first half: xtT then h_t (bf16); second half: image scratch
  unsigned short* xtT = (unsigned short*)Bb;
  unsigned short* h_t = (unsigned short*)Bb;
  float* Bb2 = Bb + TXT / 2;
  float2* imgF = (float2*)Bb2;                               // 1,216,512 floats
  float* xi = Bb2 + 1216512;                                 // 1,204,224 floats
  unsigned short* xh_i = (unsigned short*)(xi + IMG);        // bf16 LN1 / resid
  unsigned short* h_i  = xh_i + IMG;
  unsigned short* y_ib = h_i + IMG;

  // ---- one-time prep ----
  k_prep<<<PREP_WALL + 3, 256, 0, stream>>>(e_w1, e_w2, c_w1, c_w2, wbf, twg, twN);
  k_fc_t<<<dim3(24, 9, 9), 256, 0, stream>>>((const float2*)ebank, FcT);

  // ---- image path front (produces gate + xh_i) ----
  k_img_dft_f<<<dim3(11, 3, 8), 256, 0, stream>>>(image, (const float2*)cbank,
                                                  (const float2*)gsel, twN, imgF, gpart);
  k_gate_mm2<<<48, 256, 0, stream>>>(gpart, gw, gb, gatev);
  k_img_idft<<<dim3(14, 3, 8), 256, 0, stream>>>(imgF, image, twN, xi);
  k_layernorm_f2b<<<1568, 256, 0, stream>>>(xi, c_ln1_g, c_ln1_b, xh_i);

  // ---- ecg path ----
  k_transpose_g<<<dim3(24, 64, 8), 256, 0, stream>>>(ecg, A, 2048, 768);
  k_ecg_fft<<<8 * 768, 256, 0, stream>>>(A, FcT, gatev, twg, xtT);
  k_colstats_bf<<<dim3(16, 8), 256, 0, stream>>>(xtT, stats);
  k_transpose_ln<<<dim3(64, 24, 8), 256, 0, stream>>>(xtT, stats, e_ln1_g, e_ln1_b, xhat);

  // ---- combined FFN: text (128 by-blocks) + image (13 by-blocks) ----
  k_gemm_dual<0><<<dim3(6, 141), 256, 0, stream>>>(
      xhat, ew1b, e_b1, nullptr, h_t, 16384, 128,
      xh_i, cw1b, c_b1, nullptr, h_i, 1568);
  k_gemm_dual<1><<<dim3(6, 141), 256, 0, stream>>>(
      h_t, ew2b, e_b2, xhat, y_tb, 16384, 128,
      h_i, cw2b, c_b2, xh_i, y_ib, 1568);
  k_layernorm_dual<<<16384 + 1568, 256, 0, stream>>>(
      y_tb, e_ln2_g, e_ln2_b, out, 16384,
      y_ib, c_ln2_g, c_ln2_b, out + TXT);
}